// Round 2
// baseline (8541.967 us; speedup 1.0000x reference)
//
#include <hip/hip_runtime.h>
#include <hip/hip_bf16.h>
#include <cstddef>

typedef __hip_bfloat16 bf16;

// ---------------- problem constants ----------------
#define BATCH 8
#define HR 128
#define WR 128
#define CCH 192
#define HW (HR*WR)            // 16384
#define MTOK (BATCH*HW)       // 131072
#define SPH 6
#define QKVC (3*CCH)          // 576
#define NWIN 256
#define MIDC 48
#define LOGMAX 4.6051701859880914f  // log(100)

// ---------------- ws layout (BYTE offsets; peak ~169 MB) ----------------
static const size_t OFF_SPOUT  = 0;                    // bf16 M*192 = 50,331,648 B (later reused: f2)
static const size_t OFF_CHOUT  = 50331648;             // bf16 M*192 (later reused: gpre)
static const size_t OFF_QKVB   = 100663296;            // bf16 HW*576 = 18,874,368 B (per-batch)
static const size_t OFF_OSPB   = 119537664;            // bf16 HW*144 = 4,718,592 B (per-batch)
static const size_t OFF_STATS1 = 124256256;            // fp32 2*M   = 1,048,576 B
static const size_t OFF_STATS2 = 125304832;            // fp32 2*M
static const size_t OFF_RNORM  = 126353408;            // fp32 96 (per-batch)
static const size_t OFF_ATTNB  = 126353920;            // fp32 1152 (per-batch)
static const size_t OFF_MEANSP = 126359040;            // fp32 1536
static const size_t OFF_MEANCH = 126365184;
static const size_t OFF_GATES  = 126371328;
static const size_t OFF_GATEC  = 126377472;
static const size_t OFF_WCSP   = 126383616;            // fp32 192*144
static const size_t OFF_BCSP   = 126494208;            // fp32 192
static const size_t OFF_WCCH   = 126495232;            // fp32 192*48
static const size_t OFF_BCCH   = 126532096;            // fp32 192
static const size_t OFF_PH2    = 126533632;            // phase-2/3 region, 50,331,648 B
// hid_s = OFF_PH2 ; hid_c = OFF_PH2+12,582,912 (dead before f)
// f      = OFF_PH2 (bf16 M*192)
// f2     = OFF_SPOUT ; gpre = OFF_CHOUT (sp/ch dead)
// hidden = OFF_PH2 (bf16 chunk 32768*768, f dead)
// peak end = OFF_PH2 + 50,331,648 = 176,865,280 B

__device__ __forceinline__ float b2f(bf16 x) { return __bfloat162float(x); }
__device__ __forceinline__ bf16  f2b(float x){ return __float2bfloat16(x); }

template<int ABF>
__device__ __forceinline__ float loadA(const void* A, size_t idx) {
    if constexpr (ABF) return b2f(((const bf16*)A)[idx]);
    else               return ((const float*)A)[idx];
}

// =====================================================================
// Generic tiled fp32-math GEMM: C[M,N] = epi(A'[M,K] @ W[N,K]^T + bias)
// AMODE: 0 plain, 1 LN-fused (A fp32), 2 concat(A|A2, both 192), 3 implicit 3x3 conv
// WMODE: 0 row-major [N][K] fp32, 1 conv weights (O,I,3,3) fp32
// EPI: 0 bias, 1 relu, 2 per-batch roll(+4,+4)-store, 3 BN+relu,
//      4 gated residual (C += v*gate[b]), 5 gelu(exact), 6 residual add (fp32 ep0)
// ABF: A (and A2) bf16?   CBF: C bf16?
// =====================================================================
#define BM 64
#define BN 64
#define BK 16

template<int AMODE, int EPI, int WMODE, int ABF, int CBF>
__global__ __launch_bounds__(256)
void gemm_k(const void* __restrict__ A, const float* __restrict__ W,
            const float* __restrict__ bias, void* __restrict__ Cv,
            int M, int N, int K,
            const float* __restrict__ stats, const float* __restrict__ lng,
            const float* __restrict__ lnb, const void* __restrict__ A2,
            const float* __restrict__ ep0, const float* __restrict__ ep1,
            const float* __restrict__ ep2, const float* __restrict__ ep3,
            int cin, int batch)
{
    __shared__ float As[BK][BM+4];
    __shared__ float Bs[BK][BN+4];
    const int tid = threadIdx.x;
    const int m0 = blockIdx.y * BM;
    const int n0 = blockIdx.x * BN;
    const int tx = tid & 15, ty = tid >> 4;
    const int lr  = tid >> 2;        // 0..63
    const int lc4 = (tid & 3) * 4;   // 0,4,8,12
    float acc[4][4] = {};

    for (int k0 = 0; k0 < K; k0 += BK) {
        { // ---- A tile ----
            const int m = m0 + lr;
            #pragma unroll
            for (int j = 0; j < 4; ++j) {
                const int k = k0 + lc4 + j;
                float a;
                if constexpr (AMODE == 0) {
                    a = loadA<ABF>(A, (size_t)m * K + k);
                } else if constexpr (AMODE == 1) {
                    const float xv = ((const float*)A)[(size_t)m * K + k];
                    a = (xv - stats[2*m]) * stats[2*m+1] * lng[k] + lnb[k];
                } else if constexpr (AMODE == 2) {
                    a = (k < CCH) ? loadA<ABF>(A,  (size_t)m * CCH + k)
                                  : loadA<ABF>(A2, (size_t)m * CCH + (k - CCH));
                } else { // implicit conv
                    const int t = k / cin, c = k - t * cin;
                    const int ky = t / 3, kx = t - ky * 3;
                    const int b = m >> 14, pix = m & 16383;
                    const int h = (pix >> 7) + ky - 1;
                    const int w = (pix & 127) + kx - 1;
                    a = (h >= 0 && h < HR && w >= 0 && w < WR)
                        ? loadA<ABF>(A, ((size_t)(b * HW) + h * WR + w) * (size_t)cin + c) : 0.f;
                }
                As[lc4 + j][lr] = a;
            }
        }
        { // ---- B tile ----
            const int n = n0 + lr;
            #pragma unroll
            for (int j = 0; j < 4; ++j) {
                const int k = k0 + lc4 + j;
                float wv = 0.f;
                if (n < N) {
                    if constexpr (WMODE == 0) {
                        wv = W[(size_t)n * K + k];
                    } else {
                        const int t = k / cin, c = k - t * cin;
                        wv = W[((size_t)n * cin + c) * 9 + t];
                    }
                }
                Bs[lc4 + j][lr] = wv;
            }
        }
        __syncthreads();
        #pragma unroll
        for (int kk = 0; kk < BK; ++kk) {
            float ar[4], br[4];
            #pragma unroll
            for (int i = 0; i < 4; ++i) ar[i] = As[kk][ty*4 + i];
            #pragma unroll
            for (int j = 0; j < 4; ++j) br[j] = Bs[kk][tx*4 + j];
            #pragma unroll
            for (int i = 0; i < 4; ++i)
                #pragma unroll
                for (int j = 0; j < 4; ++j)
                    acc[i][j] += ar[i] * br[j];
        }
        __syncthreads();
    }

    // ---- epilogue ----
    #pragma unroll
    for (int i = 0; i < 4; ++i) {
        const int m = m0 + ty*4 + i;
        #pragma unroll
        for (int j = 0; j < 4; ++j) {
            const int n = n0 + tx*4 + j;
            if (n >= N) continue;
            float v = acc[i][j] + (bias ? bias[n] : 0.f);
            size_t outIdx;
            if constexpr (EPI == 2) {
                const int h2 = ((m >> 7) + 4) & 127;
                const int w2 = ((m & 127) + 4) & 127;
                outIdx = ((size_t)(batch * HW) + h2 * WR + w2) * (size_t)N + n;
            } else {
                outIdx = (size_t)m * N + n;
            }
            if constexpr (EPI == 1) {
                v = fmaxf(v, 0.f);
            } else if constexpr (EPI == 3) {
                v = (v - ep2[n]) * rsqrtf(ep3[n] + 1e-5f) * ep0[n] + ep1[n];
                v = fmaxf(v, 0.f);
            } else if constexpr (EPI == 4) {
                const int b = m >> 14;
                const float cold = CBF ? b2f(((const bf16*)Cv)[outIdx])
                                       : ((const float*)Cv)[outIdx];
                v = cold + v * ep0[b * N + n];
            } else if constexpr (EPI == 5) {
                v = 0.5f * v * (1.f + erff(v * 0.70710678118654752f));
            } else if constexpr (EPI == 6) {
                v = ep0[outIdx] + v;
            }
            if constexpr (CBF) ((bf16*)Cv)[outIdx] = f2b(v);
            else               ((float*)Cv)[outIdx] = v;
        }
    }
}

// =====================================================================
// LN stats: per token mean & rstd
// =====================================================================
__global__ __launch_bounds__(256)
void ln_stats_k(const float* __restrict__ x, float* __restrict__ stats)
{
    const int tok = blockIdx.x * 4 + (threadIdx.x >> 6);
    const int lane = threadIdx.x & 63;
    const float* r = x + (size_t)tok * CCH;
    float s = 0.f, sq = 0.f;
    for (int c = lane; c < CCH; c += 64) { float v = r[c]; s += v; sq += v*v; }
    for (int m = 1; m < 64; m <<= 1) { s += __shfl_xor(s, m); sq += __shfl_xor(sq, m); }
    if (lane == 0) {
        const float mean = s / (float)CCH;
        const float var = sq / (float)CCH - mean * mean;
        stats[(size_t)tok*2]   = mean;
        stats[(size_t)tok*2+1] = rsqrtf(var + 1e-5f);
    }
}

// =====================================================================
// Spatial shifted-window cosine attention, one batch (heads 0..5)
// =====================================================================
__global__ __launch_bounds__(256)
void sp_attn_k(const bf16* __restrict__ qkv, const float* __restrict__ rpb,
               const float* __restrict__ logit_sp, bf16* __restrict__ o)
{
    const int head = blockIdx.x;
    const int win  = blockIdx.y;
    const int wh = win >> 4, ww = win & 15;
    const int tid = threadIdx.x;

    __shared__ float q[64][25], k[64][25], v[64][25];
    __shared__ float attn[64][66];
    __shared__ float rq[64], rk[64];
    __shared__ int   lab[64];
    __shared__ float scale_s;

    for (int idx = tid; idx < 64*24*3; idx += 256) {
        const int which = idx / 1536;
        const int rem = idx - which * 1536;
        const int p = rem / 24, d = rem - (rem/24)*24;
        const int h = (wh*8 + (p >> 3) + 4) & 127;
        const int w = (ww*8 + (p & 7)  + 4) & 127;
        const float val = b2f(qkv[((size_t)(h*WR + w)) * QKVC + head*72 + which*24 + d]);
        if (which == 0) q[p][d] = val;
        else if (which == 1) k[p][d] = val;
        else v[p][d] = val;
    }
    if (tid == 0) scale_s = expf(fminf(logit_sp[head], LOGMAX));
    __syncthreads();

    if (tid < 64) {
        float s = 0.f;
        #pragma unroll
        for (int d = 0; d < 24; ++d) s += q[tid][d]*q[tid][d];
        rq[tid] = 1.f / fmaxf(sqrtf(s), 1e-12f);
        const int h = wh*8 + (tid >> 3), w = ww*8 + (tid & 7);
        const int rh = h < 120 ? 0 : (h < 124 ? 1 : 2);
        const int rw = w < 120 ? 0 : (w < 124 ? 1 : 2);
        lab[tid] = rh*3 + rw;
    } else if (tid < 128) {
        const int i = tid - 64;
        float s = 0.f;
        #pragma unroll
        for (int d = 0; d < 24; ++d) s += k[i][d]*k[i][d];
        rk[i] = 1.f / fmaxf(sqrtf(s), 1e-12f);
    }
    __syncthreads();

    for (int e = tid; e < 4096; e += 256) {
        const int i = e >> 6, j = e & 63;
        float s = 0.f;
        #pragma unroll
        for (int d = 0; d < 24; ++d) s += q[i][d]*k[j][d];
        s = s * rq[i] * rk[j] * scale_s;
        const int r0 = (i >> 3) - (j >> 3) + 7;
        const int r1 = (i & 7) - (j & 7) + 7;
        s += rpb[(r0*15 + r1)*SPH + head];
        if (lab[i] != lab[j]) s -= 100.f;
        attn[i][j] = s;
    }
    __syncthreads();

    { // softmax, 4 lanes per row
        const int r = tid >> 2, l = tid & 3;
        float mx = -1e30f;
        for (int j = l; j < 64; j += 4) mx = fmaxf(mx, attn[r][j]);
        mx = fmaxf(mx, __shfl_xor(mx, 1));
        mx = fmaxf(mx, __shfl_xor(mx, 2));
        float sum = 0.f;
        for (int j = l; j < 64; j += 4) { float e2 = expf(attn[r][j] - mx); attn[r][j] = e2; sum += e2; }
        sum += __shfl_xor(sum, 1);
        sum += __shfl_xor(sum, 2);
        const float inv = 1.f / sum;
        for (int j = l; j < 64; j += 4) attn[r][j] *= inv;
    }
    __syncthreads();

    for (int idx = tid; idx < 64*24; idx += 256) {
        const int i = idx / 24, d = idx - (idx/24)*24;
        float s = 0.f;
        #pragma unroll
        for (int j = 0; j < 64; ++j) s += attn[i][j] * v[j][d];
        const int h = wh*8 + (i >> 3), w = ww*8 + (i & 7);
        o[((size_t)(h*WR + w)) * 144 + head*24 + d] = f2b(s);
    }
}

// =====================================================================
// Channel attention, one batch (heads 6,7)
// =====================================================================
__global__ __launch_bounds__(256)
void ch_norm_k(const bf16* __restrict__ qkv, float* __restrict__ rnorm)
{
    const int c = blockIdx.x;     // 0..47 (q:0-23, k:24-47)
    const int head = blockIdx.y;  // 0..1
    const bf16* base = qkv + (6 + head) * 72 + c;
    float s = 0.f;
    for (int i = threadIdx.x; i < HW; i += 256) { const float v = b2f(base[(size_t)i * QKVC]); s += v*v; }
    __shared__ float red[256];
    red[threadIdx.x] = s; __syncthreads();
    for (int st = 128; st > 0; st >>= 1) { if (threadIdx.x < st) red[threadIdx.x] += red[threadIdx.x + st]; __syncthreads(); }
    if (threadIdx.x == 0) rnorm[head*48 + c] = 1.f / fmaxf(sqrtf(red[0]), 1e-12f);
}

__global__ __launch_bounds__(256)
void ch_attn_k(const bf16* __restrict__ qkv, const float* __restrict__ rnorm,
               const float* __restrict__ logit_ch, float* __restrict__ attn_ch)
{
    const int c = blockIdx.x;     // q row 0..23
    const int head = blockIdx.y;
    const bf16* base = qkv + (6 + head) * 72;
    float acc[24];
    #pragma unroll
    for (int d = 0; d < 24; ++d) acc[d] = 0.f;
    for (int i = threadIdx.x; i < HW; i += 256) {
        const bf16* row = base + (size_t)i * QKVC;
        const float qv = b2f(row[c]);
        #pragma unroll
        for (int d = 0; d < 24; ++d) acc[d] += qv * b2f(row[24 + d]);
    }
    __shared__ float red[256];
    __shared__ float rowv[24];
    for (int d = 0; d < 24; ++d) {
        red[threadIdx.x] = acc[d]; __syncthreads();
        for (int st = 128; st > 0; st >>= 1) { if (threadIdx.x < st) red[threadIdx.x] += red[threadIdx.x + st]; __syncthreads(); }
        if (threadIdx.x == 0) rowv[d] = red[0];
        __syncthreads();
    }
    if (threadIdx.x == 0) {
        const float scale = expf(fminf(logit_ch[head], LOGMAX));
        const float* rn = rnorm + head*48;
        float vals[24], mx = -1e30f;
        #pragma unroll
        for (int d = 0; d < 24; ++d) { vals[d] = rowv[d]*rn[c]*rn[24+d]*scale; mx = fmaxf(mx, vals[d]); }
        float sum = 0.f;
        #pragma unroll
        for (int d = 0; d < 24; ++d) { vals[d] = expf(vals[d] - mx); sum += vals[d]; }
        const float inv = 1.f / sum;
        float* out = attn_ch + ((size_t)head*24 + c)*24;
        #pragma unroll
        for (int d = 0; d < 24; ++d) out[d] = vals[d]*inv;
    }
}

__global__ __launch_bounds__(256)
void ch_out_k(const bf16* __restrict__ qkv, const float* __restrict__ attn_ch,
              const float* __restrict__ Wc, const float* __restrict__ bc,
              bf16* __restrict__ ch_out)
{
    const int pix0 = blockIdx.x * 64;
    const int tid = threadIdx.x;
    __shared__ float A2s[2][24][24];
    __shared__ float Wcs[192][48];
    __shared__ float bcs[192];
    __shared__ float vbuf[64][48];
    __shared__ float ocb[64][49];

    for (int idx = tid; idx < 2*24*24; idx += 256) {
        const int hh = idx / 576, rem = idx - hh*576;
        A2s[hh][rem/24][rem%24] = attn_ch[idx];
    }
    for (int idx = tid; idx < 192*48; idx += 256) Wcs[idx/48][idx%48] = Wc[idx];
    if (tid < 192) bcs[tid] = bc[tid];
    for (int idx = tid; idx < 64*48; idx += 256) {
        const int p = idx / 48, c = idx - (idx/48)*48;
        const int head = c / 24, d = c - head*24;
        vbuf[p][c] = b2f(qkv[((size_t)(pix0 + p)) * QKVC + (6 + head)*72 + 48 + d]);
    }
    __syncthreads();
    for (int idx = tid; idx < 64*48; idx += 256) {
        const int p = idx / 48, c = idx - (idx/48)*48;
        const int head = c / 24, cc = c - head*24;
        float s = 0.f;
        #pragma unroll
        for (int d = 0; d < 24; ++d) s += A2s[head][cc][d] * vbuf[p][head*24 + d];
        ocb[p][c] = s;
    }
    __syncthreads();
    for (int idx = tid; idx < 64*192; idx += 256) {
        const int p = idx / 192, n = idx - (idx/192)*192;
        float s = bcs[n];
        #pragma unroll
        for (int c = 0; c < 48; ++c) s += ocb[p][c] * Wcs[n][c];
        ch_out[((size_t)(pix0 + p)) * CCH + n] = f2b(s);
    }
}

// =====================================================================
// weight combiners
// =====================================================================
__global__ void combine_sp_k(const float* __restrict__ w_sp_proj, const float* __restrict__ w_spp,
                             const float* __restrict__ b_spp, float* __restrict__ Wc, float* __restrict__ bc)
{
    const int n = blockIdx.x; // 0..191
    for (int i = threadIdx.x; i < 144; i += blockDim.x) {
        float s = 0.f;
        for (int j = 0; j < 144; ++j) s += w_sp_proj[n*144 + j] * w_spp[j*144 + i];
        Wc[n*144 + i] = s;
    }
    if (threadIdx.x == 0) {
        float s = 0.f;
        for (int j = 0; j < 144; ++j) s += w_sp_proj[n*144 + j] * b_spp[j];
        bc[n] = s;
    }
}

__global__ void combine_ch_k(const float* __restrict__ w_ch_proj, const float* __restrict__ w_chp,
                             const float* __restrict__ b_chp, float* __restrict__ Wc, float* __restrict__ bc)
{
    const int n = blockIdx.x; // 0..191
    for (int c = threadIdx.x; c < 48; c += blockDim.x) {
        float s = 0.f;
        for (int j = 0; j < 48; ++j) s += w_ch_proj[n*48 + j] * w_chp[j*48 + c];
        Wc[n*48 + c] = s;
    }
    if (threadIdx.x == 0) {
        float s = 0.f;
        for (int j = 0; j < 48; ++j) s += w_ch_proj[n*48 + j] * b_chp[j];
        bc[n] = s;
    }
}

// =====================================================================
// per-(b,c) mean over H,W (bf16 src)
// =====================================================================
__global__ __launch_bounds__(256)
void mean_k(const bf16* __restrict__ src, float* __restrict__ dst)
{
    const int c = blockIdx.x, b = blockIdx.y;
    const bf16* base = src + (size_t)b * HW * CCH + c;
    float s = 0.f;
    for (int i = threadIdx.x; i < HW; i += 256) s += b2f(base[(size_t)i * CCH]);
    __shared__ float red[256];
    red[threadIdx.x] = s; __syncthreads();
    for (int st = 128; st > 0; st >>= 1) { if (threadIdx.x < st) red[threadIdx.x] += red[threadIdx.x + st]; __syncthreads(); }
    if (threadIdx.x == 0) dst[b*CCH + c] = red[0] / (float)HW;
}

// gate = sigmoid(relu(mean @ w1^T) @ w2^T + b2)
__global__ __launch_bounds__(192)
void gates_k(const float* __restrict__ meanv, const float* __restrict__ w1,
             const float* __restrict__ w2, const float* __restrict__ b2,
             float* __restrict__ gate)
{
    const int b = blockIdx.x;
    __shared__ float mv[192], hid[48];
    const int t = threadIdx.x;
    mv[t] = meanv[b*CCH + t];
    __syncthreads();
    if (t < 48) {
        float s = 0.f;
        for (int c = 0; c < 192; ++c) s += w1[t*192 + c] * mv[c];
        hid[t] = fmaxf(s, 0.f);
    }
    __syncthreads();
    float s = b2[t];
    for (int j = 0; j < 48; ++j) s += hid[j] * w2[t*48 + j];
    gate[b*CCH + t] = 1.f / (1.f + expf(-s));
}

// =====================================================================
// out = x + f2 * (1 + sigmoid(relu(gpre)@w_sg2 + b))
// =====================================================================
__global__ __launch_bounds__(256)
void fuse_k(const float* __restrict__ x, const bf16* __restrict__ f2,
            const bf16* __restrict__ gpre, const float* __restrict__ w_sg2,
            const float* __restrict__ b_sg2, float* __restrict__ out)
{
    const int pix = blockIdx.x * 4 + (threadIdx.x >> 6);
    const int lane = threadIdx.x & 63;
    const bf16* gp = gpre + (size_t)pix * 96;
    float s = fmaxf(b2f(gp[lane]), 0.f) * w_sg2[lane];
    if (lane < 32) s += fmaxf(b2f(gp[lane + 64]), 0.f) * w_sg2[lane + 64];
    for (int m = 1; m < 64; m <<= 1) s += __shfl_xor(s, m);
    const float g1 = 1.f + 1.f / (1.f + expf(-(s + b_sg2[0])));
    const float* xr = x  + (size_t)pix * CCH;
    const bf16* fr = f2 + (size_t)pix * CCH;
    float* orow = out + (size_t)pix * CCH;
    for (int c = lane; c < CCH; c += 64) orow[c] = xr[c] + b2f(fr[c]) * g1;
}

// =====================================================================
// launcher
// =====================================================================
extern "C" void kernel_launch(void* const* d_in, const int* in_sizes, int n_in,
                              void* d_out, int out_size, void* d_ws, size_t ws_size,
                              hipStream_t stream)
{
    const float* x        = (const float*)d_in[0];
    const float* ln1_g    = (const float*)d_in[1];
    const float* ln1_b    = (const float*)d_in[2];
    const float* w_qkv    = (const float*)d_in[3];
    const float* b_qkv    = (const float*)d_in[4];
    const float* logit_sp = (const float*)d_in[5];
    const float* rpb      = (const float*)d_in[6];
    const float* w_spp    = (const float*)d_in[7];
    const float* b_spp    = (const float*)d_in[8];
    const float* logit_ch = (const float*)d_in[9];
    const float* w_chp    = (const float*)d_in[10];
    const float* b_chp    = (const float*)d_in[11];
    const float* w_sp_proj= (const float*)d_in[12];
    const float* w_ch_proj= (const float*)d_in[13];
    const float* w_s2c1   = (const float*)d_in[14];
    const float* w_s2c2   = (const float*)d_in[15];
    const float* b_s2c2   = (const float*)d_in[16];
    const float* w_c2s1   = (const float*)d_in[17];
    const float* w_c2s2   = (const float*)d_in[18];
    const float* b_c2s2   = (const float*)d_in[19];
    const float* w_gs1    = (const float*)d_in[20];
    const float* w_gs2    = (const float*)d_in[21];
    const float* b_gs2    = (const float*)d_in[22];
    const float* w_gc1    = (const float*)d_in[23];
    const float* w_gc2    = (const float*)d_in[24];
    const float* b_gc2    = (const float*)d_in[25];
    const float* w_f1     = (const float*)d_in[26];
    const float* bn1_g    = (const float*)d_in[27];
    const float* bn1_b    = (const float*)d_in[28];
    const float* bn1_m    = (const float*)d_in[29];
    const float* bn1_v    = (const float*)d_in[30];
    const float* w_f2     = (const float*)d_in[31];
    const float* bn2_g    = (const float*)d_in[32];
    const float* bn2_b    = (const float*)d_in[33];
    const float* bn2_m    = (const float*)d_in[34];
    const float* bn2_v    = (const float*)d_in[35];
    const float* w_sg1    = (const float*)d_in[36];
    const float* w_sg2    = (const float*)d_in[37];
    const float* b_sg2    = (const float*)d_in[38];
    const float* ln2_g    = (const float*)d_in[39];
    const float* ln2_b    = (const float*)d_in[40];
    const float* w_fc1    = (const float*)d_in[41];
    const float* b_fc1    = (const float*)d_in[42];
    const float* w_fc2    = (const float*)d_in[43];
    const float* b_fc2    = (const float*)d_in[44];

    char* wsb = (char*)d_ws;
    float* out = (float*)d_out;

    bf16*  sp_out = (bf16*)(wsb + OFF_SPOUT);
    bf16*  ch_out = (bf16*)(wsb + OFF_CHOUT);
    bf16*  qkv_b  = (bf16*)(wsb + OFF_QKVB);
    bf16*  osp_b  = (bf16*)(wsb + OFF_OSPB);
    float* stats1 = (float*)(wsb + OFF_STATS1);
    float* stats2 = (float*)(wsb + OFF_STATS2);
    float* rnorm  = (float*)(wsb + OFF_RNORM);
    float* attn_b = (float*)(wsb + OFF_ATTNB);
    float* mean_sp= (float*)(wsb + OFF_MEANSP);
    float* mean_ch= (float*)(wsb + OFF_MEANCH);
    float* gate_s = (float*)(wsb + OFF_GATES);
    float* gate_c = (float*)(wsb + OFF_GATEC);
    float* Wc_sp  = (float*)(wsb + OFF_WCSP);
    float* bc_sp  = (float*)(wsb + OFF_BCSP);
    float* Wc_ch  = (float*)(wsb + OFF_WCCH);
    float* bc_ch  = (float*)(wsb + OFF_BCCH);
    bf16*  hid_s  = (bf16*)(wsb + OFF_PH2);
    bf16*  hid_c  = (bf16*)(wsb + OFF_PH2 + 12582912);
    bf16*  f      = (bf16*)(wsb + OFF_PH2);
    bf16*  f2     = (bf16*)(wsb + OFF_SPOUT);
    bf16*  gpre   = (bf16*)(wsb + OFF_CHOUT);
    bf16*  hidden = (bf16*)(wsb + OFF_PH2);

    const dim3 blk(256);

    // weight combiners
    combine_sp_k<<<192, 128, 0, stream>>>(w_sp_proj, w_spp, b_spp, Wc_sp, bc_sp);
    combine_ch_k<<<192, 64, 0, stream>>>(w_ch_proj, w_chp, b_chp, Wc_ch, bc_ch);

    // LN1 stats (full M)
    ln_stats_k<<<MTOK/4, blk, 0, stream>>>(x, stats1);

    // per-batch: qkv GEMM -> spatial attn -> sp proj (roll store) -> channel attn
    for (int b = 0; b < BATCH; ++b) {
        gemm_k<1,0,0,0,1><<<dim3(QKVC/BN, HW/BM), blk, 0, stream>>>(
            x + (size_t)b*HW*CCH, w_qkv, b_qkv, qkv_b, HW, QKVC, CCH,
            stats1 + (size_t)b*HW*2, ln1_g, ln1_b, nullptr,
            nullptr, nullptr, nullptr, nullptr, 0, b);

        sp_attn_k<<<dim3(SPH, NWIN), blk, 0, stream>>>(qkv_b, rpb, logit_sp, osp_b);

        gemm_k<0,2,0,1,1><<<dim3(CCH/BN, HW/BM), blk, 0, stream>>>(
            osp_b, Wc_sp, bc_sp, sp_out, HW, CCH, 144,
            nullptr, nullptr, nullptr, nullptr,
            nullptr, nullptr, nullptr, nullptr, 0, b);

        ch_norm_k<<<dim3(48, 2), blk, 0, stream>>>(qkv_b, rnorm);
        ch_attn_k<<<dim3(24, 2), blk, 0, stream>>>(qkv_b, rnorm, logit_ch, attn_b);
        ch_out_k<<<dim3(HW/64), blk, 0, stream>>>(qkv_b, attn_b, Wc_ch, bc_ch,
                                                  ch_out + (size_t)b*HW*CCH);
    }

    // CFCA: means, gates
    mean_k<<<dim3(CCH, BATCH), blk, 0, stream>>>(sp_out, mean_sp);
    mean_k<<<dim3(CCH, BATCH), blk, 0, stream>>>(ch_out, mean_ch);
    gates_k<<<BATCH, 192, 0, stream>>>(mean_sp, w_gs1, w_gs2, b_gs2, gate_s);
    gates_k<<<BATCH, 192, 0, stream>>>(mean_ch, w_gc1, w_gc2, b_gc2, gate_c);

    // CFCA hidden layers (relu), full M
    gemm_k<0,1,0,1,1><<<dim3(1, MTOK/BM), blk, 0, stream>>>(
        sp_out, w_s2c1, nullptr, hid_s, MTOK, MIDC, CCH,
        nullptr, nullptr, nullptr, nullptr, nullptr, nullptr, nullptr, nullptr, 0, 0);
    gemm_k<0,1,0,1,1><<<dim3(1, MTOK/BM), blk, 0, stream>>>(
        ch_out, w_c2s1, nullptr, hid_c, MTOK, MIDC, CCH,
        nullptr, nullptr, nullptr, nullptr, nullptr, nullptr, nullptr, nullptr, 0, 0);
    // gated residual adds: ch_out += (hid_s@w2+b)*gate_s ; sp_out += (hid_c@w2+b)*gate_c
    gemm_k<0,4,0,1,1><<<dim3(CCH/BN, MTOK/BM), blk, 0, stream>>>(
        hid_s, w_s2c2, b_s2c2, ch_out, MTOK, CCH, MIDC,
        nullptr, nullptr, nullptr, nullptr, gate_s, nullptr, nullptr, nullptr, 0, 0);
    gemm_k<0,4,0,1,1><<<dim3(CCH/BN, MTOK/BM), blk, 0, stream>>>(
        hid_c, w_c2s2, b_c2s2, sp_out, MTOK, CCH, MIDC,
        nullptr, nullptr, nullptr, nullptr, gate_c, nullptr, nullptr, nullptr, 0, 0);

    // f = relu(bn1(concat(spf,chf) @ w_f1^T))
    gemm_k<2,3,0,1,1><<<dim3(CCH/BN, MTOK/BM), blk, 0, stream>>>(
        sp_out, w_f1, nullptr, f, MTOK, CCH, 2*CCH,
        nullptr, nullptr, nullptr, ch_out, bn1_g, bn1_b, bn1_m, bn1_v, 0, 0);

    // f2 = relu(bn2(conv3x3(f, w_f2)))   (writes over dead sp_out region)
    gemm_k<3,3,1,1,1><<<dim3(CCH/BN, MTOK/BM), blk, 0, stream>>>(
        f, w_f2, nullptr, f2, MTOK, CCH, 9*CCH,
        nullptr, nullptr, nullptr, nullptr, bn2_g, bn2_b, bn2_m, bn2_v, CCH, 0);

    // gpre = conv3x3(f2, w_sg1)  (96 ch; writes over dead ch_out region)
    gemm_k<3,0,1,1,1><<<dim3(2, MTOK/BM), blk, 0, stream>>>(
        f2, w_sg1, nullptr, gpre, MTOK, 96, 9*CCH,
        nullptr, nullptr, nullptr, nullptr, nullptr, nullptr, nullptr, nullptr, CCH, 0);

    // xnew = x + f2*(1+g) -> d_out
    fuse_k<<<MTOK/4, blk, 0, stream>>>(x, f2, gpre, w_sg2, b_sg2, out);

    // LN2 stats + MLP (chunked over tokens; hidden reuses dead f region)
    ln_stats_k<<<MTOK/4, blk, 0, stream>>>(out, stats2);
    const int CHM = MTOK / 4;  // 32768 tokens per chunk
    for (int c0 = 0; c0 < MTOK; c0 += CHM) {
        gemm_k<1,5,0,0,1><<<dim3(768/BN, CHM/BM), blk, 0, stream>>>(
            out + (size_t)c0*CCH, w_fc1, b_fc1, hidden, CHM, 4*CCH, CCH,
            stats2 + (size_t)c0*2, ln2_g, ln2_b, nullptr,
            nullptr, nullptr, nullptr, nullptr, 0, 0);
        gemm_k<0,6,0,1,0><<<dim3(CCH/BN, CHM/BM), blk, 0, stream>>>(
            hidden, w_fc2, b_fc2, out + (size_t)c0*CCH, CHM, CCH, 4*CCH,
            nullptr, nullptr, nullptr, nullptr, out + (size_t)c0*CCH,
            nullptr, nullptr, nullptr, 0, 0);
    }
}

// Round 3
// 3992.471 us; speedup vs baseline: 2.1395x; 2.1395x over previous
//
#include <hip/hip_runtime.h>
#include <hip/hip_bf16.h>
#include <cstddef>

typedef __hip_bfloat16 bf16;
typedef unsigned short u16;
typedef short s16x8 __attribute__((ext_vector_type(8)));
typedef float f32x4 __attribute__((ext_vector_type(4)));

// ---------------- problem constants ----------------
#define BATCH 8
#define HR 128
#define WR 128
#define CCH 192
#define HW (HR*WR)            // 16384
#define MTOK (BATCH*HW)       // 131072
#define SPH 6
#define QKVC (3*CCH)          // 576
#define NWIN 256
#define MIDC 48
#define LOGMAX 4.6051701859880914f  // log(100)

// ---------------- ws layout (BYTE offsets; peak ~177 MB) ----------------
static const size_t OFF_SPOUT  = 0;                    // bf16 M*192 (later reused: f2)
static const size_t OFF_CHOUT  = 50331648;             // bf16 M*192 (later reused: gpre)
static const size_t OFF_QKVB   = 100663296;            // bf16 HW*576 (per-batch)
static const size_t OFF_OSPB   = 119537664;            // bf16 HW*144 (per-batch)
static const size_t OFF_STATS1 = 124256256;            // fp32 2*M
static const size_t OFF_STATS2 = 125304832;            // fp32 2*M
static const size_t OFF_RNORM  = 126353408;            // fp32 96 (per-batch)
static const size_t OFF_ATTNB  = 126353920;            // fp32 1152 (per-batch)
static const size_t OFF_MEANSP = 126359040;
static const size_t OFF_MEANCH = 126365184;
static const size_t OFF_GATES  = 126371328;
static const size_t OFF_GATEC  = 126377472;
static const size_t OFF_WCSP   = 126383616;            // fp32 192*144
static const size_t OFF_BCSP   = 126494208;
static const size_t OFF_WCCH   = 126495232;            // fp32 192*48
static const size_t OFF_BCCH   = 126532096;
static const size_t OFF_PH2    = 126533632;            // phase-2/3 region

__device__ __forceinline__ float b2f(bf16 x) { return __bfloat162float(x); }
__device__ __forceinline__ bf16  f2b(float x){ return __float2bfloat16(x); }
__device__ __forceinline__ u16   f2u(float x){
    bf16 h = __float2bfloat16(x);
    union { bf16 b; u16 u; } c; c.b = h; return c.u;
}

// =====================================================================
// MFMA bf16 GEMM: C[M,N] = epi(A'[M,K] @ W[N,K]^T + bias)
// block 256 thr = 4 waves (2x2), tile BM=128 x BN=64, BK=32 (one MFMA K-step).
// Fragment layout (m89-verified): operand frag [dim16 = lane&15][k = (lane>>4)*8+i],
// C/D: col = lane&15, row = (lane>>4)*4 + reg.
// AMODE: 0 plain, 1 LN-fused (A fp32), 2 concat(A|A2), 3 implicit 3x3 conv
// WMODE: 0 row-major [N][K] fp32, 1 conv weights (O,I,3,3) fp32
// EPI: 0 bias, 1 relu, 2 roll(+4,+4)-store (per-batch), 3 BN+relu,
//      4 gated residual (C += v*gate[b]), 5 gelu, 6 residual add (fp32 ep0)
// ABF: A (and A2) bf16?   CBF: C bf16?
// Requirements: M % 128 == 0, K % 8 == 0.
// =====================================================================
#define GBM 128
#define GBN 64
#define GBK 32
#define LDA 40   // padded row length in ushorts (80 B -> no excess bank conflicts)

template<int AMODE, int EPI, int WMODE, int ABF, int CBF>
__global__ __launch_bounds__(256)
void gemm_k(const void* __restrict__ A, const float* __restrict__ W,
            const float* __restrict__ bias, void* __restrict__ Cv,
            int M, int N, int K,
            const float* __restrict__ stats, const float* __restrict__ lng,
            const float* __restrict__ lnb, const void* __restrict__ A2,
            const float* __restrict__ ep0, const float* __restrict__ ep1,
            const float* __restrict__ ep2, const float* __restrict__ ep3,
            int cin, int batch)
{
    __shared__ u16 As[GBM * LDA];   // 10240 B
    __shared__ u16 Bs[GBN * LDA];   // 5120 B

    const int tid  = threadIdx.x;
    const int lane = tid & 63;
    const int wid  = tid >> 6;
    const int wm   = (wid >> 1) * 64;
    const int wn   = (wid & 1) * 32;
    const int m0   = blockIdx.y * GBM;
    const int n0   = blockIdx.x * GBN;
    const int row16 = lane & 15;
    const int koff  = (lane >> 4) * 8;

    f32x4 acc[4][2];
    #pragma unroll
    for (int mf = 0; mf < 4; ++mf)
        #pragma unroll
        for (int nf = 0; nf < 2; ++nf)
            acc[mf][nf] = (f32x4){0.f, 0.f, 0.f, 0.f};

    const int nsteps = (K + GBK - 1) / GBK;
    for (int step = 0; step < nsteps; ++step) {
        const int k0 = step * GBK;
        // ---- stage A (128 x 32): 512 segments of 8 bf16, 2 per thread ----
        #pragma unroll
        for (int it = 0; it < 2; ++it) {
            const int s  = tid + it * 256;
            const int r  = s >> 2;
            const int kk = (s & 3) * 8;
            const int m  = m0 + r;
            const int k  = k0 + kk;
            union { u16 u[8]; uint4 v; } pk;
            if (k < K) {
                if constexpr (AMODE == 0) {
                    if constexpr (ABF) {
                        pk.v = *(const uint4*)((const u16*)A + (size_t)m * K + k);
                    } else {
                        const float* p = (const float*)A + (size_t)m * K + k;
                        #pragma unroll
                        for (int j = 0; j < 8; ++j) pk.u[j] = f2u(p[j]);
                    }
                } else if constexpr (AMODE == 1) {
                    const float mean = stats[2*m], rstd = stats[2*m+1];
                    const float* p = (const float*)A + (size_t)m * K + k;
                    #pragma unroll
                    for (int j = 0; j < 8; ++j)
                        pk.u[j] = f2u((p[j] - mean) * rstd * lng[k+j] + lnb[k+j]);
                } else if constexpr (AMODE == 2) {
                    const u16* src = (k < CCH) ? (const u16*)A  + (size_t)m * CCH + k
                                               : (const u16*)A2 + (size_t)m * CCH + (k - CCH);
                    pk.v = *(const uint4*)src;
                } else { // implicit 3x3 conv, bf16 source
                    const int t = k / cin, c = k - t * cin;
                    const int ky = t / 3, kx = t - ky * 3;
                    const int b = m >> 14, pix = m & 16383;
                    const int h = (pix >> 7) + ky - 1;
                    const int w = (pix & 127) + kx - 1;
                    if (h >= 0 && h < HR && w >= 0 && w < WR) {
                        pk.v = *(const uint4*)((const u16*)A +
                                ((size_t)(b * HW) + h * WR + w) * (size_t)cin + c);
                    } else {
                        pk.v = (uint4){0u,0u,0u,0u};
                    }
                }
            } else {
                pk.v = (uint4){0u,0u,0u,0u};
            }
            *(uint4*)&As[r * LDA + kk] = pk.v;
        }
        // ---- stage B (64 x 32): 256 segments of 8, 1 per thread ----
        {
            const int r  = tid >> 2;
            const int kk = (tid & 3) * 8;
            const int n  = n0 + r;
            const int k  = k0 + kk;
            union { u16 u[8]; uint4 v; } pk;
            pk.v = (uint4){0u,0u,0u,0u};
            if (k < K && n < N) {
                if constexpr (WMODE == 0) {
                    const float* p = W + (size_t)n * K + k;
                    #pragma unroll
                    for (int j = 0; j < 8; ++j) pk.u[j] = f2u(p[j]);
                } else {
                    const int t = k / cin, c = k - t * cin;
                    #pragma unroll
                    for (int j = 0; j < 8; ++j)
                        pk.u[j] = f2u(W[((size_t)n * cin + c + j) * 9 + t]);
                }
            }
            *(uint4*)&Bs[r * LDA + kk] = pk.v;
        }
        __syncthreads();
        // ---- MFMA: each wave computes a 64x32 sub-tile ----
        {
            s16x8 af[4], bf[2];
            #pragma unroll
            for (int mf = 0; mf < 4; ++mf)
                af[mf] = *(const s16x8*)&As[(wm + mf*16 + row16) * LDA + koff];
            #pragma unroll
            for (int nf = 0; nf < 2; ++nf)
                bf[nf] = *(const s16x8*)&Bs[(wn + nf*16 + row16) * LDA + koff];
            #pragma unroll
            for (int mf = 0; mf < 4; ++mf)
                #pragma unroll
                for (int nf = 0; nf < 2; ++nf)
                    acc[mf][nf] = __builtin_amdgcn_mfma_f32_16x16x32_bf16(
                        af[mf], bf[nf], acc[mf][nf], 0, 0, 0);
        }
        __syncthreads();
    }

    // ---- epilogue ----
    #pragma unroll
    for (int mf = 0; mf < 4; ++mf) {
        #pragma unroll
        for (int nf = 0; nf < 2; ++nf) {
            const int n = n0 + wn + nf*16 + row16;
            if (n >= N) continue;
            #pragma unroll
            for (int r = 0; r < 4; ++r) {
                const int m = m0 + wm + mf*16 + (lane >> 4)*4 + r;
                float v = acc[mf][nf][r] + (bias ? bias[n] : 0.f);
                size_t outIdx;
                if constexpr (EPI == 2) {
                    const int h2 = ((m >> 7) + 4) & 127;
                    const int w2 = ((m & 127) + 4) & 127;
                    outIdx = ((size_t)(batch * HW) + h2 * WR + w2) * (size_t)N + n;
                } else {
                    outIdx = (size_t)m * N + n;
                }
                if constexpr (EPI == 1) {
                    v = fmaxf(v, 0.f);
                } else if constexpr (EPI == 3) {
                    v = (v - ep2[n]) * rsqrtf(ep3[n] + 1e-5f) * ep0[n] + ep1[n];
                    v = fmaxf(v, 0.f);
                } else if constexpr (EPI == 4) {
                    const int b = m >> 14;
                    const float cold = CBF ? b2f(((const bf16*)Cv)[outIdx])
                                           : ((const float*)Cv)[outIdx];
                    v = cold + v * ep0[b * N + n];
                } else if constexpr (EPI == 5) {
                    v = 0.5f * v * (1.f + erff(v * 0.70710678118654752f));
                } else if constexpr (EPI == 6) {
                    v = ep0[outIdx] + v;
                }
                if constexpr (CBF) ((bf16*)Cv)[outIdx] = f2b(v);
                else               ((float*)Cv)[outIdx] = v;
            }
        }
    }
}

// =====================================================================
// LN stats: per token mean & rstd
// =====================================================================
__global__ __launch_bounds__(256)
void ln_stats_k(const float* __restrict__ x, float* __restrict__ stats)
{
    const int tok = blockIdx.x * 4 + (threadIdx.x >> 6);
    const int lane = threadIdx.x & 63;
    const float* r = x + (size_t)tok * CCH;
    float s = 0.f, sq = 0.f;
    for (int c = lane; c < CCH; c += 64) { float v = r[c]; s += v; sq += v*v; }
    for (int m = 1; m < 64; m <<= 1) { s += __shfl_xor(s, m); sq += __shfl_xor(sq, m); }
    if (lane == 0) {
        const float mean = s / (float)CCH;
        const float var = sq / (float)CCH - mean * mean;
        stats[(size_t)tok*2]   = mean;
        stats[(size_t)tok*2+1] = rsqrtf(var + 1e-5f);
    }
}

// =====================================================================
// Spatial shifted-window cosine attention, one batch (heads 0..5)
// =====================================================================
__global__ __launch_bounds__(256)
void sp_attn_k(const bf16* __restrict__ qkv, const float* __restrict__ rpb,
               const float* __restrict__ logit_sp, bf16* __restrict__ o)
{
    const int head = blockIdx.x;
    const int win  = blockIdx.y;
    const int wh = win >> 4, ww = win & 15;
    const int tid = threadIdx.x;

    __shared__ float q[64][25], k[64][25], v[64][25];
    __shared__ float attn[64][66];
    __shared__ float rq[64], rk[64];
    __shared__ int   lab[64];
    __shared__ float scale_s;

    for (int idx = tid; idx < 64*24*3; idx += 256) {
        const int which = idx / 1536;
        const int rem = idx - which * 1536;
        const int p = rem / 24, d = rem - (rem/24)*24;
        const int h = (wh*8 + (p >> 3) + 4) & 127;
        const int w = (ww*8 + (p & 7)  + 4) & 127;
        const float val = b2f(qkv[((size_t)(h*WR + w)) * QKVC + head*72 + which*24 + d]);
        if (which == 0) q[p][d] = val;
        else if (which == 1) k[p][d] = val;
        else v[p][d] = val;
    }
    if (tid == 0) scale_s = expf(fminf(logit_sp[head], LOGMAX));
    __syncthreads();

    if (tid < 64) {
        float s = 0.f;
        #pragma unroll
        for (int d = 0; d < 24; ++d) s += q[tid][d]*q[tid][d];
        rq[tid] = 1.f / fmaxf(sqrtf(s), 1e-12f);
        const int h = wh*8 + (tid >> 3), w = ww*8 + (tid & 7);
        const int rh = h < 120 ? 0 : (h < 124 ? 1 : 2);
        const int rw = w < 120 ? 0 : (w < 124 ? 1 : 2);
        lab[tid] = rh*3 + rw;
    } else if (tid < 128) {
        const int i = tid - 64;
        float s = 0.f;
        #pragma unroll
        for (int d = 0; d < 24; ++d) s += k[i][d]*k[i][d];
        rk[i] = 1.f / fmaxf(sqrtf(s), 1e-12f);
    }
    __syncthreads();

    for (int e = tid; e < 4096; e += 256) {
        const int i = e >> 6, j = e & 63;
        float s = 0.f;
        #pragma unroll
        for (int d = 0; d < 24; ++d) s += q[i][d]*k[j][d];
        s = s * rq[i] * rk[j] * scale_s;
        const int r0 = (i >> 3) - (j >> 3) + 7;
        const int r1 = (i & 7) - (j & 7) + 7;
        s += rpb[(r0*15 + r1)*SPH + head];
        if (lab[i] != lab[j]) s -= 100.f;
        attn[i][j] = s;
    }
    __syncthreads();

    { // softmax, 4 lanes per row
        const int r = tid >> 2, l = tid & 3;
        float mx = -1e30f;
        for (int j = l; j < 64; j += 4) mx = fmaxf(mx, attn[r][j]);
        mx = fmaxf(mx, __shfl_xor(mx, 1));
        mx = fmaxf(mx, __shfl_xor(mx, 2));
        float sum = 0.f;
        for (int j = l; j < 64; j += 4) { float e2 = expf(attn[r][j] - mx); attn[r][j] = e2; sum += e2; }
        sum += __shfl_xor(sum, 1);
        sum += __shfl_xor(sum, 2);
        const float inv = 1.f / sum;
        for (int j = l; j < 64; j += 4) attn[r][j] *= inv;
    }
    __syncthreads();

    for (int idx = tid; idx < 64*24; idx += 256) {
        const int i = idx / 24, d = idx - (idx/24)*24;
        float s = 0.f;
        #pragma unroll
        for (int j = 0; j < 64; ++j) s += attn[i][j] * v[j][d];
        const int h = wh*8 + (i >> 3), w = ww*8 + (i & 7);
        o[((size_t)(h*WR + w)) * 144 + head*24 + d] = f2b(s);
    }
}

// =====================================================================
// Channel attention, one batch (heads 6,7)
// =====================================================================
__global__ __launch_bounds__(256)
void ch_norm_k(const bf16* __restrict__ qkv, float* __restrict__ rnorm)
{
    const int c = blockIdx.x;     // 0..47 (q:0-23, k:24-47)
    const int head = blockIdx.y;  // 0..1
    const bf16* base = qkv + (6 + head) * 72 + c;
    float s = 0.f;
    for (int i = threadIdx.x; i < HW; i += 256) { const float v = b2f(base[(size_t)i * QKVC]); s += v*v; }
    __shared__ float red[256];
    red[threadIdx.x] = s; __syncthreads();
    for (int st = 128; st > 0; st >>= 1) { if (threadIdx.x < st) red[threadIdx.x] += red[threadIdx.x + st]; __syncthreads(); }
    if (threadIdx.x == 0) rnorm[head*48 + c] = 1.f / fmaxf(sqrtf(red[0]), 1e-12f);
}

__global__ __launch_bounds__(256)
void ch_attn_k(const bf16* __restrict__ qkv, const float* __restrict__ rnorm,
               const float* __restrict__ logit_ch, float* __restrict__ attn_ch)
{
    const int c = blockIdx.x;     // q row 0..23
    const int head = blockIdx.y;
    const bf16* base = qkv + (6 + head) * 72;
    float acc[24];
    #pragma unroll
    for (int d = 0; d < 24; ++d) acc[d] = 0.f;
    for (int i = threadIdx.x; i < HW; i += 256) {
        const bf16* row = base + (size_t)i * QKVC;
        const float qv = b2f(row[c]);
        #pragma unroll
        for (int d = 0; d < 24; ++d) acc[d] += qv * b2f(row[24 + d]);
    }
    __shared__ float red[256];
    __shared__ float rowv[24];
    for (int d = 0; d < 24; ++d) {
        red[threadIdx.x] = acc[d]; __syncthreads();
        for (int st = 128; st > 0; st >>= 1) { if (threadIdx.x < st) red[threadIdx.x] += red[threadIdx.x + st]; __syncthreads(); }
        if (threadIdx.x == 0) rowv[d] = red[0];
        __syncthreads();
    }
    if (threadIdx.x == 0) {
        const float scale = expf(fminf(logit_ch[head], LOGMAX));
        const float* rn = rnorm + head*48;
        float vals[24], mx = -1e30f;
        #pragma unroll
        for (int d = 0; d < 24; ++d) { vals[d] = rowv[d]*rn[c]*rn[24+d]*scale; mx = fmaxf(mx, vals[d]); }
        float sum = 0.f;
        #pragma unroll
        for (int d = 0; d < 24; ++d) { vals[d] = expf(vals[d] - mx); sum += vals[d]; }
        const float inv = 1.f / sum;
        float* out = attn_ch + ((size_t)head*24 + c)*24;
        #pragma unroll
        for (int d = 0; d < 24; ++d) out[d] = vals[d]*inv;
    }
}

__global__ __launch_bounds__(256)
void ch_out_k(const bf16* __restrict__ qkv, const float* __restrict__ attn_ch,
              const float* __restrict__ Wc, const float* __restrict__ bc,
              bf16* __restrict__ ch_out)
{
    const int pix0 = blockIdx.x * 64;
    const int tid = threadIdx.x;
    __shared__ float A2s[2][24][24];
    __shared__ float Wcs[192][48];
    __shared__ float bcs[192];
    __shared__ float vbuf[64][48];
    __shared__ float ocb[64][49];

    for (int idx = tid; idx < 2*24*24; idx += 256) {
        const int hh = idx / 576, rem = idx - hh*576;
        A2s[hh][rem/24][rem%24] = attn_ch[idx];
    }
    for (int idx = tid; idx < 192*48; idx += 256) Wcs[idx/48][idx%48] = Wc[idx];
    if (tid < 192) bcs[tid] = bc[tid];
    for (int idx = tid; idx < 64*48; idx += 256) {
        const int p = idx / 48, c = idx - (idx/48)*48;
        const int head = c / 24, d = c - head*24;
        vbuf[p][c] = b2f(qkv[((size_t)(pix0 + p)) * QKVC + (6 + head)*72 + 48 + d]);
    }
    __syncthreads();
    for (int idx = tid; idx < 64*48; idx += 256) {
        const int p = idx / 48, c = idx - (idx/48)*48;
        const int head = c / 24, cc = c - head*24;
        float s = 0.f;
        #pragma unroll
        for (int d = 0; d < 24; ++d) s += A2s[head][cc][d] * vbuf[p][head*24 + d];
        ocb[p][c] = s;
    }
    __syncthreads();
    for (int idx = tid; idx < 64*192; idx += 256) {
        const int p = idx / 192, n = idx - (idx/192)*192;
        float s = bcs[n];
        #pragma unroll
        for (int c = 0; c < 48; ++c) s += ocb[p][c] * Wcs[n][c];
        ch_out[((size_t)(pix0 + p)) * CCH + n] = f2b(s);
    }
}

// =====================================================================
// weight combiners
// =====================================================================
__global__ void combine_sp_k(const float* __restrict__ w_sp_proj, const float* __restrict__ w_spp,
                             const float* __restrict__ b_spp, float* __restrict__ Wc, float* __restrict__ bc)
{
    const int n = blockIdx.x; // 0..191
    for (int i = threadIdx.x; i < 144; i += blockDim.x) {
        float s = 0.f;
        for (int j = 0; j < 144; ++j) s += w_sp_proj[n*144 + j] * w_spp[j*144 + i];
        Wc[n*144 + i] = s;
    }
    if (threadIdx.x == 0) {
        float s = 0.f;
        for (int j = 0; j < 144; ++j) s += w_sp_proj[n*144 + j] * b_spp[j];
        bc[n] = s;
    }
}

__global__ void combine_ch_k(const float* __restrict__ w_ch_proj, const float* __restrict__ w_chp,
                             const float* __restrict__ b_chp, float* __restrict__ Wc, float* __restrict__ bc)
{
    const int n = blockIdx.x; // 0..191
    for (int c = threadIdx.x; c < 48; c += blockDim.x) {
        float s = 0.f;
        for (int j = 0; j < 48; ++j) s += w_ch_proj[n*48 + j] * w_chp[j*48 + c];
        Wc[n*48 + c] = s;
    }
    if (threadIdx.x == 0) {
        float s = 0.f;
        for (int j = 0; j < 48; ++j) s += w_ch_proj[n*48 + j] * b_chp[j];
        bc[n] = s;
    }
}

// =====================================================================
// per-(b,c) mean over H,W (bf16 src)
// =====================================================================
__global__ __launch_bounds__(256)
void mean_k(const bf16* __restrict__ src, float* __restrict__ dst)
{
    const int c = blockIdx.x, b = blockIdx.y;
    const bf16* base = src + (size_t)b * HW * CCH + c;
    float s = 0.f;
    for (int i = threadIdx.x; i < HW; i += 256) s += b2f(base[(size_t)i * CCH]);
    __shared__ float red[256];
    red[threadIdx.x] = s; __syncthreads();
    for (int st = 128; st > 0; st >>= 1) { if (threadIdx.x < st) red[threadIdx.x] += red[threadIdx.x + st]; __syncthreads(); }
    if (threadIdx.x == 0) dst[b*CCH + c] = red[0] / (float)HW;
}

// gate = sigmoid(relu(mean @ w1^T) @ w2^T + b2)
__global__ __launch_bounds__(192)
void gates_k(const float* __restrict__ meanv, const float* __restrict__ w1,
             const float* __restrict__ w2, const float* __restrict__ b2,
             float* __restrict__ gate)
{
    const int b = blockIdx.x;
    __shared__ float mv[192], hid[48];
    const int t = threadIdx.x;
    mv[t] = meanv[b*CCH + t];
    __syncthreads();
    if (t < 48) {
        float s = 0.f;
        for (int c = 0; c < 192; ++c) s += w1[t*192 + c] * mv[c];
        hid[t] = fmaxf(s, 0.f);
    }
    __syncthreads();
    float s = b2[t];
    for (int j = 0; j < 48; ++j) s += hid[j] * w2[t*48 + j];
    gate[b*CCH + t] = 1.f / (1.f + expf(-s));
}

// =====================================================================
// out = x + f2 * (1 + sigmoid(relu(gpre)@w_sg2 + b))
// =====================================================================
__global__ __launch_bounds__(256)
void fuse_k(const float* __restrict__ x, const bf16* __restrict__ f2,
            const bf16* __restrict__ gpre, const float* __restrict__ w_sg2,
            const float* __restrict__ b_sg2, float* __restrict__ out)
{
    const int pix = blockIdx.x * 4 + (threadIdx.x >> 6);
    const int lane = threadIdx.x & 63;
    const bf16* gp = gpre + (size_t)pix * 96;
    float s = fmaxf(b2f(gp[lane]), 0.f) * w_sg2[lane];
    if (lane < 32) s += fmaxf(b2f(gp[lane + 64]), 0.f) * w_sg2[lane + 64];
    for (int m = 1; m < 64; m <<= 1) s += __shfl_xor(s, m);
    const float g1 = 1.f + 1.f / (1.f + expf(-(s + b_sg2[0])));
    const float* xr = x  + (size_t)pix * CCH;
    const bf16* fr = f2 + (size_t)pix * CCH;
    float* orow = out + (size_t)pix * CCH;
    for (int c = lane; c < CCH; c += 64) orow[c] = xr[c] + b2f(fr[c]) * g1;
}

// =====================================================================
// launcher
// =====================================================================
extern "C" void kernel_launch(void* const* d_in, const int* in_sizes, int n_in,
                              void* d_out, int out_size, void* d_ws, size_t ws_size,
                              hipStream_t stream)
{
    const float* x        = (const float*)d_in[0];
    const float* ln1_g    = (const float*)d_in[1];
    const float* ln1_b    = (const float*)d_in[2];
    const float* w_qkv    = (const float*)d_in[3];
    const float* b_qkv    = (const float*)d_in[4];
    const float* logit_sp = (const float*)d_in[5];
    const float* rpb      = (const float*)d_in[6];
    const float* w_spp    = (const float*)d_in[7];
    const float* b_spp    = (const float*)d_in[8];
    const float* logit_ch = (const float*)d_in[9];
    const float* w_chp    = (const float*)d_in[10];
    const float* b_chp    = (const float*)d_in[11];
    const float* w_sp_proj= (const float*)d_in[12];
    const float* w_ch_proj= (const float*)d_in[13];
    const float* w_s2c1   = (const float*)d_in[14];
    const float* w_s2c2   = (const float*)d_in[15];
    const float* b_s2c2   = (const float*)d_in[16];
    const float* w_c2s1   = (const float*)d_in[17];
    const float* w_c2s2   = (const float*)d_in[18];
    const float* b_c2s2   = (const float*)d_in[19];
    const float* w_gs1    = (const float*)d_in[20];
    const float* w_gs2    = (const float*)d_in[21];
    const float* b_gs2    = (const float*)d_in[22];
    const float* w_gc1    = (const float*)d_in[23];
    const float* w_gc2    = (const float*)d_in[24];
    const float* b_gc2    = (const float*)d_in[25];
    const float* w_f1     = (const float*)d_in[26];
    const float* bn1_g    = (const float*)d_in[27];
    const float* bn1_b    = (const float*)d_in[28];
    const float* bn1_m    = (const float*)d_in[29];
    const float* bn1_v    = (const float*)d_in[30];
    const float* w_f2     = (const float*)d_in[31];
    const float* bn2_g    = (const float*)d_in[32];
    const float* bn2_b    = (const float*)d_in[33];
    const float* bn2_m    = (const float*)d_in[34];
    const float* bn2_v    = (const float*)d_in[35];
    const float* w_sg1    = (const float*)d_in[36];
    const float* w_sg2    = (const float*)d_in[37];
    const float* b_sg2    = (const float*)d_in[38];
    const float* ln2_g    = (const float*)d_in[39];
    const float* ln2_b    = (const float*)d_in[40];
    const float* w_fc1    = (const float*)d_in[41];
    const float* b_fc1    = (const float*)d_in[42];
    const float* w_fc2    = (const float*)d_in[43];
    const float* b_fc2    = (const float*)d_in[44];

    char* wsb = (char*)d_ws;
    float* out = (float*)d_out;

    bf16*  sp_out = (bf16*)(wsb + OFF_SPOUT);
    bf16*  ch_out = (bf16*)(wsb + OFF_CHOUT);
    bf16*  qkv_b  = (bf16*)(wsb + OFF_QKVB);
    bf16*  osp_b  = (bf16*)(wsb + OFF_OSPB);
    float* stats1 = (float*)(wsb + OFF_STATS1);
    float* stats2 = (float*)(wsb + OFF_STATS2);
    float* rnorm  = (float*)(wsb + OFF_RNORM);
    float* attn_b = (float*)(wsb + OFF_ATTNB);
    float* mean_sp= (float*)(wsb + OFF_MEANSP);
    float* mean_ch= (float*)(wsb + OFF_MEANCH);
    float* gate_s = (float*)(wsb + OFF_GATES);
    float* gate_c = (float*)(wsb + OFF_GATEC);
    float* Wc_sp  = (float*)(wsb + OFF_WCSP);
    float* bc_sp  = (float*)(wsb + OFF_BCSP);
    float* Wc_ch  = (float*)(wsb + OFF_WCCH);
    float* bc_ch  = (float*)(wsb + OFF_BCCH);
    bf16*  hid_s  = (bf16*)(wsb + OFF_PH2);
    bf16*  hid_c  = (bf16*)(wsb + OFF_PH2 + 12582912);
    bf16*  f      = (bf16*)(wsb + OFF_PH2);
    bf16*  f2     = (bf16*)(wsb + OFF_SPOUT);
    bf16*  gpre   = (bf16*)(wsb + OFF_CHOUT);
    bf16*  hidden = (bf16*)(wsb + OFF_PH2);

    const dim3 blk(256);

    // weight combiners
    combine_sp_k<<<192, 128, 0, stream>>>(w_sp_proj, w_spp, b_spp, Wc_sp, bc_sp);
    combine_ch_k<<<192, 64, 0, stream>>>(w_ch_proj, w_chp, b_chp, Wc_ch, bc_ch);

    // LN1 stats (full M)
    ln_stats_k<<<MTOK/4, blk, 0, stream>>>(x, stats1);

    // per-batch: qkv GEMM -> spatial attn -> sp proj (roll store) -> channel attn
    for (int b = 0; b < BATCH; ++b) {
        gemm_k<1,0,0,0,1><<<dim3(QKVC/GBN, HW/GBM), blk, 0, stream>>>(
            x + (size_t)b*HW*CCH, w_qkv, b_qkv, qkv_b, HW, QKVC, CCH,
            stats1 + (size_t)b*HW*2, ln1_g, ln1_b, nullptr,
            nullptr, nullptr, nullptr, nullptr, 0, b);

        sp_attn_k<<<dim3(SPH, NWIN), blk, 0, stream>>>(qkv_b, rpb, logit_sp, osp_b);

        gemm_k<0,2,0,1,1><<<dim3(CCH/GBN, HW/GBM), blk, 0, stream>>>(
            osp_b, Wc_sp, bc_sp, sp_out, HW, CCH, 144,
            nullptr, nullptr, nullptr, nullptr,
            nullptr, nullptr, nullptr, nullptr, 0, b);

        ch_norm_k<<<dim3(48, 2), blk, 0, stream>>>(qkv_b, rnorm);
        ch_attn_k<<<dim3(24, 2), blk, 0, stream>>>(qkv_b, rnorm, logit_ch, attn_b);
        ch_out_k<<<dim3(HW/64), blk, 0, stream>>>(qkv_b, attn_b, Wc_ch, bc_ch,
                                                  ch_out + (size_t)b*HW*CCH);
    }

    // CFCA: means, gates
    mean_k<<<dim3(CCH, BATCH), blk, 0, stream>>>(sp_out, mean_sp);
    mean_k<<<dim3(CCH, BATCH), blk, 0, stream>>>(ch_out, mean_ch);
    gates_k<<<BATCH, 192, 0, stream>>>(mean_sp, w_gs1, w_gs2, b_gs2, gate_s);
    gates_k<<<BATCH, 192, 0, stream>>>(mean_ch, w_gc1, w_gc2, b_gc2, gate_c);

    // CFCA hidden layers (relu), full M
    gemm_k<0,1,0,1,1><<<dim3(1, MTOK/GBM), blk, 0, stream>>>(
        sp_out, w_s2c1, nullptr, hid_s, MTOK, MIDC, CCH,
        nullptr, nullptr, nullptr, nullptr, nullptr, nullptr, nullptr, nullptr, 0, 0);
    gemm_k<0,1,0,1,1><<<dim3(1, MTOK/GBM), blk, 0, stream>>>(
        ch_out, w_c2s1, nullptr, hid_c, MTOK, MIDC, CCH,
        nullptr, nullptr, nullptr, nullptr, nullptr, nullptr, nullptr, nullptr, 0, 0);
    // gated residual adds: ch_out += (hid_s@w2+b)*gate_s ; sp_out += (hid_c@w2+b)*gate_c
    gemm_k<0,4,0,1,1><<<dim3(CCH/GBN, MTOK/GBM), blk, 0, stream>>>(
        hid_s, w_s2c2, b_s2c2, ch_out, MTOK, CCH, MIDC,
        nullptr, nullptr, nullptr, nullptr, gate_s, nullptr, nullptr, nullptr, 0, 0);
    gemm_k<0,4,0,1,1><<<dim3(CCH/GBN, MTOK/GBM), blk, 0, stream>>>(
        hid_c, w_c2s2, b_c2s2, sp_out, MTOK, CCH, MIDC,
        nullptr, nullptr, nullptr, nullptr, gate_c, nullptr, nullptr, nullptr, 0, 0);

    // f = relu(bn1(concat(spf,chf) @ w_f1^T))
    gemm_k<2,3,0,1,1><<<dim3(CCH/GBN, MTOK/GBM), blk, 0, stream>>>(
        sp_out, w_f1, nullptr, f, MTOK, CCH, 2*CCH,
        nullptr, nullptr, nullptr, ch_out, bn1_g, bn1_b, bn1_m, bn1_v, 0, 0);

    // f2 = relu(bn2(conv3x3(f, w_f2)))   (writes over dead sp_out region)
    gemm_k<3,3,1,1,1><<<dim3(CCH/GBN, MTOK/GBM), blk, 0, stream>>>(
        f, w_f2, nullptr, f2, MTOK, CCH, 9*CCH,
        nullptr, nullptr, nullptr, nullptr, bn2_g, bn2_b, bn2_m, bn2_v, CCH, 0);

    // gpre = conv3x3(f2, w_sg1)  (96 ch; writes over dead ch_out region)
    gemm_k<3,0,1,1,1><<<dim3(2, MTOK/GBM), blk, 0, stream>>>(
        f2, w_sg1, nullptr, gpre, MTOK, 96, 9*CCH,
        nullptr, nullptr, nullptr, nullptr, nullptr, nullptr, nullptr, nullptr, CCH, 0);

    // xnew = x + f2*(1+g) -> d_out
    fuse_k<<<MTOK/4, blk, 0, stream>>>(x, f2, gpre, w_sg2, b_sg2, out);

    // LN2 stats + MLP (chunked over tokens; hidden reuses dead f region)
    ln_stats_k<<<MTOK/4, blk, 0, stream>>>(out, stats2);
    const int CHM = MTOK / 4;  // 32768 tokens per chunk
    for (int c0 = 0; c0 < MTOK; c0 += CHM) {
        gemm_k<1,5,0,0,1><<<dim3(768/GBN, CHM/GBM), blk, 0, stream>>>(
            out + (size_t)c0*CCH, w_fc1, b_fc1, hidden, CHM, 4*CCH, CCH,
            stats2 + (size_t)c0*2, ln2_g, ln2_b, nullptr,
            nullptr, nullptr, nullptr, nullptr, 0, 0);
        gemm_k<0,6,0,1,0><<<dim3(CCH/GBN, CHM/GBM), blk, 0, stream>>>(
            hidden, w_fc2, b_fc2, out + (size_t)c0*CCH, CHM, CCH, 4*CCH,
            nullptr, nullptr, nullptr, nullptr, out + (size_t)c0*CCH,
            nullptr, nullptr, nullptr, 0, 0);
    }
}

// Round 4
// 3089.423 us; speedup vs baseline: 2.7649x; 1.2923x over previous
//
#include <hip/hip_runtime.h>
#include <hip/hip_bf16.h>
#include <cstddef>

typedef __hip_bfloat16 bf16;
typedef unsigned short u16;
typedef short s16x8 __attribute__((ext_vector_type(8)));
typedef float f32x4 __attribute__((ext_vector_type(4)));

// ---------------- problem constants ----------------
#define BATCH 8
#define HR 128
#define WR 128
#define CCH 192
#define HW (HR*WR)            // 16384
#define MTOK (BATCH*HW)       // 131072
#define SPH 6
#define SPC 432               // spatial qkv channels (heads 0..5)
#define CHC 144               // channel-head qkv channels (heads 6,7)
#define NWIN 256
#define MIDC 48
#define LOGMAX 4.6051701859880914f  // log(100)

// ---------------- ws layout (BYTE offsets; peak ~172 MB) ----------------
static const size_t OFF_SPOUT  = 0;                     // bf16 M*192 (reused: f2)
static const size_t OFF_CHOUT  = 50331648;              // bf16 M*192 (reused: gpre)
static const size_t OFF_QKVB   = 100663296;             // bf16 HW*432 (per-batch)
static const size_t OFF_OSPB   = 114819072;             // bf16 HW*144 (per-batch)
static const size_t OFF_STATS1 = 119537664;             // fp32 2*M
static const size_t OFF_STATS2 = 120586240;             // fp32 2*M
static const size_t OFF_RNORM  = 121634816;             // fp32 8*2*48
static const size_t OFF_ATTNB  = 121637888;             // fp32 8*2*24*24
static const size_t OFF_MEANSP = 121674752;
static const size_t OFF_MEANCH = 121680896;
static const size_t OFF_GATES  = 121687040;
static const size_t OFF_GATEC  = 121693184;
static const size_t OFF_WCSP   = 121699328;             // fp32 192*144
static const size_t OFF_BCSP   = 121809920;
static const size_t OFF_WCCH   = 121810688;             // fp32 192*48
static const size_t OFF_BCCH   = 121847552;
static const size_t OFF_PH2    = 121868544;             // chqkv / hid / f / hidden region
// chqkv: bf16 M*144 = 37,748,736 (dead after ch_out_k)
// hid_s = PH2, hid_c = PH2+12,582,912 ; f = PH2 (50MB) ; hidden = PH2 (50MB)
// f2 = OFF_SPOUT ; gpre = OFF_CHOUT.  peak end = PH2 + 50,331,648 = 172,200,192

__device__ __forceinline__ float b2f(bf16 x) { return __bfloat162float(x); }
__device__ __forceinline__ bf16  f2b(float x){ return __float2bfloat16(x); }
__device__ __forceinline__ u16   f2u(float x){
    bf16 h = __float2bfloat16(x);
    union { bf16 b; u16 u; } c; c.b = h; return c.u;
}

// =====================================================================
// MFMA bf16 GEMM with register prefetch.
// block 256 thr = 4 waves (2x2), tile BM=128 x BN=96, BK=32.
// AMODE: 0 plain, 1 LN-fused (A fp32), 2 concat(A|A2), 3 implicit 3x3 conv
// WMODE: 0 row-major [N][K] fp32, 1 conv weights (O,I,3,3) fp32
// EPI: 0 bias, 1 relu, 2 roll(+4,+4)-store (per-batch), 3 BN+relu,
//      4 gated residual (C += v*gate[b]), 5 gelu, 6 residual add (fp32 ep0),
//      7 qkv split store (n<432 -> Cv stride 432; else chqkv via ep0)
// ABF: A (and A2) bf16?   CBF: C bf16?   CIN: conv input channels (compile-time)
// Requirements: M % 128 == 0, K % 8 == 0.
// =====================================================================
#define GBM 128
#define GBN 96
#define GBK 32
#define LDA 40   // padded row length in ushorts (80 B)

struct SegRaw { union { uint4 v; struct { float4 lo, hi; } f; } d; };

template<int AMODE, int EPI, int WMODE, int ABF, int CBF, int CIN>
__global__ __launch_bounds__(256)
void gemm_k(const void* __restrict__ A, const float* __restrict__ W,
            const float* __restrict__ bias, void* __restrict__ Cv,
            int M, int N, int K,
            const float* __restrict__ stats, const float* __restrict__ lng,
            const float* __restrict__ lnb, const void* __restrict__ A2,
            const float* __restrict__ ep0, const float* __restrict__ ep1,
            const float* __restrict__ ep2, const float* __restrict__ ep3,
            int batch)
{
    __shared__ u16 As[GBM * LDA];   // 10240 B
    __shared__ u16 Bs[GBN * LDA];   // 7680 B

    const int tid  = threadIdx.x;
    const int lane = tid & 63;
    const int wid  = tid >> 6;
    const int wm   = (wid >> 1) * 64;
    const int wn   = (wid & 1) * 48;
    const int m0   = blockIdx.y * GBM;
    const int n0   = blockIdx.x * GBN;
    const int row16 = lane & 15;
    const int koff  = (lane >> 4) * 8;

    const int arow[2] = { tid >> 2, (tid + 256) >> 2 };
    const int akk     = (tid & 3) * 8;
    const int brow[2] = { tid >> 2, (tid + 256) >> 2 };
    const int bkk     = (tid & 3) * 8;

    float meanA[2], rstdA[2];
    if constexpr (AMODE == 1) {
        #pragma unroll
        for (int it = 0; it < 2; ++it) {
            const int m = m0 + arow[it];
            meanA[it] = stats[2*m]; rstdA[it] = stats[2*m+1];
        }
    }

    f32x4 acc[4][3];
    #pragma unroll
    for (int mf = 0; mf < 4; ++mf)
        #pragma unroll
        for (int nf = 0; nf < 3; ++nf)
            acc[mf][nf] = (f32x4){0.f, 0.f, 0.f, 0.f};

    const int nsteps = (K + GBK - 1) / GBK;

    auto loadA = [&](int step, SegRaw seg[2]) {
        const int k0 = step * GBK;
        #pragma unroll
        for (int it = 0; it < 2; ++it) {
            const int m = m0 + arow[it];
            const int k = k0 + akk;
            SegRaw& s = seg[it];
            if (k >= K) { s.d.v = (uint4){0u,0u,0u,0u}; continue; }
            if constexpr (AMODE == 0) {
                if constexpr (ABF) {
                    s.d.v = *(const uint4*)((const u16*)A + (size_t)m * K + k);
                } else {
                    const float* p = (const float*)A + (size_t)m * K + k;
                    s.d.f.lo = *(const float4*)p; s.d.f.hi = *(const float4*)(p+4);
                }
            } else if constexpr (AMODE == 1) {
                const float* p = (const float*)A + (size_t)m * K + k;
                s.d.f.lo = *(const float4*)p; s.d.f.hi = *(const float4*)(p+4);
            } else if constexpr (AMODE == 2) {
                const u16* src = (k < CCH) ? (const u16*)A  + (size_t)m * CCH + k
                                           : (const u16*)A2 + (size_t)m * CCH + (k - CCH);
                s.d.v = *(const uint4*)src;
            } else { // implicit 3x3 conv, bf16 source
                const int t = k / CIN, c = k - t * CIN;
                const int ky = t / 3, kx = t - ky * 3;
                const int b = m >> 14, pix = m & 16383;
                const int h = (pix >> 7) + ky - 1;
                const int w = (pix & 127) + kx - 1;
                if (h >= 0 && h < HR && w >= 0 && w < WR)
                    s.d.v = *(const uint4*)((const u16*)A +
                            ((size_t)(b * HW) + h * WR + w) * (size_t)CIN + c);
                else
                    s.d.v = (uint4){0u,0u,0u,0u};
            }
        }
    };
    auto loadB = [&](int step, SegRaw seg[2]) {
        const int k0 = step * GBK;
        #pragma unroll
        for (int it = 0; it < 2; ++it) {
            if (it == 1 && tid >= 128) break;
            const int n = n0 + brow[it];
            const int k = k0 + bkk;
            SegRaw& s = seg[it];
            s.d.f.lo = (float4){0.f,0.f,0.f,0.f};
            s.d.f.hi = (float4){0.f,0.f,0.f,0.f};
            if (k < K && n < N) {
                if constexpr (WMODE == 0) {
                    const float* p = W + (size_t)n * K + k;
                    s.d.f.lo = *(const float4*)p; s.d.f.hi = *(const float4*)(p+4);
                } else {
                    const int t = k / CIN, c = k - t * CIN;
                    float tmp[8];
                    #pragma unroll
                    for (int j = 0; j < 8; ++j)
                        tmp[j] = W[((size_t)n * CIN + c + j) * 9 + t];
                    s.d.f.lo = (float4){tmp[0],tmp[1],tmp[2],tmp[3]};
                    s.d.f.hi = (float4){tmp[4],tmp[5],tmp[6],tmp[7]};
                }
            }
        }
    };
    auto writeA = [&](int step, SegRaw seg[2]) {
        const int k0 = step * GBK;
        #pragma unroll
        for (int it = 0; it < 2; ++it) {
            const int r = arow[it];
            if constexpr (AMODE == 2 || AMODE == 3 || (AMODE == 0 && ABF)) {
                *(uint4*)&As[r * LDA + akk] = seg[it].d.v;
            } else {
                const int k = k0 + akk;
                union { u16 u[8]; uint4 v; } pk;
                #pragma unroll
                for (int j = 0; j < 8; ++j) {
                    float xx = (j < 4) ? seg[it].d.f.lo[j] : seg[it].d.f.hi[j-4];
                    if constexpr (AMODE == 1)
                        xx = (xx - meanA[it]) * rstdA[it] * lng[k+j] + lnb[k+j];
                    pk.u[j] = f2u(xx);
                }
                *(uint4*)&As[r * LDA + akk] = pk.v;
            }
        }
    };
    auto writeB = [&](SegRaw seg[2]) {
        #pragma unroll
        for (int it = 0; it < 2; ++it) {
            if (it == 1 && tid >= 128) break;
            union { u16 u[8]; uint4 v; } pk;
            #pragma unroll
            for (int j = 0; j < 8; ++j) {
                float xx = (j < 4) ? seg[it].d.f.lo[j] : seg[it].d.f.hi[j-4];
                pk.u[j] = f2u(xx);
            }
            *(uint4*)&Bs[brow[it] * LDA + bkk] = pk.v;
        }
    };

    SegRaw segA[2], segB[2];
    loadA(0, segA); loadB(0, segB);

    for (int step = 0; step < nsteps; ++step) {
        writeA(step, segA);
        writeB(segB);
        __syncthreads();
        if (step + 1 < nsteps) { loadA(step+1, segA); loadB(step+1, segB); }
        s16x8 af[4], bfr[3];
        #pragma unroll
        for (int mf = 0; mf < 4; ++mf)
            af[mf] = *(const s16x8*)&As[(wm + mf*16 + row16) * LDA + koff];
        #pragma unroll
        for (int nf = 0; nf < 3; ++nf)
            bfr[nf] = *(const s16x8*)&Bs[(wn + nf*16 + row16) * LDA + koff];
        #pragma unroll
        for (int mf = 0; mf < 4; ++mf)
            #pragma unroll
            for (int nf = 0; nf < 3; ++nf)
                acc[mf][nf] = __builtin_amdgcn_mfma_f32_16x16x32_bf16(
                    af[mf], bfr[nf], acc[mf][nf], 0, 0, 0);
        __syncthreads();
    }

    // ---- epilogue ----
    #pragma unroll
    for (int mf = 0; mf < 4; ++mf) {
        #pragma unroll
        for (int nf = 0; nf < 3; ++nf) {
            const int n = n0 + wn + nf*16 + row16;
            if (n >= N) continue;
            #pragma unroll
            for (int r = 0; r < 4; ++r) {
                const int m = m0 + wm + mf*16 + (lane >> 4)*4 + r;
                float v = acc[mf][nf][r] + (bias ? bias[n] : 0.f);
                if constexpr (EPI == 7) {
                    if (n < SPC) {
                        ((bf16*)Cv)[(size_t)m * SPC + n] = f2b(v);
                    } else {
                        bf16* chq = (bf16*)ep0;
                        chq[((size_t)(batch * HW) + m) * CHC + (n - SPC)] = f2b(v);
                    }
                    continue;
                }
                size_t outIdx;
                if constexpr (EPI == 2) {
                    const int h2 = ((m >> 7) + 4) & 127;
                    const int w2 = ((m & 127) + 4) & 127;
                    outIdx = ((size_t)(batch * HW) + h2 * WR + w2) * (size_t)N + n;
                } else {
                    outIdx = (size_t)m * N + n;
                }
                if constexpr (EPI == 1) {
                    v = fmaxf(v, 0.f);
                } else if constexpr (EPI == 3) {
                    v = (v - ep2[n]) * rsqrtf(ep3[n] + 1e-5f) * ep0[n] + ep1[n];
                    v = fmaxf(v, 0.f);
                } else if constexpr (EPI == 4) {
                    const int b = m >> 14;
                    const float cold = CBF ? b2f(((const bf16*)Cv)[outIdx])
                                           : ((const float*)Cv)[outIdx];
                    v = cold + v * ep0[b * N + n];
                } else if constexpr (EPI == 5) {
                    v = 0.5f * v * (1.f + erff(v * 0.70710678118654752f));
                } else if constexpr (EPI == 6) {
                    v = ep0[outIdx] + v;
                }
                if constexpr (CBF) ((bf16*)Cv)[outIdx] = f2b(v);
                else               ((float*)Cv)[outIdx] = v;
            }
        }
    }
}

// =====================================================================
// LN stats
// =====================================================================
__global__ __launch_bounds__(256)
void ln_stats_k(const float* __restrict__ x, float* __restrict__ stats)
{
    const int tok = blockIdx.x * 4 + (threadIdx.x >> 6);
    const int lane = threadIdx.x & 63;
    const float* r = x + (size_t)tok * CCH;
    float s = 0.f, sq = 0.f;
    for (int c = lane; c < CCH; c += 64) { float v = r[c]; s += v; sq += v*v; }
    for (int m = 1; m < 64; m <<= 1) { s += __shfl_xor(s, m); sq += __shfl_xor(sq, m); }
    if (lane == 0) {
        const float mean = s / (float)CCH;
        const float var = sq / (float)CCH - mean * mean;
        stats[(size_t)tok*2]   = mean;
        stats[(size_t)tok*2+1] = rsqrtf(var + 1e-5f);
    }
}

// =====================================================================
// Spatial shifted-window cosine attention, one batch (stride 432)
// =====================================================================
__global__ __launch_bounds__(256)
void sp_attn_k(const bf16* __restrict__ qkv, const float* __restrict__ rpb,
               const float* __restrict__ logit_sp, bf16* __restrict__ o)
{
    const int head = blockIdx.x;
    const int win  = blockIdx.y;
    const int wh = win >> 4, ww = win & 15;
    const int tid = threadIdx.x;

    __shared__ float q[64][25], k[64][25], v[64][25];
    __shared__ float attn[64][66];
    __shared__ float rq[64], rk[64];
    __shared__ int   lab[64];
    __shared__ float scale_s;

    for (int idx = tid; idx < 64*24*3; idx += 256) {
        const int which = idx / 1536;
        const int rem = idx - which * 1536;
        const int p = rem / 24, d = rem - (rem/24)*24;
        const int h = (wh*8 + (p >> 3) + 4) & 127;
        const int w = (ww*8 + (p & 7)  + 4) & 127;
        const float val = b2f(qkv[((size_t)(h*WR + w)) * SPC + head*72 + which*24 + d]);
        if (which == 0) q[p][d] = val;
        else if (which == 1) k[p][d] = val;
        else v[p][d] = val;
    }
    if (tid == 0) scale_s = expf(fminf(logit_sp[head], LOGMAX));
    __syncthreads();

    if (tid < 64) {
        float s = 0.f;
        #pragma unroll
        for (int d = 0; d < 24; ++d) s += q[tid][d]*q[tid][d];
        rq[tid] = 1.f / fmaxf(sqrtf(s), 1e-12f);
        const int h = wh*8 + (tid >> 3), w = ww*8 + (tid & 7);
        const int rh = h < 120 ? 0 : (h < 124 ? 1 : 2);
        const int rw = w < 120 ? 0 : (w < 124 ? 1 : 2);
        lab[tid] = rh*3 + rw;
    } else if (tid < 128) {
        const int i = tid - 64;
        float s = 0.f;
        #pragma unroll
        for (int d = 0; d < 24; ++d) s += k[i][d]*k[i][d];
        rk[i] = 1.f / fmaxf(sqrtf(s), 1e-12f);
    }
    __syncthreads();

    for (int e = tid; e < 4096; e += 256) {
        const int i = e >> 6, j = e & 63;
        float s = 0.f;
        #pragma unroll
        for (int d = 0; d < 24; ++d) s += q[i][d]*k[j][d];
        s = s * rq[i] * rk[j] * scale_s;
        const int r0 = (i >> 3) - (j >> 3) + 7;
        const int r1 = (i & 7) - (j & 7) + 7;
        s += rpb[(r0*15 + r1)*SPH + head];
        if (lab[i] != lab[j]) s -= 100.f;
        attn[i][j] = s;
    }
    __syncthreads();

    {
        const int r = tid >> 2, l = tid & 3;
        float mx = -1e30f;
        for (int j = l; j < 64; j += 4) mx = fmaxf(mx, attn[r][j]);
        mx = fmaxf(mx, __shfl_xor(mx, 1));
        mx = fmaxf(mx, __shfl_xor(mx, 2));
        float sum = 0.f;
        for (int j = l; j < 64; j += 4) { float e2 = expf(attn[r][j] - mx); attn[r][j] = e2; sum += e2; }
        sum += __shfl_xor(sum, 1);
        sum += __shfl_xor(sum, 2);
        const float inv = 1.f / sum;
        for (int j = l; j < 64; j += 4) attn[r][j] *= inv;
    }
    __syncthreads();

    for (int idx = tid; idx < 64*24; idx += 256) {
        const int i = idx / 24, d = idx - (idx/24)*24;
        float s = 0.f;
        #pragma unroll
        for (int j = 0; j < 64; ++j) s += attn[i][j] * v[j][d];
        const int h = wh*8 + (i >> 3), w = ww*8 + (i & 7);
        o[((size_t)(h*WR + w)) * 144 + head*24 + d] = f2b(s);
    }
}

// =====================================================================
// Channel attention, FULL batch; chqkv: [M][144] bf16
// =====================================================================
__global__ __launch_bounds__(256)
void ch_norm_k(const bf16* __restrict__ chqkv, float* __restrict__ rnorm)
{
    const int c = blockIdx.x;     // 0..47
    const int head = blockIdx.y;
    const int b = blockIdx.z;
    const bf16* base = chqkv + (size_t)b * HW * CHC + head * 72 + c;
    float s = 0.f;
    for (int i = threadIdx.x; i < HW; i += 256) { const float v = b2f(base[(size_t)i * CHC]); s += v*v; }
    for (int m = 1; m < 64; m <<= 1) s += __shfl_xor(s, m);
    __shared__ float red[4];
    if ((threadIdx.x & 63) == 0) red[threadIdx.x >> 6] = s;
    __syncthreads();
    if (threadIdx.x == 0)
        rnorm[(b*2 + head)*48 + c] = 1.f / fmaxf(sqrtf(red[0]+red[1]+red[2]+red[3]), 1e-12f);
}

__global__ __launch_bounds__(256)
void ch_attn_k(const bf16* __restrict__ chqkv, const float* __restrict__ rnorm,
               const float* __restrict__ logit_ch, float* __restrict__ attn_ch)
{
    const int c = blockIdx.x;     // q row 0..23
    const int head = blockIdx.y;
    const int b = blockIdx.z;
    const int tid = threadIdx.x;
    const bf16* base = chqkv + (size_t)b * HW * CHC + head * 72;
    float acc[24];
    #pragma unroll
    for (int d = 0; d < 24; ++d) acc[d] = 0.f;
    for (int i = tid; i < HW; i += 256) {
        const u16* row = (const u16*)(base + (size_t)i * CHC);
        const float qv = b2f(*(const bf16*)&row[c]);
        union { uint4 v; u16 u[8]; } kv[3];
        kv[0].v = *(const uint4*)(row + 24);
        kv[1].v = *(const uint4*)(row + 32);
        kv[2].v = *(const uint4*)(row + 40);
        #pragma unroll
        for (int d = 0; d < 24; ++d)
            acc[d] += qv * b2f(*(const bf16*)&kv[d>>3].u[d&7]);
    }
    #pragma unroll
    for (int d = 0; d < 24; ++d)
        for (int m = 1; m < 64; m <<= 1) acc[d] += __shfl_xor(acc[d], m);
    __shared__ float wsum[4][24];
    const int wid = tid >> 6, lane = tid & 63;
    if (lane == 0) {
        #pragma unroll
        for (int d = 0; d < 24; ++d) wsum[wid][d] = acc[d];
    }
    __syncthreads();
    if (tid == 0) {
        const float scale = expf(fminf(logit_ch[head], LOGMAX));
        const float* rn = rnorm + (b*2 + head)*48;
        float vals[24], mx = -1e30f;
        #pragma unroll
        for (int d = 0; d < 24; ++d) {
            const float rowv = wsum[0][d] + wsum[1][d] + wsum[2][d] + wsum[3][d];
            vals[d] = rowv * rn[c] * rn[24+d] * scale;
            mx = fmaxf(mx, vals[d]);
        }
        float sum = 0.f;
        #pragma unroll
        for (int d = 0; d < 24; ++d) { vals[d] = expf(vals[d] - mx); sum += vals[d]; }
        const float inv = 1.f / sum;
        float* outp = attn_ch + ((size_t)(b*2 + head)*24 + c)*24;
        #pragma unroll
        for (int d = 0; d < 24; ++d) outp[d] = vals[d]*inv;
    }
}

__global__ __launch_bounds__(256)
void ch_out_k(const bf16* __restrict__ chqkv, const float* __restrict__ attn_ch,
              const float* __restrict__ Wc, const float* __restrict__ bc,
              bf16* __restrict__ ch_out)
{
    const int pix0 = blockIdx.x * 64;
    const int b = blockIdx.y;
    const int tid = threadIdx.x;
    __shared__ float A2s[2][24][24];
    __shared__ float Wcs[192][48];
    __shared__ float bcs[192];
    __shared__ float vbuf[64][48];
    __shared__ float ocb[64][49];

    for (int idx = tid; idx < 2*24*24; idx += 256) {
        const int hh = idx / 576, rem = idx - hh*576;
        A2s[hh][rem/24][rem%24] = attn_ch[(size_t)b*1152 + idx];
    }
    for (int idx = tid; idx < 192*48; idx += 256) Wcs[idx/48][idx%48] = Wc[idx];
    if (tid < 192) bcs[tid] = bc[tid];
    for (int idx = tid; idx < 64*48; idx += 256) {
        const int p = idx / 48, c = idx - (idx/48)*48;
        const int head = c / 24, d = c - head*24;
        vbuf[p][c] = b2f(chqkv[((size_t)(b*HW + pix0 + p)) * CHC + head*72 + 48 + d]);
    }
    __syncthreads();
    for (int idx = tid; idx < 64*48; idx += 256) {
        const int p = idx / 48, c = idx - (idx/48)*48;
        const int head = c / 24, cc = c - head*24;
        float s = 0.f;
        #pragma unroll
        for (int d = 0; d < 24; ++d) s += A2s[head][cc][d] * vbuf[p][head*24 + d];
        ocb[p][c] = s;
    }
    __syncthreads();
    for (int idx = tid; idx < 64*192; idx += 256) {
        const int p = idx / 192, n = idx - (idx/192)*192;
        float s = bcs[n];
        #pragma unroll
        for (int c = 0; c < 48; ++c) s += ocb[p][c] * Wcs[n][c];
        ch_out[((size_t)(b*HW + pix0 + p)) * CCH + n] = f2b(s);
    }
}

// =====================================================================
// weight combiners
// =====================================================================
__global__ void combine_sp_k(const float* __restrict__ w_sp_proj, const float* __restrict__ w_spp,
                             const float* __restrict__ b_spp, float* __restrict__ Wc, float* __restrict__ bc)
{
    const int n = blockIdx.x;
    for (int i = threadIdx.x; i < 144; i += blockDim.x) {
        float s = 0.f;
        for (int j = 0; j < 144; ++j) s += w_sp_proj[n*144 + j] * w_spp[j*144 + i];
        Wc[n*144 + i] = s;
    }
    if (threadIdx.x == 0) {
        float s = 0.f;
        for (int j = 0; j < 144; ++j) s += w_sp_proj[n*144 + j] * b_spp[j];
        bc[n] = s;
    }
}

__global__ void combine_ch_k(const float* __restrict__ w_ch_proj, const float* __restrict__ w_chp,
                             const float* __restrict__ b_chp, float* __restrict__ Wc, float* __restrict__ bc)
{
    const int n = blockIdx.x;
    for (int c = threadIdx.x; c < 48; c += blockDim.x) {
        float s = 0.f;
        for (int j = 0; j < 48; ++j) s += w_ch_proj[n*48 + j] * w_chp[j*48 + c];
        Wc[n*48 + c] = s;
    }
    if (threadIdx.x == 0) {
        float s = 0.f;
        for (int j = 0; j < 48; ++j) s += w_ch_proj[n*48 + j] * b_chp[j];
        bc[n] = s;
    }
}

// =====================================================================
// per-(b,c) mean over H,W (bf16 src)
// =====================================================================
__global__ __launch_bounds__(256)
void mean_k(const bf16* __restrict__ src, float* __restrict__ dst)
{
    const int c = blockIdx.x, b = blockIdx.y;
    const bf16* base = src + (size_t)b * HW * CCH + c;
    float s = 0.f;
    for (int i = threadIdx.x; i < HW; i += 256) s += b2f(base[(size_t)i * CCH]);
    for (int m = 1; m < 64; m <<= 1) s += __shfl_xor(s, m);
    __shared__ float red[4];
    if ((threadIdx.x & 63) == 0) red[threadIdx.x >> 6] = s;
    __syncthreads();
    if (threadIdx.x == 0) dst[b*CCH + c] = (red[0]+red[1]+red[2]+red[3]) / (float)HW;
}

__global__ __launch_bounds__(192)
void gates_k(const float* __restrict__ meanv, const float* __restrict__ w1,
             const float* __restrict__ w2, const float* __restrict__ b2,
             float* __restrict__ gate)
{
    const int b = blockIdx.x;
    __shared__ float mv[192], hid[48];
    const int t = threadIdx.x;
    mv[t] = meanv[b*CCH + t];
    __syncthreads();
    if (t < 48) {
        float s = 0.f;
        for (int c = 0; c < 192; ++c) s += w1[t*192 + c] * mv[c];
        hid[t] = fmaxf(s, 0.f);
    }
    __syncthreads();
    float s = b2[t];
    for (int j = 0; j < 48; ++j) s += hid[j] * w2[t*48 + j];
    gate[b*CCH + t] = 1.f / (1.f + expf(-s));
}

// =====================================================================
// out = x + f2 * (1 + sigmoid(relu(gpre)@w_sg2 + b))
// =====================================================================
__global__ __launch_bounds__(256)
void fuse_k(const float* __restrict__ x, const bf16* __restrict__ f2,
            const bf16* __restrict__ gpre, const float* __restrict__ w_sg2,
            const float* __restrict__ b_sg2, float* __restrict__ out)
{
    const int pix = blockIdx.x * 4 + (threadIdx.x >> 6);
    const int lane = threadIdx.x & 63;
    const bf16* gp = gpre + (size_t)pix * 96;
    float s = fmaxf(b2f(gp[lane]), 0.f) * w_sg2[lane];
    if (lane < 32) s += fmaxf(b2f(gp[lane + 64]), 0.f) * w_sg2[lane + 64];
    for (int m = 1; m < 64; m <<= 1) s += __shfl_xor(s, m);
    const float g1 = 1.f + 1.f / (1.f + expf(-(s + b_sg2[0])));
    const float* xr = x  + (size_t)pix * CCH;
    const bf16* fr = f2 + (size_t)pix * CCH;
    float* orow = out + (size_t)pix * CCH;
    for (int c = lane; c < CCH; c += 64) orow[c] = xr[c] + b2f(fr[c]) * g1;
}

// =====================================================================
// launcher
// =====================================================================
extern "C" void kernel_launch(void* const* d_in, const int* in_sizes, int n_in,
                              void* d_out, int out_size, void* d_ws, size_t ws_size,
                              hipStream_t stream)
{
    const float* x        = (const float*)d_in[0];
    const float* ln1_g    = (const float*)d_in[1];
    const float* ln1_b    = (const float*)d_in[2];
    const float* w_qkv    = (const float*)d_in[3];
    const float* b_qkv    = (const float*)d_in[4];
    const float* logit_sp = (const float*)d_in[5];
    const float* rpb      = (const float*)d_in[6];
    const float* w_spp    = (const float*)d_in[7];
    const float* b_spp    = (const float*)d_in[8];
    const float* logit_ch = (const float*)d_in[9];
    const float* w_chp    = (const float*)d_in[10];
    const float* b_chp    = (const float*)d_in[11];
    const float* w_sp_proj= (const float*)d_in[12];
    const float* w_ch_proj= (const float*)d_in[13];
    const float* w_s2c1   = (const float*)d_in[14];
    const float* w_s2c2   = (const float*)d_in[15];
    const float* b_s2c2   = (const float*)d_in[16];
    const float* w_c2s1   = (const float*)d_in[17];
    const float* w_c2s2   = (const float*)d_in[18];
    const float* b_c2s2   = (const float*)d_in[19];
    const float* w_gs1    = (const float*)d_in[20];
    const float* w_gs2    = (const float*)d_in[21];
    const float* b_gs2    = (const float*)d_in[22];
    const float* w_gc1    = (const float*)d_in[23];
    const float* w_gc2    = (const float*)d_in[24];
    const float* b_gc2    = (const float*)d_in[25];
    const float* w_f1     = (const float*)d_in[26];
    const float* bn1_g    = (const float*)d_in[27];
    const float* bn1_b    = (const float*)d_in[28];
    const float* bn1_m    = (const float*)d_in[29];
    const float* bn1_v    = (const float*)d_in[30];
    const float* w_f2     = (const float*)d_in[31];
    const float* bn2_g    = (const float*)d_in[32];
    const float* bn2_b    = (const float*)d_in[33];
    const float* bn2_m    = (const float*)d_in[34];
    const float* bn2_v    = (const float*)d_in[35];
    const float* w_sg1    = (const float*)d_in[36];
    const float* w_sg2    = (const float*)d_in[37];
    const float* b_sg2    = (const float*)d_in[38];
    const float* ln2_g    = (const float*)d_in[39];
    const float* ln2_b    = (const float*)d_in[40];
    const float* w_fc1    = (const float*)d_in[41];
    const float* b_fc1    = (const float*)d_in[42];
    const float* w_fc2    = (const float*)d_in[43];
    const float* b_fc2    = (const float*)d_in[44];

    char* wsb = (char*)d_ws;
    float* out = (float*)d_out;

    bf16*  sp_out = (bf16*)(wsb + OFF_SPOUT);
    bf16*  ch_out = (bf16*)(wsb + OFF_CHOUT);
    bf16*  qkv_b  = (bf16*)(wsb + OFF_QKVB);
    bf16*  osp_b  = (bf16*)(wsb + OFF_OSPB);
    float* stats1 = (float*)(wsb + OFF_STATS1);
    float* stats2 = (float*)(wsb + OFF_STATS2);
    float* rnorm  = (float*)(wsb + OFF_RNORM);
    float* attn_b = (float*)(wsb + OFF_ATTNB);
    float* mean_sp= (float*)(wsb + OFF_MEANSP);
    float* mean_ch= (float*)(wsb + OFF_MEANCH);
    float* gate_s = (float*)(wsb + OFF_GATES);
    float* gate_c = (float*)(wsb + OFF_GATEC);
    float* Wc_sp  = (float*)(wsb + OFF_WCSP);
    float* bc_sp  = (float*)(wsb + OFF_BCSP);
    float* Wc_ch  = (float*)(wsb + OFF_WCCH);
    float* bc_ch  = (float*)(wsb + OFF_BCCH);
    bf16*  chqkv  = (bf16*)(wsb + OFF_PH2);
    bf16*  hid_s  = (bf16*)(wsb + OFF_PH2);
    bf16*  hid_c  = (bf16*)(wsb + OFF_PH2 + 12582912);
    bf16*  f      = (bf16*)(wsb + OFF_PH2);
    bf16*  f2     = (bf16*)(wsb + OFF_SPOUT);
    bf16*  gpre   = (bf16*)(wsb + OFF_CHOUT);
    bf16*  hidden = (bf16*)(wsb + OFF_PH2);

    const dim3 blk(256);

    combine_sp_k<<<192, 128, 0, stream>>>(w_sp_proj, w_spp, b_spp, Wc_sp, bc_sp);
    combine_ch_k<<<192, 64, 0, stream>>>(w_ch_proj, w_chp, b_chp, Wc_ch, bc_ch);

    ln_stats_k<<<MTOK/4, blk, 0, stream>>>(x, stats1);

    // per-batch: qkv GEMM (split store) -> spatial attn -> sp proj (roll store)
    for (int b = 0; b < BATCH; ++b) {
        gemm_k<1,7,0,0,1,1><<<dim3(6, HW/GBM), blk, 0, stream>>>(
            x + (size_t)b*HW*CCH, w_qkv, b_qkv, qkv_b, HW, 576, CCH,
            stats1 + (size_t)b*HW*2, ln1_g, ln1_b, nullptr,
            (const float*)chqkv, nullptr, nullptr, nullptr, b);

        sp_attn_k<<<dim3(SPH, NWIN), blk, 0, stream>>>(qkv_b, rpb, logit_sp, osp_b);

        gemm_k<0,2,0,1,1,1><<<dim3(2, HW/GBM), blk, 0, stream>>>(
            osp_b, Wc_sp, bc_sp, sp_out, HW, CCH, 144,
            nullptr, nullptr, nullptr, nullptr,
            nullptr, nullptr, nullptr, nullptr, b);
    }

    // channel attention, full batch
    ch_norm_k<<<dim3(48, 2, BATCH), blk, 0, stream>>>(chqkv, rnorm);
    ch_attn_k<<<dim3(24, 2, BATCH), blk, 0, stream>>>(chqkv, rnorm, logit_ch, attn_b);
    ch_out_k<<<dim3(HW/64, BATCH), blk, 0, stream>>>(chqkv, attn_b, Wc_ch, bc_ch, ch_out);

    // CFCA: means, gates
    mean_k<<<dim3(CCH, BATCH), blk, 0, stream>>>(sp_out, mean_sp);
    mean_k<<<dim3(CCH, BATCH), blk, 0, stream>>>(ch_out, mean_ch);
    gates_k<<<BATCH, 192, 0, stream>>>(mean_sp, w_gs1, w_gs2, b_gs2, gate_s);
    gates_k<<<BATCH, 192, 0, stream>>>(mean_ch, w_gc1, w_gc2, b_gc2, gate_c);

    // CFCA hidden layers (relu), full M  (chqkv dead now)
    gemm_k<0,1,0,1,1,1><<<dim3(1, MTOK/GBM), blk, 0, stream>>>(
        sp_out, w_s2c1, nullptr, hid_s, MTOK, MIDC, CCH,
        nullptr, nullptr, nullptr, nullptr, nullptr, nullptr, nullptr, nullptr, 0);
    gemm_k<0,1,0,1,1,1><<<dim3(1, MTOK/GBM), blk, 0, stream>>>(
        ch_out, w_c2s1, nullptr, hid_c, MTOK, MIDC, CCH,
        nullptr, nullptr, nullptr, nullptr, nullptr, nullptr, nullptr, nullptr, 0);
    gemm_k<0,4,0,1,1,1><<<dim3(2, MTOK/GBM), blk, 0, stream>>>(
        hid_s, w_s2c2, b_s2c2, ch_out, MTOK, CCH, MIDC,
        nullptr, nullptr, nullptr, nullptr, gate_s, nullptr, nullptr, nullptr, 0);
    gemm_k<0,4,0,1,1,1><<<dim3(2, MTOK/GBM), blk, 0, stream>>>(
        hid_c, w_c2s2, b_c2s2, sp_out, MTOK, CCH, MIDC,
        nullptr, nullptr, nullptr, nullptr, gate_c, nullptr, nullptr, nullptr, 0);

    // f = relu(bn1(concat(spf,chf) @ w_f1^T))
    gemm_k<2,3,0,1,1,1><<<dim3(2, MTOK/GBM), blk, 0, stream>>>(
        sp_out, w_f1, nullptr, f, MTOK, CCH, 2*CCH,
        nullptr, nullptr, nullptr, ch_out, bn1_g, bn1_b, bn1_m, bn1_v, 0);

    // f2 = relu(bn2(conv3x3(f, w_f2)))
    gemm_k<3,3,1,1,1,CCH><<<dim3(2, MTOK/GBM), blk, 0, stream>>>(
        f, w_f2, nullptr, f2, MTOK, CCH, 9*CCH,
        nullptr, nullptr, nullptr, nullptr, bn2_g, bn2_b, bn2_m, bn2_v, 0);

    // gpre = conv3x3(f2, w_sg1)  (96 ch)
    gemm_k<3,0,1,1,1,CCH><<<dim3(1, MTOK/GBM), blk, 0, stream>>>(
        f2, w_sg1, nullptr, gpre, MTOK, 96, 9*CCH,
        nullptr, nullptr, nullptr, nullptr, nullptr, nullptr, nullptr, nullptr, 0);

    // xnew = x + f2*(1+g) -> d_out
    fuse_k<<<MTOK/4, blk, 0, stream>>>(x, f2, gpre, w_sg2, b_sg2, out);

    // LN2 stats + MLP (chunked)
    ln_stats_k<<<MTOK/4, blk, 0, stream>>>(out, stats2);
    const int CHM = MTOK / 4;
    for (int c0 = 0; c0 < MTOK; c0 += CHM) {
        gemm_k<1,5,0,0,1,1><<<dim3(8, CHM/GBM), blk, 0, stream>>>(
            out + (size_t)c0*CCH, w_fc1, b_fc1, hidden, CHM, 4*CCH, CCH,
            stats2 + (size_t)c0*2, ln2_g, ln2_b, nullptr,
            nullptr, nullptr, nullptr, nullptr, 0);
        gemm_k<0,6,0,1,0,1><<<dim3(2, CHM/GBM), blk, 0, stream>>>(
            hidden, w_fc2, b_fc2, out + (size_t)c0*CCH, CHM, CCH, 4*CCH,
            nullptr, nullptr, nullptr, nullptr, out + (size_t)c0*CCH,
            nullptr, nullptr, nullptr, 0);
    }
}

// Round 5
// 2491.280 us; speedup vs baseline: 3.4287x; 1.2401x over previous
//
#include <hip/hip_runtime.h>
#include <hip/hip_bf16.h>
#include <cstddef>

typedef __hip_bfloat16 bf16;
typedef unsigned short u16;
typedef short s16x8 __attribute__((ext_vector_type(8)));
typedef float f32x4 __attribute__((ext_vector_type(4)));

// ---------------- problem constants ----------------
#define BATCH 8
#define HR 128
#define WR 128
#define CCH 192
#define HW (HR*WR)            // 16384
#define MTOK (BATCH*HW)       // 131072
#define SPH 6
#define SPC 432               // spatial qkv channels (heads 0..5)
#define CHC 144               // channel-head qkv channels (heads 6,7)
#define NWIN 256
#define MIDC 48
#define PH 130                // padded conv H/W
#define PHW (PH*PH)           // 16900
#define LOGMAX 4.6051701859880914f

// ---------------- ws layout (BYTE offsets; peak ~184 MB) ----------------
static const size_t OFF_REG0  = 0;          // sp_out (50.3MB) -> f2pad (51.9MB)
static const size_t OFF_REG1  = 51916800;   // ch_out (50.3MB) -> gpre (25.2MB)
static const size_t OFF_REG2  = 103833600;  // chqkv (37.7MB) -> fpad (51.9MB) -> hidden (50.3MB)
static const size_t OFF_REG3  = 155750400;  // qkv_b+osp_b (18.9MB) -> hid_s+hid_c (25.2MB)
static const size_t OFF_SMALL = 180916224;
static const size_t SO_STATS  = 0;          // fp32 2*M (shared LN1/LN2)
static const size_t SO_RNORM  = 1048576;
static const size_t SO_ATTNB  = 1051648;
static const size_t SO_MEANSP = 1088512;
static const size_t SO_MEANCH = 1094656;
static const size_t SO_GATES  = 1100800;
static const size_t SO_GATEC  = 1106944;
static const size_t SO_BCSP   = 1113088;    // fp32 192
static const size_t SO_WCCH   = 1114112;    // fp32 192*48
static const size_t SO_BCCH   = 1150976;    // fp32 192
static const size_t SO_WCSPB  = 1152000;    // bf16 192*144
static const size_t SO_WQB    = 1207296;    // bf16 576*192
static const size_t SO_WS2C1B = 1428480;    // bf16 48*192
static const size_t SO_WC2S1B = 1446912;
static const size_t SO_WS2C2B = 1465344;    // bf16 192*48
static const size_t SO_WC2S2B = 1483776;
static const size_t SO_WF1B   = 1502208;    // bf16 192*384
static const size_t SO_WF2CB  = 1649664;    // bf16 192*1728
static const size_t SO_WSG1CB = 2313216;    // bf16 96*1728
static const size_t SO_WFC1B  = 2644992;    // bf16 768*192
static const size_t SO_WFC2B  = 2939904;    // bf16 192*768

__device__ __forceinline__ float b2f(bf16 x) { return __bfloat162float(x); }
__device__ __forceinline__ bf16  f2b(float x){ return __float2bfloat16(x); }
__device__ __forceinline__ u16   f2u(float x){
    bf16 h = __float2bfloat16(x);
    union { bf16 b; u16 u; } c; c.b = h; return c.u;
}

// =====================================================================
// MFMA bf16 GEMM, register prefetch, all-bf16 B [N][K].
// block 256 thr = 4 waves (2x2), tile 128 x BNT, BK=32.
// AMODE: 0 plain bf16, 1 LN-fused (A fp32 + stats), 2 concat(A|A2 bf16),
//        3 implicit 3x3 conv over PADDED [8][130][130][192] bf16 input
// EPI: 0 bias, 1 relu, 2 roll(+4,+4)-store (per-batch), 3 BN+relu,
//      4 gated residual (C += v*gate[b]), 5 gelu, 6 residual add (fp32 ep0),
//      7 qkv split store (n<432 -> Cv stride 432; else chqkv via ep0)
// CBF: C bf16?   BNT: 96 or 192.  CPAD: store to padded conv layout.
// =====================================================================
#define GBM 128
#define GBK 32
#define LDA 40   // padded LDS row length in ushorts (80 B, 16B-aligned rows)

struct SegRaw { union { uint4 v; struct { float4 lo, hi; } f; } d; };

template<int AMODE, int EPI, int CBF, int BNT, int CPAD>
__global__ __launch_bounds__(256)
void gemm_k(const void* __restrict__ A, const u16* __restrict__ W,
            const float* __restrict__ bias, void* __restrict__ Cv,
            int M, int N, int K,
            const float* __restrict__ stats, const float* __restrict__ lng,
            const float* __restrict__ lnb, const void* __restrict__ A2,
            const float* __restrict__ ep0, const float* __restrict__ ep1,
            const float* __restrict__ ep2, const float* __restrict__ ep3,
            int batch)
{
    constexpr int NF = BNT / 32;               // B frags per wave
    constexpr int NB = (BNT * 4 + 255) / 256;  // B segments per thread
    __shared__ u16 As[GBM * LDA];
    __shared__ u16 Bs[BNT * LDA];

    const int tid  = threadIdx.x;
    const int lane = tid & 63;
    const int wid  = tid >> 6;
    const int wm   = (wid >> 1) * 64;
    const int wn   = (wid & 1) * (BNT / 2);
    const int m0   = blockIdx.y * GBM;
    const int n0   = blockIdx.x * BNT;
    const int row16 = lane & 15;
    const int koff  = (lane >> 4) * 8;

    const int arow[2] = { tid >> 2, (tid + 256) >> 2 };
    const int akk     = (tid & 3) * 8;

    float meanA[2], rstdA[2];
    if constexpr (AMODE == 1) {
        #pragma unroll
        for (int it = 0; it < 2; ++it) {
            const int m = m0 + arow[it];
            meanA[it] = stats[2*m]; rstdA[it] = stats[2*m+1];
        }
    }

    f32x4 acc[4][NF];
    #pragma unroll
    for (int mf = 0; mf < 4; ++mf)
        #pragma unroll
        for (int nf = 0; nf < NF; ++nf)
            acc[mf][nf] = (f32x4){0.f, 0.f, 0.f, 0.f};

    const int nsteps = (K + GBK - 1) / GBK;

    auto loadA = [&](int step, SegRaw seg[2]) {
        const int k0 = step * GBK;
        #pragma unroll
        for (int it = 0; it < 2; ++it) {
            const int m = m0 + arow[it];
            const int k = k0 + akk;
            SegRaw& s = seg[it];
            if (k >= K) { s.d.v = (uint4){0u,0u,0u,0u}; continue; }
            if constexpr (AMODE == 0) {
                s.d.v = *(const uint4*)((const u16*)A + (size_t)m * K + k);
            } else if constexpr (AMODE == 1) {
                const float* p = (const float*)A + (size_t)m * K + k;
                s.d.f.lo = *(const float4*)p; s.d.f.hi = *(const float4*)(p+4);
            } else if constexpr (AMODE == 2) {
                const u16* src = (k < CCH) ? (const u16*)A  + (size_t)m * CCH + k
                                           : (const u16*)A2 + (size_t)m * CCH + (k - CCH);
                s.d.v = *(const uint4*)src;
            } else { // padded conv: always in-bounds
                const int tap = k / CCH, c = k - tap * CCH;
                const int ky = tap / 3, kx = tap - ky * 3;
                const int b = m >> 14, pix = m & 16383;
                const int h = pix >> 7, w = pix & 127;
                s.d.v = *(const uint4*)((const u16*)A +
                        ((size_t)b * PHW + (size_t)(h + ky) * PH + (w + kx)) * CCH + c);
            }
        }
    };
    auto loadB = [&](int step, SegRaw seg[NB]) {
        const int k0 = step * GBK;
        #pragma unroll
        for (int it = 0; it < NB; ++it) {
            const int s = tid + it * 256;
            const int n = n0 + (s >> 2);
            const int k = k0 + (s & 3) * 8;
            seg[it].d.v = (uint4){0u,0u,0u,0u};
            if (s < BNT*4 && k < K && n < N)
                seg[it].d.v = *(const uint4*)(W + (size_t)n * K + k);
        }
    };
    auto writeA = [&](int step, SegRaw seg[2]) {
        const int k0 = step * GBK;
        #pragma unroll
        for (int it = 0; it < 2; ++it) {
            if constexpr (AMODE == 1) {
                const int k = k0 + akk;
                union { u16 u[8]; uint4 v; } pk;
                #pragma unroll
                for (int j = 0; j < 8; ++j) {
                    float xx = (j < 4) ? seg[it].d.f.lo[j] : seg[it].d.f.hi[j-4];
                    xx = (xx - meanA[it]) * rstdA[it] * lng[k+j] + lnb[k+j];
                    pk.u[j] = f2u(xx);
                }
                *(uint4*)&As[arow[it] * LDA + akk] = pk.v;
            } else {
                *(uint4*)&As[arow[it] * LDA + akk] = seg[it].d.v;
            }
        }
    };
    auto writeB = [&](SegRaw seg[NB]) {
        #pragma unroll
        for (int it = 0; it < NB; ++it) {
            const int s = tid + it * 256;
            if (s < BNT*4)
                *(uint4*)&Bs[(s >> 2) * LDA + (s & 3) * 8] = seg[it].d.v;
        }
    };

    SegRaw segA[2], segB[NB];
    loadA(0, segA); loadB(0, segB);

    for (int step = 0; step < nsteps; ++step) {
        writeA(step, segA);
        writeB(segB);
        __syncthreads();
        if (step + 1 < nsteps) { loadA(step+1, segA); loadB(step+1, segB); }
        s16x8 af[4], bfr[NF];
        #pragma unroll
        for (int mf = 0; mf < 4; ++mf)
            af[mf] = *(const s16x8*)&As[(wm + mf*16 + row16) * LDA + koff];
        #pragma unroll
        for (int nf = 0; nf < NF; ++nf)
            bfr[nf] = *(const s16x8*)&Bs[(wn + nf*16 + row16) * LDA + koff];
        #pragma unroll
        for (int mf = 0; mf < 4; ++mf)
            #pragma unroll
            for (int nf = 0; nf < NF; ++nf)
                acc[mf][nf] = __builtin_amdgcn_mfma_f32_16x16x32_bf16(
                    af[mf], bfr[nf], acc[mf][nf], 0, 0, 0);
        __syncthreads();
    }

    // ---- epilogue ----
    #pragma unroll
    for (int mf = 0; mf < 4; ++mf) {
        #pragma unroll
        for (int nf = 0; nf < NF; ++nf) {
            const int n = n0 + wn + nf*16 + row16;
            if (n >= N) continue;
            #pragma unroll
            for (int r = 0; r < 4; ++r) {
                const int m = m0 + wm + mf*16 + (lane >> 4)*4 + r;
                float v = acc[mf][nf][r] + (bias ? bias[n] : 0.f);
                if constexpr (EPI == 7) {
                    if (n < SPC) {
                        ((bf16*)Cv)[(size_t)m * SPC + n] = f2b(v);
                    } else {
                        bf16* chq = (bf16*)ep0;
                        chq[((size_t)(batch * HW) + m) * CHC + (n - SPC)] = f2b(v);
                    }
                    continue;
                }
                size_t outIdx;
                if constexpr (CPAD == 1) {
                    const int b = m >> 14, pix = m & 16383;
                    const int h = pix >> 7, w = pix & 127;
                    outIdx = ((size_t)b * PHW + (size_t)(h+1) * PH + (w+1)) * (size_t)N + n;
                } else if constexpr (EPI == 2) {
                    const int h2 = ((m >> 7) + 4) & 127;
                    const int w2 = ((m & 127) + 4) & 127;
                    outIdx = ((size_t)(batch * HW) + h2 * WR + w2) * (size_t)N + n;
                } else {
                    outIdx = (size_t)m * N + n;
                }
                if constexpr (EPI == 1) {
                    v = fmaxf(v, 0.f);
                } else if constexpr (EPI == 3) {
                    v = (v - ep2[n]) * rsqrtf(ep3[n] + 1e-5f) * ep0[n] + ep1[n];
                    v = fmaxf(v, 0.f);
                } else if constexpr (EPI == 4) {
                    const int b = m >> 14;
                    const float cold = CBF ? b2f(((const bf16*)Cv)[outIdx])
                                           : ((const float*)Cv)[outIdx];
                    v = cold + v * ep0[b * N + n];
                } else if constexpr (EPI == 5) {
                    v = 0.5f * v * (1.f + erff(v * 0.70710678118654752f));
                } else if constexpr (EPI == 6) {
                    v = ep0[outIdx] + v;
                }
                if constexpr (CBF) ((bf16*)Cv)[outIdx] = f2b(v);
                else               ((float*)Cv)[outIdx] = v;
            }
        }
    }
}

// =====================================================================
// weight prep: fp32 -> bf16 (same layout)
// =====================================================================
__global__ __launch_bounds__(256)
void wprep_lin_k(const float* __restrict__ in, bf16* __restrict__ outb, int n)
{
    const int i = blockIdx.x * 256 + threadIdx.x;
    if (i < n) outb[i] = f2b(in[i]);
}

// conv (O,I,3,3) -> bf16 [O][9*192] with k = tap*192 + c
__global__ __launch_bounds__(256)
void wprep_conv_k(const float* __restrict__ in, bf16* __restrict__ outb, int total)
{
    const int i = blockIdx.x * 256 + threadIdx.x;
    if (i >= total) return;
    const int n = i / 1728, r = i - n * 1728;
    const int tap = r / CCH, c = r - tap * CCH;
    outb[i] = f2b(in[((size_t)n * CCH + c) * 9 + tap]);
}

// zero borders of padded [8][130][130][192] bf16 buffer
__global__ __launch_bounds__(256)
void zb_k(bf16* __restrict__ buf)
{
    const int i = blockIdx.x * 256 + threadIdx.x;
    if (i >= 8 * 516 * 24) return;
    const int chunk = i % 24;
    const int p = (i / 24) % 516;
    const int b = i / (24 * 516);
    int h, w;
    if (p < 130)      { h = 0;   w = p; }
    else if (p < 260) { h = 129; w = p - 130; }
    else { const int q = p - 260; h = 1 + (q >> 1); w = (q & 1) ? 129 : 0; }
    *(uint4*)((u16*)buf + ((size_t)b * PHW + (size_t)h * PH + w) * CCH + chunk * 8)
        = (uint4){0u,0u,0u,0u};
}

// =====================================================================
// LN stats
// =====================================================================
__global__ __launch_bounds__(256)
void ln_stats_k(const float* __restrict__ x, float* __restrict__ stats)
{
    const int tok = blockIdx.x * 4 + (threadIdx.x >> 6);
    const int lane = threadIdx.x & 63;
    const float* r = x + (size_t)tok * CCH;
    float s = 0.f, sq = 0.f;
    for (int c = lane; c < CCH; c += 64) { float v = r[c]; s += v; sq += v*v; }
    for (int m = 1; m < 64; m <<= 1) { s += __shfl_xor(s, m); sq += __shfl_xor(sq, m); }
    if (lane == 0) {
        const float mean = s / (float)CCH;
        const float var = sq / (float)CCH - mean * mean;
        stats[(size_t)tok*2]   = mean;
        stats[(size_t)tok*2+1] = rsqrtf(var + 1e-5f);
    }
}

// =====================================================================
// Spatial shifted-window cosine attention, one batch (stride 432)
// =====================================================================
__global__ __launch_bounds__(256)
void sp_attn_k(const bf16* __restrict__ qkv, const float* __restrict__ rpb,
               const float* __restrict__ logit_sp, bf16* __restrict__ o)
{
    const int head = blockIdx.x;
    const int win  = blockIdx.y;
    const int wh = win >> 4, ww = win & 15;
    const int tid = threadIdx.x;

    __shared__ float q[64][25], k[64][25], v[64][25];
    __shared__ float attn[64][66];
    __shared__ float rq[64], rk[64];
    __shared__ int   lab[64];
    __shared__ float scale_s;

    for (int idx = tid; idx < 64*24*3; idx += 256) {
        const int which = idx / 1536;
        const int rem = idx - which * 1536;
        const int p = rem / 24, d = rem - (rem/24)*24;
        const int h = (wh*8 + (p >> 3) + 4) & 127;
        const int w = (ww*8 + (p & 7)  + 4) & 127;
        const float val = b2f(qkv[((size_t)(h*WR + w)) * SPC + head*72 + which*24 + d]);
        if (which == 0) q[p][d] = val;
        else if (which == 1) k[p][d] = val;
        else v[p][d] = val;
    }
    if (tid == 0) scale_s = expf(fminf(logit_sp[head], LOGMAX));
    __syncthreads();

    if (tid < 64) {
        float s = 0.f;
        #pragma unroll
        for (int d = 0; d < 24; ++d) s += q[tid][d]*q[tid][d];
        rq[tid] = 1.f / fmaxf(sqrtf(s), 1e-12f);
        const int h = wh*8 + (tid >> 3), w = ww*8 + (tid & 7);
        const int rh = h < 120 ? 0 : (h < 124 ? 1 : 2);
        const int rw = w < 120 ? 0 : (w < 124 ? 1 : 2);
        lab[tid] = rh*3 + rw;
    } else if (tid < 128) {
        const int i = tid - 64;
        float s = 0.f;
        #pragma unroll
        for (int d = 0; d < 24; ++d) s += k[i][d]*k[i][d];
        rk[i] = 1.f / fmaxf(sqrtf(s), 1e-12f);
    }
    __syncthreads();

    for (int e = tid; e < 4096; e += 256) {
        const int i = e >> 6, j = e & 63;
        float s = 0.f;
        #pragma unroll
        for (int d = 0; d < 24; ++d) s += q[i][d]*k[j][d];
        s = s * rq[i] * rk[j] * scale_s;
        const int r0 = (i >> 3) - (j >> 3) + 7;
        const int r1 = (i & 7) - (j & 7) + 7;
        s += rpb[(r0*15 + r1)*SPH + head];
        if (lab[i] != lab[j]) s -= 100.f;
        attn[i][j] = s;
    }
    __syncthreads();

    {
        const int r = tid >> 2, l = tid & 3;
        float mx = -1e30f;
        for (int j = l; j < 64; j += 4) mx = fmaxf(mx, attn[r][j]);
        mx = fmaxf(mx, __shfl_xor(mx, 1));
        mx = fmaxf(mx, __shfl_xor(mx, 2));
        float sum = 0.f;
        for (int j = l; j < 64; j += 4) { float e2 = expf(attn[r][j] - mx); attn[r][j] = e2; sum += e2; }
        sum += __shfl_xor(sum, 1);
        sum += __shfl_xor(sum, 2);
        const float inv = 1.f / sum;
        for (int j = l; j < 64; j += 4) attn[r][j] *= inv;
    }
    __syncthreads();

    for (int idx = tid; idx < 64*24; idx += 256) {
        const int i = idx / 24, d = idx - (idx/24)*24;
        float s = 0.f;
        #pragma unroll
        for (int j = 0; j < 64; ++j) s += attn[i][j] * v[j][d];
        const int h = wh*8 + (i >> 3), w = ww*8 + (i & 7);
        o[((size_t)(h*WR + w)) * 144 + head*24 + d] = f2b(s);
    }
}

// =====================================================================
// Channel attention, FULL batch; chqkv: [M][144] bf16
// =====================================================================
__global__ __launch_bounds__(256)
void ch_norm_k(const bf16* __restrict__ chqkv, float* __restrict__ rnorm)
{
    const int c = blockIdx.x;
    const int head = blockIdx.y;
    const int b = blockIdx.z;
    const bf16* base = chqkv + (size_t)b * HW * CHC + head * 72 + c;
    float s = 0.f;
    for (int i = threadIdx.x; i < HW; i += 256) { const float v = b2f(base[(size_t)i * CHC]); s += v*v; }
    for (int m = 1; m < 64; m <<= 1) s += __shfl_xor(s, m);
    __shared__ float red[4];
    if ((threadIdx.x & 63) == 0) red[threadIdx.x >> 6] = s;
    __syncthreads();
    if (threadIdx.x == 0)
        rnorm[(b*2 + head)*48 + c] = 1.f / fmaxf(sqrtf(red[0]+red[1]+red[2]+red[3]), 1e-12f);
}

__global__ __launch_bounds__(256)
void ch_attn_k(const bf16* __restrict__ chqkv, const float* __restrict__ rnorm,
               const float* __restrict__ logit_ch, float* __restrict__ attn_ch)
{
    const int c = blockIdx.x;
    const int head = blockIdx.y;
    const int b = blockIdx.z;
    const int tid = threadIdx.x;
    const bf16* base = chqkv + (size_t)b * HW * CHC + head * 72;
    float acc[24];
    #pragma unroll
    for (int d = 0; d < 24; ++d) acc[d] = 0.f;
    for (int i = tid; i < HW; i += 256) {
        const u16* row = (const u16*)(base + (size_t)i * CHC);
        const float qv = b2f(*(const bf16*)&row[c]);
        union { uint4 v; u16 u[8]; } kv[3];
        kv[0].v = *(const uint4*)(row + 24);
        kv[1].v = *(const uint4*)(row + 32);
        kv[2].v = *(const uint4*)(row + 40);
        #pragma unroll
        for (int d = 0; d < 24; ++d)
            acc[d] += qv * b2f(*(const bf16*)&kv[d>>3].u[d&7]);
    }
    #pragma unroll
    for (int d = 0; d < 24; ++d)
        for (int m = 1; m < 64; m <<= 1) acc[d] += __shfl_xor(acc[d], m);
    __shared__ float wsum[4][24];
    const int wid = tid >> 6, lane = tid & 63;
    if (lane == 0) {
        #pragma unroll
        for (int d = 0; d < 24; ++d) wsum[wid][d] = acc[d];
    }
    __syncthreads();
    if (tid == 0) {
        const float scale = expf(fminf(logit_ch[head], LOGMAX));
        const float* rn = rnorm + (b*2 + head)*48;
        float vals[24], mx = -1e30f;
        #pragma unroll
        for (int d = 0; d < 24; ++d) {
            const float rowv = wsum[0][d] + wsum[1][d] + wsum[2][d] + wsum[3][d];
            vals[d] = rowv * rn[c] * rn[24+d] * scale;
            mx = fmaxf(mx, vals[d]);
        }
        float sum = 0.f;
        #pragma unroll
        for (int d = 0; d < 24; ++d) { vals[d] = expf(vals[d] - mx); sum += vals[d]; }
        const float inv = 1.f / sum;
        float* outp = attn_ch + ((size_t)(b*2 + head)*24 + c)*24;
        #pragma unroll
        for (int d = 0; d < 24; ++d) outp[d] = vals[d]*inv;
    }
}

__global__ __launch_bounds__(256)
void ch_out_k(const bf16* __restrict__ chqkv, const float* __restrict__ attn_ch,
              const float* __restrict__ Wc, const float* __restrict__ bc,
              bf16* __restrict__ ch_out)
{
    const int pix0 = blockIdx.x * 64;
    const int b = blockIdx.y;
    const int tid = threadIdx.x;
    __shared__ float A2s[2][24][24];
    __shared__ float Wcs[192][48];
    __shared__ float bcs[192];
    __shared__ float vbuf[64][48];
    __shared__ float ocb[64][49];

    for (int idx = tid; idx < 2*24*24; idx += 256) {
        const int hh = idx / 576, rem = idx - hh*576;
        A2s[hh][rem/24][rem%24] = attn_ch[(size_t)b*1152 + idx];
    }
    for (int idx = tid; idx < 192*48; idx += 256) Wcs[idx/48][idx%48] = Wc[idx];
    if (tid < 192) bcs[tid] = bc[tid];
    for (int idx = tid; idx < 64*48; idx += 256) {
        const int p = idx / 48, c = idx - (idx/48)*48;
        const int head = c / 24, d = c - head*24;
        vbuf[p][c] = b2f(chqkv[((size_t)(b*HW + pix0 + p)) * CHC + head*72 + 48 + d]);
    }
    __syncthreads();
    for (int idx = tid; idx < 64*48; idx += 256) {
        const int p = idx / 48, c = idx - (idx/48)*48;
        const int head = c / 24, cc = c - head*24;
        float s = 0.f;
        #pragma unroll
        for (int d = 0; d < 24; ++d) s += A2s[head][cc][d] * vbuf[p][head*24 + d];
        ocb[p][c] = s;
    }
    __syncthreads();
    for (int idx = tid; idx < 64*192; idx += 256) {
        const int p = idx / 192, n = idx - (idx/192)*192;
        float s = bcs[n];
        #pragma unroll
        for (int c = 0; c < 48; ++c) s += ocb[p][c] * Wcs[n][c];
        ch_out[((size_t)(b*HW + pix0 + p)) * CCH + n] = f2b(s);
    }
}

// =====================================================================
// weight combiners
// =====================================================================
__global__ void combine_sp_k(const float* __restrict__ w_sp_proj, const float* __restrict__ w_spp,
                             const float* __restrict__ b_spp, bf16* __restrict__ Wc, float* __restrict__ bc)
{
    const int n = blockIdx.x;
    for (int i = threadIdx.x; i < 144; i += blockDim.x) {
        float s = 0.f;
        for (int j = 0; j < 144; ++j) s += w_sp_proj[n*144 + j] * w_spp[j*144 + i];
        Wc[n*144 + i] = f2b(s);
    }
    if (threadIdx.x == 0) {
        float s = 0.f;
        for (int j = 0; j < 144; ++j) s += w_sp_proj[n*144 + j] * b_spp[j];
        bc[n] = s;
    }
}

__global__ void combine_ch_k(const float* __restrict__ w_ch_proj, const float* __restrict__ w_chp,
                             const float* __restrict__ b_chp, float* __restrict__ Wc, float* __restrict__ bc)
{
    const int n = blockIdx.x;
    for (int c = threadIdx.x; c < 48; c += blockDim.x) {
        float s = 0.f;
        for (int j = 0; j < 48; ++j) s += w_ch_proj[n*48 + j] * w_chp[j*48 + c];
        Wc[n*48 + c] = s;
    }
    if (threadIdx.x == 0) {
        float s = 0.f;
        for (int j = 0; j < 48; ++j) s += w_ch_proj[n*48 + j] * b_chp[j];
        bc[n] = s;
    }
}

// =====================================================================
// per-(b,c) mean over H,W (bf16 src)
// =====================================================================
__global__ __launch_bounds__(256)
void mean_k(const bf16* __restrict__ src, float* __restrict__ dst)
{
    const int c = blockIdx.x, b = blockIdx.y;
    const bf16* base = src + (size_t)b * HW * CCH + c;
    float s = 0.f;
    for (int i = threadIdx.x; i < HW; i += 256) s += b2f(base[(size_t)i * CCH]);
    for (int m = 1; m < 64; m <<= 1) s += __shfl_xor(s, m);
    __shared__ float red[4];
    if ((threadIdx.x & 63) == 0) red[threadIdx.x >> 6] = s;
    __syncthreads();
    if (threadIdx.x == 0) dst[b*CCH + c] = (red[0]+red[1]+red[2]+red[3]) / (float)HW;
}

__global__ __launch_bounds__(192)
void gates_k(const float* __restrict__ meanv, const float* __restrict__ w1,
             const float* __restrict__ w2, const float* __restrict__ b2,
             float* __restrict__ gate)
{
    const int b = blockIdx.x;
    __shared__ float mv[192], hid[48];
    const int t = threadIdx.x;
    mv[t] = meanv[b*CCH + t];
    __syncthreads();
    if (t < 48) {
        float s = 0.f;
        for (int c = 0; c < 192; ++c) s += w1[t*192 + c] * mv[c];
        hid[t] = fmaxf(s, 0.f);
    }
    __syncthreads();
    float s = b2[t];
    for (int j = 0; j < 48; ++j) s += hid[j] * w2[t*48 + j];
    gate[b*CCH + t] = 1.f / (1.f + expf(-s));
}

// =====================================================================
// out = x + f2(padded) * (1 + sigmoid(relu(gpre)@w_sg2 + b))
// =====================================================================
__global__ __launch_bounds__(256)
void fuse_k(const float* __restrict__ x, const bf16* __restrict__ f2pad,
            const bf16* __restrict__ gpre, const float* __restrict__ w_sg2,
            const float* __restrict__ b_sg2, float* __restrict__ out)
{
    const int pix = blockIdx.x * 4 + (threadIdx.x >> 6);
    const int lane = threadIdx.x & 63;
    const bf16* gp = gpre + (size_t)pix * 96;
    float s = fmaxf(b2f(gp[lane]), 0.f) * w_sg2[lane];
    if (lane < 32) s += fmaxf(b2f(gp[lane + 64]), 0.f) * w_sg2[lane + 64];
    for (int m = 1; m < 64; m <<= 1) s += __shfl_xor(s, m);
    const float g1 = 1.f + 1.f / (1.f + expf(-(s + b_sg2[0])));
    const int b = pix >> 14, p = pix & 16383;
    const int h = p >> 7, w = p & 127;
    const bf16* fr = f2pad + ((size_t)b * PHW + (size_t)(h+1) * PH + (w+1)) * CCH;
    const float* xr = x + (size_t)pix * CCH;
    float* orow = out + (size_t)pix * CCH;
    for (int c = lane; c < CCH; c += 64) orow[c] = xr[c] + b2f(fr[c]) * g1;
}

// =====================================================================
// launcher
// =====================================================================
extern "C" void kernel_launch(void* const* d_in, const int* in_sizes, int n_in,
                              void* d_out, int out_size, void* d_ws, size_t ws_size,
                              hipStream_t stream)
{
    const float* x        = (const float*)d_in[0];
    const float* ln1_g    = (const float*)d_in[1];
    const float* ln1_b    = (const float*)d_in[2];
    const float* w_qkv    = (const float*)d_in[3];
    const float* b_qkv    = (const float*)d_in[4];
    const float* logit_sp = (const float*)d_in[5];
    const float* rpb      = (const float*)d_in[6];
    const float* w_spp    = (const float*)d_in[7];
    const float* b_spp    = (const float*)d_in[8];
    const float* logit_ch = (const float*)d_in[9];
    const float* w_chp    = (const float*)d_in[10];
    const float* b_chp    = (const float*)d_in[11];
    const float* w_sp_proj= (const float*)d_in[12];
    const float* w_ch_proj= (const float*)d_in[13];
    const float* w_s2c1   = (const float*)d_in[14];
    const float* w_s2c2   = (const float*)d_in[15];
    const float* b_s2c2   = (const float*)d_in[16];
    const float* w_c2s1   = (const float*)d_in[17];
    const float* w_c2s2   = (const float*)d_in[18];
    const float* b_c2s2   = (const float*)d_in[19];
    const float* w_gs1    = (const float*)d_in[20];
    const float* w_gs2    = (const float*)d_in[21];
    const float* b_gs2    = (const float*)d_in[22];
    const float* w_gc1    = (const float*)d_in[23];
    const float* w_gc2    = (const float*)d_in[24];
    const float* b_gc2    = (const float*)d_in[25];
    const float* w_f1     = (const float*)d_in[26];
    const float* bn1_g    = (const float*)d_in[27];
    const float* bn1_b    = (const float*)d_in[28];
    const float* bn1_m    = (const float*)d_in[29];
    const float* bn1_v    = (const float*)d_in[30];
    const float* w_f2     = (const float*)d_in[31];
    const float* bn2_g    = (const float*)d_in[32];
    const float* bn2_b    = (const float*)d_in[33];
    const float* bn2_m    = (const float*)d_in[34];
    const float* bn2_v    = (const float*)d_in[35];
    const float* w_sg1    = (const float*)d_in[36];
    const float* w_sg2    = (const float*)d_in[37];
    const float* b_sg2    = (const float*)d_in[38];
    const float* ln2_g    = (const float*)d_in[39];
    const float* ln2_b    = (const float*)d_in[40];
    const float* w_fc1    = (const float*)d_in[41];
    const float* b_fc1    = (const float*)d_in[42];
    const float* w_fc2    = (const float*)d_in[43];
    const float* b_fc2    = (const float*)d_in[44];

    char* wsb = (char*)d_ws;
    char* sm  = wsb + OFF_SMALL;
    float* out = (float*)d_out;

    bf16*  sp_out = (bf16*)(wsb + OFF_REG0);
    bf16*  f2pad  = (bf16*)(wsb + OFF_REG0);
    bf16*  ch_out = (bf16*)(wsb + OFF_REG1);
    bf16*  gpre   = (bf16*)(wsb + OFF_REG1);
    bf16*  chqkv  = (bf16*)(wsb + OFF_REG2);
    bf16*  fpad   = (bf16*)(wsb + OFF_REG2);
    bf16*  hidden = (bf16*)(wsb + OFF_REG2);
    bf16*  qkv_b  = (bf16*)(wsb + OFF_REG3);
    bf16*  osp_b  = (bf16*)(wsb + OFF_REG3 + 14155776);
    bf16*  hid_s  = (bf16*)(wsb + OFF_REG3);
    bf16*  hid_c  = (bf16*)(wsb + OFF_REG3 + 12582912);

    float* stats  = (float*)(sm + SO_STATS);
    float* rnorm  = (float*)(sm + SO_RNORM);
    float* attn_b = (float*)(sm + SO_ATTNB);
    float* mean_sp= (float*)(sm + SO_MEANSP);
    float* mean_ch= (float*)(sm + SO_MEANCH);
    float* gate_s = (float*)(sm + SO_GATES);
    float* gate_c = (float*)(sm + SO_GATEC);
    float* bc_sp  = (float*)(sm + SO_BCSP);
    float* Wc_ch  = (float*)(sm + SO_WCCH);
    float* bc_ch  = (float*)(sm + SO_BCCH);
    bf16*  Wc_spB = (bf16*)(sm + SO_WCSPB);
    u16*   wqB    = (u16*)(sm + SO_WQB);
    u16*   ws2c1B = (u16*)(sm + SO_WS2C1B);
    u16*   wc2s1B = (u16*)(sm + SO_WC2S1B);
    u16*   ws2c2B = (u16*)(sm + SO_WS2C2B);
    u16*   wc2s2B = (u16*)(sm + SO_WC2S2B);
    u16*   wf1B   = (u16*)(sm + SO_WF1B);
    u16*   wf2cB  = (u16*)(sm + SO_WF2CB);
    u16*   wsg1cB = (u16*)(sm + SO_WSG1CB);
    u16*   wfc1B  = (u16*)(sm + SO_WFC1B);
    u16*   wfc2B  = (u16*)(sm + SO_WFC2B);

    const dim3 blk(256);

    // ---- weight prep ----
    wprep_lin_k<<<(110592+255)/256, blk, 0, stream>>>(w_qkv,  (bf16*)wqB,    110592);
    wprep_lin_k<<<(9216+255)/256,   blk, 0, stream>>>(w_s2c1, (bf16*)ws2c1B, 9216);
    wprep_lin_k<<<(9216+255)/256,   blk, 0, stream>>>(w_c2s1, (bf16*)wc2s1B, 9216);
    wprep_lin_k<<<(9216+255)/256,   blk, 0, stream>>>(w_s2c2, (bf16*)ws2c2B, 9216);
    wprep_lin_k<<<(9216+255)/256,   blk, 0, stream>>>(w_c2s2, (bf16*)wc2s2B, 9216);
    wprep_lin_k<<<(73728+255)/256,  blk, 0, stream>>>(w_f1,   (bf16*)wf1B,   73728);
    wprep_lin_k<<<(147456+255)/256, blk, 0, stream>>>(w_fc1,  (bf16*)wfc1B,  147456);
    wprep_lin_k<<<(147456+255)/256, blk, 0, stream>>>(w_fc2,  (bf16*)wfc2B,  147456);
    wprep_conv_k<<<(331776+255)/256, blk, 0, stream>>>(w_f2,  (bf16*)wf2cB,  331776);
    wprep_conv_k<<<(165888+255)/256, blk, 0, stream>>>(w_sg1, (bf16*)wsg1cB, 165888);
    combine_sp_k<<<192, 128, 0, stream>>>(w_sp_proj, w_spp, b_spp, Wc_spB, bc_sp);
    combine_ch_k<<<192, 64, 0, stream>>>(w_ch_proj, w_chp, b_chp, Wc_ch, bc_ch);

    // ---- LN1 stats ----
    ln_stats_k<<<MTOK/4, blk, 0, stream>>>(x, stats);

    // ---- per-batch: qkv GEMM (split) -> spatial attn -> sp proj (roll store) ----
    for (int b = 0; b < BATCH; ++b) {
        gemm_k<1,7,1,192,0><<<dim3(3, HW/GBM), blk, 0, stream>>>(
            x + (size_t)b*HW*CCH, wqB, b_qkv, qkv_b, HW, 576, CCH,
            stats + (size_t)b*HW*2, ln1_g, ln1_b, nullptr,
            (const float*)chqkv, nullptr, nullptr, nullptr, b);

        sp_attn_k<<<dim3(SPH, NWIN), blk, 0, stream>>>(qkv_b, rpb, logit_sp, osp_b);

        gemm_k<0,2,1,192,0><<<dim3(1, HW/GBM), blk, 0, stream>>>(
            osp_b, (const u16*)Wc_spB, bc_sp, sp_out, HW, CCH, 144,
            nullptr, nullptr, nullptr, nullptr,
            nullptr, nullptr, nullptr, nullptr, b);
    }

    // ---- channel attention, full batch ----
    ch_norm_k<<<dim3(48, 2, BATCH), blk, 0, stream>>>(chqkv, rnorm);
    ch_attn_k<<<dim3(24, 2, BATCH), blk, 0, stream>>>(chqkv, rnorm, logit_ch, attn_b);
    ch_out_k<<<dim3(HW/64, BATCH), blk, 0, stream>>>(chqkv, attn_b, Wc_ch, bc_ch, ch_out);

    // ---- CFCA means/gates ----
    mean_k<<<dim3(CCH, BATCH), blk, 0, stream>>>(sp_out, mean_sp);
    mean_k<<<dim3(CCH, BATCH), blk, 0, stream>>>(ch_out, mean_ch);
    gates_k<<<BATCH, 192, 0, stream>>>(mean_sp, w_gs1, w_gs2, b_gs2, gate_s);
    gates_k<<<BATCH, 192, 0, stream>>>(mean_ch, w_gc1, w_gc2, b_gc2, gate_c);

    // ---- CFCA hiddens (both BEFORE the in-place gated adds) ----
    gemm_k<0,1,1,96,0><<<dim3(1, MTOK/GBM), blk, 0, stream>>>(
        sp_out, ws2c1B, nullptr, hid_s, MTOK, MIDC, CCH,
        nullptr, nullptr, nullptr, nullptr, nullptr, nullptr, nullptr, nullptr, 0);
    gemm_k<0,1,1,96,0><<<dim3(1, MTOK/GBM), blk, 0, stream>>>(
        ch_out, wc2s1B, nullptr, hid_c, MTOK, MIDC, CCH,
        nullptr, nullptr, nullptr, nullptr, nullptr, nullptr, nullptr, nullptr, 0);
    gemm_k<0,4,1,192,0><<<dim3(1, MTOK/GBM), blk, 0, stream>>>(
        hid_s, ws2c2B, b_s2c2, ch_out, MTOK, CCH, MIDC,
        nullptr, nullptr, nullptr, nullptr, gate_s, nullptr, nullptr, nullptr, 0);
    gemm_k<0,4,1,192,0><<<dim3(1, MTOK/GBM), blk, 0, stream>>>(
        hid_c, wc2s2B, b_c2s2, sp_out, MTOK, CCH, MIDC,
        nullptr, nullptr, nullptr, nullptr, gate_c, nullptr, nullptr, nullptr, 0);

    // ---- f = relu(bn1(concat @ w_f1^T)) -> PADDED fpad ----
    zb_k<<<(8*516*24+255)/256, blk, 0, stream>>>(fpad);
    gemm_k<2,3,1,192,1><<<dim3(1, MTOK/GBM), blk, 0, stream>>>(
        sp_out, wf1B, nullptr, fpad, MTOK, CCH, 2*CCH,
        nullptr, nullptr, nullptr, ch_out, bn1_g, bn1_b, bn1_m, bn1_v, 0);

    // ---- f2 = relu(bn2(conv3x3(f))) -> PADDED f2pad (over dead sp/ch region) ----
    zb_k<<<(8*516*24+255)/256, blk, 0, stream>>>(f2pad);
    gemm_k<3,3,1,192,1><<<dim3(1, MTOK/GBM), blk, 0, stream>>>(
        fpad, wf2cB, nullptr, f2pad, MTOK, CCH, 9*CCH,
        nullptr, nullptr, nullptr, nullptr, bn2_g, bn2_b, bn2_m, bn2_v, 0);

    // ---- gpre = conv3x3(f2) (96 ch, normal layout) ----
    gemm_k<3,0,1,96,0><<<dim3(1, MTOK/GBM), blk, 0, stream>>>(
        f2pad, wsg1cB, nullptr, gpre, MTOK, 96, 9*CCH,
        nullptr, nullptr, nullptr, nullptr, nullptr, nullptr, nullptr, nullptr, 0);

    // ---- xnew = x + f2*(1+g) -> d_out ----
    fuse_k<<<MTOK/4, blk, 0, stream>>>(x, f2pad, gpre, w_sg2, b_sg2, out);

    // ---- LN2 + MLP (chunked; hidden over dead fpad region) ----
    ln_stats_k<<<MTOK/4, blk, 0, stream>>>(out, stats);
    const int CHM = MTOK / 4;
    for (int c0 = 0; c0 < MTOK; c0 += CHM) {
        gemm_k<1,5,1,192,0><<<dim3(4, CHM/GBM), blk, 0, stream>>>(
            out + (size_t)c0*CCH, wfc1B, b_fc1, hidden, CHM, 4*CCH, CCH,
            stats + (size_t)c0*2, ln2_g, ln2_b, nullptr,
            nullptr, nullptr, nullptr, nullptr, 0);
        gemm_k<0,6,0,192,0><<<dim3(1, CHM/GBM), blk, 0, stream>>>(
            hidden, wfc2B, b_fc2, out + (size_t)c0*CCH, CHM, CCH, 4*CCH,
            nullptr, nullptr, nullptr, nullptr, out + (size_t)c0*CCH,
            nullptr, nullptr, nullptr, 0);
    }
}

// Round 6
// 1987.572 us; speedup vs baseline: 4.2977x; 1.2534x over previous
//
#include <hip/hip_runtime.h>
#include <hip/hip_bf16.h>
#include <cstddef>

typedef __hip_bfloat16 bf16;
typedef unsigned short u16;
typedef short s16x8 __attribute__((ext_vector_type(8)));
typedef float f32x4 __attribute__((ext_vector_type(4)));

// ---------------- problem constants ----------------
#define BATCH 8
#define HR 128
#define WR 128
#define CCH 192
#define HW (HR*WR)            // 16384
#define MTOK (BATCH*HW)       // 131072
#define SPH 6
#define SPC 432               // spatial qkv channels (heads 0..5)
#define CHC 144               // channel-head qkv channels (heads 6,7)
#define NWIN 256
#define MIDC 48
#define PH 130                // padded conv H/W
#define PHW (PH*PH)           // 16900
#define LOGMAX 4.6051701859880914f

// ---------------- ws layout (BYTE offsets; peak ~193 MB) ----------------
// A0: spqkv [M][432] (113.2MB) -> {sp_out [M][192] @0, ch_out [M][192] @+50.3MB}
//     -> {f2pad (51.9MB) @0, gpre (25.2MB) @+51.9MB}
// B0: chqkv [M][144] (37.7MB) -> {hid_s @0, hid_c @+12.6MB} -> fpad (51.9MB,
//     spills into dead C0) -> hidden (50.3MB per chunk)
// C0: osp [M][144] (37.7MB, dead after sp proj)
static const size_t OFF_A0    = 0;
static const size_t OFF_B0    = 113246208;
static const size_t OFF_C0    = 150994944;
static const size_t OFF_SMALL = 188743680;
static const size_t SO_STATS  = 0;          // fp32 2*M
static const size_t SO_PGRAM  = 1048576;    // fp32 [8][2][16][576]
static const size_t SO_PSS    = 1638400;    // fp32 [8][2][16][48]
static const size_t SO_ATTNB  = 1687552;    // fp32 [8][2][24][24]
static const size_t SO_MEANSP = 1724416;
static const size_t SO_MEANCH = 1732608;
static const size_t SO_GATES  = 1740800;
static const size_t SO_GATEC  = 1748992;
static const size_t SO_BCSP   = 1757184;    // fp32 192
static const size_t SO_WCCH   = 1758208;    // fp32 192*48
static const size_t SO_BCCH   = 1795072;    // fp32 192
static const size_t SO_WFUSE  = 1796096;    // bf16 [8][192][48]
static const size_t SO_WCSPB  = 1943552;    // bf16 192*144
static const size_t SO_WQB    = 1998848;    // bf16 576*192
static const size_t SO_WS2C1B = 2220032;    // bf16 48*192
static const size_t SO_WC2S1B = 2238464;
static const size_t SO_WS2C2B = 2256896;    // bf16 192*48
static const size_t SO_WC2S2B = 2275328;
static const size_t SO_WF1B   = 2293760;    // bf16 192*384
static const size_t SO_WF2CB  = 2441216;    // bf16 192*1728
static const size_t SO_WSG1CB = 3104768;    // bf16 96*1728
static const size_t SO_WFC1B  = 3436544;    // bf16 768*192
static const size_t SO_WFC2B  = 3731456;    // bf16 192*768

__device__ __forceinline__ float b2f(bf16 x) { return __bfloat162float(x); }
__device__ __forceinline__ bf16  f2b(float x){ return __float2bfloat16(x); }
__device__ __forceinline__ u16   f2u(float x){
    bf16 h = __float2bfloat16(x);
    union { bf16 b; u16 u; } c; c.b = h; return c.u;
}

// =====================================================================
// MFMA bf16 GEMM, register prefetch, bf16 B [N][K].
// block 256 thr = 4 waves (2x2), tile 128 x BNT, BK=32.
// AMODE: 0 plain bf16, 1 LN-fused (A fp32 + stats), 2 concat(A|A2 bf16),
//        3 implicit 3x3 conv over PADDED [8][130][130][192] bf16 input,
//        4 V-extract from chqkv [M][144] (k<24 -> col 48+k, else col 96+k)
// EPI: 0 bias, 1 relu, 2 roll(+4,+4)-store (batch from m), 3 BN+relu,
//      4 gated residual (C += v*gate[b]), 5 gelu, 6 residual add (fp32 ep0),
//      7 qkv split store (n<432 -> Cv stride 432; else chqkv via ep0)
// CBF: C bf16?  BNT: 96/192.  CPAD: padded conv store.  WPB: per-batch W (192x48)
// =====================================================================
#define GBM 128
#define GBK 32
#define LDA 40   // padded LDS row length in ushorts (80 B)

struct SegRaw { union { uint4 v; struct { float4 lo, hi; } f; } d; };

template<int AMODE, int EPI, int CBF, int BNT, int CPAD, int WPB>
__global__ __launch_bounds__(256)
void gemm_k(const void* __restrict__ A, const u16* __restrict__ W,
            const float* __restrict__ bias, void* __restrict__ Cv,
            int M, int N, int K,
            const float* __restrict__ stats, const float* __restrict__ lng,
            const float* __restrict__ lnb, const void* __restrict__ A2,
            const float* __restrict__ ep0, const float* __restrict__ ep1,
            const float* __restrict__ ep2, const float* __restrict__ ep3)
{
    constexpr int NF = BNT / 32;               // B frags per wave
    constexpr int NB = (BNT * 4 + 255) / 256;  // B segments per thread
    __shared__ u16 As[GBM * LDA];
    __shared__ u16 Bs[BNT * LDA];

    const int tid  = threadIdx.x;
    const int lane = tid & 63;
    const int wid  = tid >> 6;
    const int wm   = (wid >> 1) * 64;
    const int wn   = (wid & 1) * (BNT / 2);
    const int m0   = blockIdx.y * GBM;
    const int n0   = blockIdx.x * BNT;
    const int row16 = lane & 15;
    const int koff  = (lane >> 4) * 8;

    const int arow[2] = { tid >> 2, (tid + 256) >> 2 };
    const int akk     = (tid & 3) * 8;

    const u16* Wb = W;
    if constexpr (WPB) Wb = W + (size_t)(m0 >> 14) * 9216;  // [b][192][48]

    float meanA[2], rstdA[2];
    if constexpr (AMODE == 1) {
        #pragma unroll
        for (int it = 0; it < 2; ++it) {
            const int m = m0 + arow[it];
            meanA[it] = stats[2*m]; rstdA[it] = stats[2*m+1];
        }
    }

    f32x4 acc[4][NF];
    #pragma unroll
    for (int mf = 0; mf < 4; ++mf)
        #pragma unroll
        for (int nf = 0; nf < NF; ++nf)
            acc[mf][nf] = (f32x4){0.f, 0.f, 0.f, 0.f};

    const int nsteps = (K + GBK - 1) / GBK;

    auto loadA = [&](int step, SegRaw seg[2]) {
        const int k0 = step * GBK;
        #pragma unroll
        for (int it = 0; it < 2; ++it) {
            const int m = m0 + arow[it];
            const int k = k0 + akk;
            SegRaw& s = seg[it];
            if (k >= K) { s.d.v = (uint4){0u,0u,0u,0u}; continue; }
            if constexpr (AMODE == 0) {
                s.d.v = *(const uint4*)((const u16*)A + (size_t)m * K + k);
            } else if constexpr (AMODE == 1) {
                const float* p = (const float*)A + (size_t)m * K + k;
                s.d.f.lo = *(const float4*)p; s.d.f.hi = *(const float4*)(p+4);
            } else if constexpr (AMODE == 2) {
                const u16* src = (k < CCH) ? (const u16*)A  + (size_t)m * CCH + k
                                           : (const u16*)A2 + (size_t)m * CCH + (k - CCH);
                s.d.v = *(const uint4*)src;
            } else if constexpr (AMODE == 3) { // padded conv: always in-bounds
                const int tap = k / CCH, c = k - tap * CCH;
                const int ky = tap / 3, kx = tap - ky * 3;
                const int b = m >> 14, pix = m & 16383;
                const int h = pix >> 7, w = pix & 127;
                s.d.v = *(const uint4*)((const u16*)A +
                        ((size_t)b * PHW + (size_t)(h + ky) * PH + (w + kx)) * CCH + c);
            } else { // AMODE 4: V-extract from chqkv
                const int col = (k < 24) ? (48 + k) : (96 + k);
                s.d.v = *(const uint4*)((const u16*)A + (size_t)m * CHC + col);
            }
        }
    };
    auto loadB = [&](int step, SegRaw seg[NB]) {
        const int k0 = step * GBK;
        #pragma unroll
        for (int it = 0; it < NB; ++it) {
            const int s = tid + it * 256;
            const int n = n0 + (s >> 2);
            const int k = k0 + (s & 3) * 8;
            seg[it].d.v = (uint4){0u,0u,0u,0u};
            if (s < BNT*4 && k < K && n < N)
                seg[it].d.v = *(const uint4*)(Wb + (size_t)n * K + k);
        }
    };
    auto writeA = [&](int step, SegRaw seg[2]) {
        const int k0 = step * GBK;
        #pragma unroll
        for (int it = 0; it < 2; ++it) {
            if constexpr (AMODE == 1) {
                const int k = k0 + akk;
                union { u16 u[8]; uint4 v; } pk;
                #pragma unroll
                for (int j = 0; j < 8; ++j) {
                    float xx = (j < 4) ? seg[it].d.f.lo[j] : seg[it].d.f.hi[j-4];
                    xx = (xx - meanA[it]) * rstdA[it] * lng[k+j] + lnb[k+j];
                    pk.u[j] = f2u(xx);
                }
                *(uint4*)&As[arow[it] * LDA + akk] = pk.v;
            } else {
                *(uint4*)&As[arow[it] * LDA + akk] = seg[it].d.v;
            }
        }
    };
    auto writeB = [&](SegRaw seg[NB]) {
        #pragma unroll
        for (int it = 0; it < NB; ++it) {
            const int s = tid + it * 256;
            if (s < BNT*4)
                *(uint4*)&Bs[(s >> 2) * LDA + (s & 3) * 8] = seg[it].d.v;
        }
    };

    SegRaw segA[2], segB[NB];
    loadA(0, segA); loadB(0, segB);

    for (int step = 0; step < nsteps; ++step) {
        writeA(step, segA);
        writeB(segB);
        __syncthreads();
        if (step + 1 < nsteps) { loadA(step+1, segA); loadB(step+1, segB); }
        s16x8 af[4], bfr[NF];
        #pragma unroll
        for (int mf = 0; mf < 4; ++mf)
            af[mf] = *(const s16x8*)&As[(wm + mf*16 + row16) * LDA + koff];
        #pragma unroll
        for (int nf = 0; nf < NF; ++nf)
            bfr[nf] = *(const s16x8*)&Bs[(wn + nf*16 + row16) * LDA + koff];
        #pragma unroll
        for (int mf = 0; mf < 4; ++mf)
            #pragma unroll
            for (int nf = 0; nf < NF; ++nf)
                acc[mf][nf] = __builtin_amdgcn_mfma_f32_16x16x32_bf16(
                    af[mf], bfr[nf], acc[mf][nf], 0, 0, 0);
        __syncthreads();
    }

    // ---- epilogue ----
    #pragma unroll
    for (int mf = 0; mf < 4; ++mf) {
        #pragma unroll
        for (int nf = 0; nf < NF; ++nf) {
            const int n = n0 + wn + nf*16 + row16;
            if (n >= N) continue;
            #pragma unroll
            for (int r = 0; r < 4; ++r) {
                const int m = m0 + wm + mf*16 + (lane >> 4)*4 + r;
                float v = acc[mf][nf][r] + (bias ? bias[n] : 0.f);
                if constexpr (EPI == 7) {
                    if (n < SPC) {
                        ((bf16*)Cv)[(size_t)m * SPC + n] = f2b(v);
                    } else {
                        bf16* chq = (bf16*)ep0;
                        chq[(size_t)m * CHC + (n - SPC)] = f2b(v);
                    }
                    continue;
                }
                size_t outIdx;
                if constexpr (CPAD == 1) {
                    const int b = m >> 14, pix = m & 16383;
                    const int h = pix >> 7, w = pix & 127;
                    outIdx = ((size_t)b * PHW + (size_t)(h+1) * PH + (w+1)) * (size_t)N + n;
                } else if constexpr (EPI == 2) {
                    const int b = m >> 14, pix = m & 16383;
                    const int h2 = ((pix >> 7) + 4) & 127;
                    const int w2 = ((pix & 127) + 4) & 127;
                    outIdx = ((size_t)(b * HW) + h2 * WR + w2) * (size_t)N + n;
                } else {
                    outIdx = (size_t)m * N + n;
                }
                if constexpr (EPI == 1) {
                    v = fmaxf(v, 0.f);
                } else if constexpr (EPI == 3) {
                    v = (v - ep2[n]) * rsqrtf(ep3[n] + 1e-5f) * ep0[n] + ep1[n];
                    v = fmaxf(v, 0.f);
                } else if constexpr (EPI == 4) {
                    const int b = m >> 14;
                    const float cold = CBF ? b2f(((const bf16*)Cv)[outIdx])
                                           : ((const float*)Cv)[outIdx];
                    v = cold + v * ep0[b * N + n];
                } else if constexpr (EPI == 5) {
                    v = 0.5f * v * (1.f + erff(v * 0.70710678118654752f));
                } else if constexpr (EPI == 6) {
                    v = ep0[outIdx] + v;
                }
                if constexpr (CBF) ((bf16*)Cv)[outIdx] = f2b(v);
                else               ((float*)Cv)[outIdx] = v;
            }
        }
    }
}

// =====================================================================
// weight prep
// =====================================================================
__global__ __launch_bounds__(256)
void wprep_lin_k(const float* __restrict__ in, bf16* __restrict__ outb, int n)
{
    const int i = blockIdx.x * 256 + threadIdx.x;
    if (i < n) outb[i] = f2b(in[i]);
}

__global__ __launch_bounds__(256)
void wprep_conv_k(const float* __restrict__ in, bf16* __restrict__ outb, int total)
{
    const int i = blockIdx.x * 256 + threadIdx.x;
    if (i >= total) return;
    const int n = i / 1728, r = i - n * 1728;
    const int tap = r / CCH, c = r - tap * CCH;
    outb[i] = f2b(in[((size_t)n * CCH + c) * 9 + tap]);
}

__global__ __launch_bounds__(256)
void zb_k(bf16* __restrict__ buf)
{
    const int i = blockIdx.x * 256 + threadIdx.x;
    if (i >= 8 * 516 * 24) return;
    const int chunk = i % 24;
    const int p = (i / 24) % 516;
    const int b = i / (24 * 516);
    int h, w;
    if (p < 130)      { h = 0;   w = p; }
    else if (p < 260) { h = 129; w = p - 130; }
    else { const int q = p - 260; h = 1 + (q >> 1); w = (q & 1) ? 129 : 0; }
    *(uint4*)((u16*)buf + ((size_t)b * PHW + (size_t)h * PH + w) * CCH + chunk * 8)
        = (uint4){0u,0u,0u,0u};
}

// =====================================================================
// LN stats
// =====================================================================
__global__ __launch_bounds__(256)
void ln_stats_k(const float* __restrict__ x, float* __restrict__ stats)
{
    const int tok = blockIdx.x * 4 + (threadIdx.x >> 6);
    const int lane = threadIdx.x & 63;
    const float* r = x + (size_t)tok * CCH;
    float s = 0.f, sq = 0.f;
    for (int c = lane; c < CCH; c += 64) { float v = r[c]; s += v; sq += v*v; }
    for (int m = 1; m < 64; m <<= 1) { s += __shfl_xor(s, m); sq += __shfl_xor(sq, m); }
    if (lane == 0) {
        const float mean = s / (float)CCH;
        const float var = sq / (float)CCH - mean * mean;
        stats[(size_t)tok*2]   = mean;
        stats[(size_t)tok*2+1] = rsqrtf(var + 1e-5f);
    }
}

// =====================================================================
// Spatial shifted-window cosine attention, full batch (grid.z = batch)
// =====================================================================
__global__ __launch_bounds__(256)
void sp_attn_k(const bf16* __restrict__ spqkv, const float* __restrict__ rpb,
               const float* __restrict__ logit_sp, bf16* __restrict__ osp)
{
    const int head = blockIdx.x;
    const int win  = blockIdx.y;
    const int bb   = blockIdx.z;
    const int wh = win >> 4, ww = win & 15;
    const int tid = threadIdx.x;
    const bf16* qkv = spqkv + (size_t)bb * HW * SPC;
    bf16* o = osp + (size_t)bb * HW * 144;

    __shared__ float q[64][25], k[64][25], v[64][25];
    __shared__ float attn[64][66];
    __shared__ float rq[64], rk[64];
    __shared__ int   lab[64];
    __shared__ float scale_s;

    for (int idx = tid; idx < 64*24*3; idx += 256) {
        const int which = idx / 1536;
        const int rem = idx - which * 1536;
        const int p = rem / 24, d = rem - (rem/24)*24;
        const int h = (wh*8 + (p >> 3) + 4) & 127;
        const int w = (ww*8 + (p & 7)  + 4) & 127;
        const float val = b2f(qkv[((size_t)(h*WR + w)) * SPC + head*72 + which*24 + d]);
        if (which == 0) q[p][d] = val;
        else if (which == 1) k[p][d] = val;
        else v[p][d] = val;
    }
    if (tid == 0) scale_s = expf(fminf(logit_sp[head], LOGMAX));
    __syncthreads();

    if (tid < 64) {
        float s = 0.f;
        #pragma unroll
        for (int d = 0; d < 24; ++d) s += q[tid][d]*q[tid][d];
        rq[tid] = 1.f / fmaxf(sqrtf(s), 1e-12f);
        const int h = wh*8 + (tid >> 3), w = ww*8 + (tid & 7);
        const int rh = h < 120 ? 0 : (h < 124 ? 1 : 2);
        const int rw = w < 120 ? 0 : (w < 124 ? 1 : 2);
        lab[tid] = rh*3 + rw;
    } else if (tid < 128) {
        const int i = tid - 64;
        float s = 0.f;
        #pragma unroll
        for (int d = 0; d < 24; ++d) s += k[i][d]*k[i][d];
        rk[i] = 1.f / fmaxf(sqrtf(s), 1e-12f);
    }
    __syncthreads();

    for (int e = tid; e < 4096; e += 256) {
        const int i = e >> 6, j = e & 63;
        float s = 0.f;
        #pragma unroll
        for (int d = 0; d < 24; ++d) s += q[i][d]*k[j][d];
        s = s * rq[i] * rk[j] * scale_s;
        const int r0 = (i >> 3) - (j >> 3) + 7;
        const int r1 = (i & 7) - (j & 7) + 7;
        s += rpb[(r0*15 + r1)*SPH + head];
        if (lab[i] != lab[j]) s -= 100.f;
        attn[i][j] = s;
    }
    __syncthreads();

    {
        const int r = tid >> 2, l = tid & 3;
        float mx = -1e30f;
        for (int j = l; j < 64; j += 4) mx = fmaxf(mx, attn[r][j]);
        mx = fmaxf(mx, __shfl_xor(mx, 1));
        mx = fmaxf(mx, __shfl_xor(mx, 2));
        float sum = 0.f;
        for (int j = l; j < 64; j += 4) { float e2 = expf(attn[r][j] - mx); attn[r][j] = e2; sum += e2; }
        sum += __shfl_xor(sum, 1);
        sum += __shfl_xor(sum, 2);
        const float inv = 1.f / sum;
        for (int j = l; j < 64; j += 4) attn[r][j] *= inv;
    }
    __syncthreads();

    for (int idx = tid; idx < 64*24; idx += 256) {
        const int i = idx / 24, d = idx - (idx/24)*24;
        float s = 0.f;
        #pragma unroll
        for (int j = 0; j < 64; ++j) s += attn[i][j] * v[j][d];
        const int h = wh*8 + (i >> 3), w = ww*8 + (i & 7);
        o[((size_t)(h*WR + w)) * 144 + head*24 + d] = f2b(s);
    }
}

// =====================================================================
// Channel attention stage 1: partial gram (24x24) + column sum-squares,
// coalesced via LDS row tiles. grid (16, 2, 8)
// =====================================================================
__global__ __launch_bounds__(256)
void ch_part_k(const bf16* __restrict__ chqkv, float* __restrict__ pgram,
               float* __restrict__ pss)
{
    const int ci = blockIdx.x, head = blockIdx.y, b = blockIdx.z;
    const int tid = threadIdx.x;
    __shared__ u16 tile[256][48];
    float g[3] = {0.f, 0.f, 0.f};
    float ss = 0.f;
    const u16* src = (const u16*)chqkv + (size_t)b * HW * CHC + head * 72;
    const int rbase = ci * 1024;

    for (int t0 = 0; t0 < 1024; t0 += 256) {
        __syncthreads();
        for (int idx = tid; idx < 256*6; idx += 256) {
            const int row = idx / 6, seg = idx - (idx/6)*6;
            *(uint4*)&tile[row][seg*8] =
                *(const uint4*)(src + (size_t)(rbase + t0 + row) * CHC + seg*8);
        }
        __syncthreads();
        #pragma unroll
        for (int i = 0; i < 3; ++i) {
            const int e = tid + i*256;
            if (e < 576) {
                const int c = e / 24, d = e - (e/24)*24;
                float s = 0.f;
                for (int r = 0; r < 256; ++r)
                    s += b2f(*(const bf16*)&tile[r][c]) * b2f(*(const bf16*)&tile[r][24+d]);
                g[i] += s;
            }
        }
        if (tid < 48) {
            float s = 0.f;
            for (int r = 0; r < 256; ++r) { const float v = b2f(*(const bf16*)&tile[r][tid]); s += v*v; }
            ss += s;
        }
    }
    float* pg = pgram + ((size_t)(b*2+head)*16 + ci) * 576;
    #pragma unroll
    for (int i = 0; i < 3; ++i) { const int e = tid + i*256; if (e < 576) pg[e] = g[i]; }
    if (tid < 48) pss[((size_t)(b*2+head)*16 + ci) * 48 + tid] = ss;
}

// stage 2: reduce partials -> cosine scale -> softmax. grid (2, 8)
__global__ __launch_bounds__(256)
void ch_soft_k(const float* __restrict__ pgram, const float* __restrict__ pss,
               const float* __restrict__ logit_ch, float* __restrict__ attn)
{
    const int head = blockIdx.x, b = blockIdx.y;
    const int tid = threadIdx.x;
    __shared__ float gs[576], rn[48];
    for (int e = tid; e < 576; e += 256) {
        float s = 0.f;
        const float* pg = pgram + (size_t)(b*2+head)*16*576 + e;
        for (int c = 0; c < 16; ++c) s += pg[c*576];
        gs[e] = s;
    }
    if (tid < 48) {
        float s = 0.f;
        const float* ps = pss + (size_t)(b*2+head)*16*48 + tid;
        for (int c = 0; c < 16; ++c) s += ps[c*48];
        rn[tid] = 1.f / fmaxf(sqrtf(s), 1e-12f);
    }
    __syncthreads();
    if (tid < 24) {
        const float scale = expf(fminf(logit_ch[head], LOGMAX));
        float vals[24], mx = -1e30f;
        #pragma unroll
        for (int d = 0; d < 24; ++d) {
            vals[d] = gs[tid*24+d] * rn[tid] * rn[24+d] * scale;
            mx = fmaxf(mx, vals[d]);
        }
        float sum = 0.f;
        #pragma unroll
        for (int d = 0; d < 24; ++d) { vals[d] = expf(vals[d]-mx); sum += vals[d]; }
        const float inv = 1.f / sum;
        float* o = attn + ((size_t)(b*2+head)*24 + tid)*24;
        #pragma unroll
        for (int d = 0; d < 24; ++d) o[d] = vals[d]*inv;
    }
}

// Wfused[b][n][h*24+d] = sum_cc Wc[n][h*24+cc] * attn[b][h][cc][d]. grid 8 x 192thr
__global__ __launch_bounds__(192)
void fuse_chw_k(const float* __restrict__ Wc, const float* __restrict__ attn,
                bf16* __restrict__ Wf)
{
    const int b = blockIdx.x;
    const int n = threadIdx.x;
    __shared__ float As_[2][24][24];
    for (int e = n; e < 1152; e += 192) {
        const int h = e / 576, r = e - h*576;
        As_[h][r/24][r%24] = attn[(size_t)b*1152 + e];
    }
    __syncthreads();
    const float* wr = Wc + n*48;
    bf16* o = Wf + ((size_t)b*192 + n) * 48;
    for (int h = 0; h < 2; ++h)
        for (int d = 0; d < 24; ++d) {
            float s = 0.f;
            #pragma unroll
            for (int cc = 0; cc < 24; ++cc) s += wr[h*24+cc] * As_[h][cc][d];
            o[h*24+d] = f2b(s);
        }
}

// =====================================================================
// weight combiners
// =====================================================================
__global__ void combine_sp_k(const float* __restrict__ w_sp_proj, const float* __restrict__ w_spp,
                             const float* __restrict__ b_spp, bf16* __restrict__ Wc, float* __restrict__ bc)
{
    const int n = blockIdx.x;
    for (int i = threadIdx.x; i < 144; i += blockDim.x) {
        float s = 0.f;
        for (int j = 0; j < 144; ++j) s += w_sp_proj[n*144 + j] * w_spp[j*144 + i];
        Wc[n*144 + i] = f2b(s);
    }
    if (threadIdx.x == 0) {
        float s = 0.f;
        for (int j = 0; j < 144; ++j) s += w_sp_proj[n*144 + j] * b_spp[j];
        bc[n] = s;
    }
}

__global__ void combine_ch_k(const float* __restrict__ w_ch_proj, const float* __restrict__ w_chp,
                             const float* __restrict__ b_chp, float* __restrict__ Wc, float* __restrict__ bc)
{
    const int n = blockIdx.x;
    for (int c = threadIdx.x; c < 48; c += blockDim.x) {
        float s = 0.f;
        for (int j = 0; j < 48; ++j) s += w_ch_proj[n*48 + j] * w_chp[j*48 + c];
        Wc[n*48 + c] = s;
    }
    if (threadIdx.x == 0) {
        float s = 0.f;
        for (int j = 0; j < 48; ++j) s += w_ch_proj[n*48 + j] * b_chp[j];
        bc[n] = s;
    }
}

// =====================================================================
// per-(b,c) mean over H,W (bf16 src)
// =====================================================================
__global__ __launch_bounds__(256)
void mean_k(const bf16* __restrict__ src, float* __restrict__ dst)
{
    const int c = blockIdx.x, b = blockIdx.y;
    const bf16* base = src + (size_t)b * HW * CCH + c;
    float s = 0.f;
    for (int i = threadIdx.x; i < HW; i += 256) s += b2f(base[(size_t)i * CCH]);
    for (int m = 1; m < 64; m <<= 1) s += __shfl_xor(s, m);
    __shared__ float red[4];
    if ((threadIdx.x & 63) == 0) red[threadIdx.x >> 6] = s;
    __syncthreads();
    if (threadIdx.x == 0) dst[b*CCH + c] = (red[0]+red[1]+red[2]+red[3]) / (float)HW;
}

__global__ __launch_bounds__(192)
void gates_k(const float* __restrict__ meanv, const float* __restrict__ w1,
             const float* __restrict__ w2, const float* __restrict__ b2,
             float* __restrict__ gate)
{
    const int b = blockIdx.x;
    __shared__ float mv[192], hid[48];
    const int t = threadIdx.x;
    mv[t] = meanv[b*CCH + t];
    __syncthreads();
    if (t < 48) {
        float s = 0.f;
        for (int c = 0; c < 192; ++c) s += w1[t*192 + c] * mv[c];
        hid[t] = fmaxf(s, 0.f);
    }
    __syncthreads();
    float s = b2[t];
    for (int j = 0; j < 48; ++j) s += hid[j] * w2[t*48 + j];
    gate[b*CCH + t] = 1.f / (1.f + expf(-s));
}

// =====================================================================
// out = x + f2(padded) * (1 + sigmoid(relu(gpre)@w_sg2 + b))
// =====================================================================
__global__ __launch_bounds__(256)
void fuse_k(const float* __restrict__ x, const bf16* __restrict__ f2pad,
            const bf16* __restrict__ gpre, const float* __restrict__ w_sg2,
            const float* __restrict__ b_sg2, float* __restrict__ out)
{
    const int pix = blockIdx.x * 4 + (threadIdx.x >> 6);
    const int lane = threadIdx.x & 63;
    const bf16* gp = gpre + (size_t)pix * 96;
    float s = fmaxf(b2f(gp[lane]), 0.f) * w_sg2[lane];
    if (lane < 32) s += fmaxf(b2f(gp[lane + 64]), 0.f) * w_sg2[lane + 64];
    for (int m = 1; m < 64; m <<= 1) s += __shfl_xor(s, m);
    const float g1 = 1.f + 1.f / (1.f + expf(-(s + b_sg2[0])));
    const int b = pix >> 14, p = pix & 16383;
    const int h = p >> 7, w = p & 127;
    const bf16* fr = f2pad + ((size_t)b * PHW + (size_t)(h+1) * PH + (w+1)) * CCH;
    const float* xr = x + (size_t)pix * CCH;
    float* orow = out + (size_t)pix * CCH;
    for (int c = lane; c < CCH; c += 64) orow[c] = xr[c] + b2f(fr[c]) * g1;
}

// =====================================================================
// launcher
// =====================================================================
extern "C" void kernel_launch(void* const* d_in, const int* in_sizes, int n_in,
                              void* d_out, int out_size, void* d_ws, size_t ws_size,
                              hipStream_t stream)
{
    const float* x        = (const float*)d_in[0];
    const float* ln1_g    = (const float*)d_in[1];
    const float* ln1_b    = (const float*)d_in[2];
    const float* w_qkv    = (const float*)d_in[3];
    const float* b_qkv    = (const float*)d_in[4];
    const float* logit_sp = (const float*)d_in[5];
    const float* rpb      = (const float*)d_in[6];
    const float* w_spp    = (const float*)d_in[7];
    const float* b_spp    = (const float*)d_in[8];
    const float* logit_ch = (const float*)d_in[9];
    const float* w_chp    = (const float*)d_in[10];
    const float* b_chp    = (const float*)d_in[11];
    const float* w_sp_proj= (const float*)d_in[12];
    const float* w_ch_proj= (const float*)d_in[13];
    const float* w_s2c1   = (const float*)d_in[14];
    const float* w_s2c2   = (const float*)d_in[15];
    const float* b_s2c2   = (const float*)d_in[16];
    const float* w_c2s1   = (const float*)d_in[17];
    const float* w_c2s2   = (const float*)d_in[18];
    const float* b_c2s2   = (const float*)d_in[19];
    const float* w_gs1    = (const float*)d_in[20];
    const float* w_gs2    = (const float*)d_in[21];
    const float* b_gs2    = (const float*)d_in[22];
    const float* w_gc1    = (const float*)d_in[23];
    const float* w_gc2    = (const float*)d_in[24];
    const float* b_gc2    = (const float*)d_in[25];
    const float* w_f1     = (const float*)d_in[26];
    const float* bn1_g    = (const float*)d_in[27];
    const float* bn1_b    = (const float*)d_in[28];
    const float* bn1_m    = (const float*)d_in[29];
    const float* bn1_v    = (const float*)d_in[30];
    const float* w_f2     = (const float*)d_in[31];
    const float* bn2_g    = (const float*)d_in[32];
    const float* bn2_b    = (const float*)d_in[33];
    const float* bn2_m    = (const float*)d_in[34];
    const float* bn2_v    = (const float*)d_in[35];
    const float* w_sg1    = (const float*)d_in[36];
    const float* w_sg2    = (const float*)d_in[37];
    const float* b_sg2    = (const float*)d_in[38];
    const float* ln2_g    = (const float*)d_in[39];
    const float* ln2_b    = (const float*)d_in[40];
    const float* w_fc1    = (const float*)d_in[41];
    const float* b_fc1    = (const float*)d_in[42];
    const float* w_fc2    = (const float*)d_in[43];
    const float* b_fc2    = (const float*)d_in[44];

    char* wsb = (char*)d_ws;
    char* sm  = wsb + OFF_SMALL;
    float* out = (float*)d_out;

    bf16*  spqkv  = (bf16*)(wsb + OFF_A0);
    bf16*  sp_out = (bf16*)(wsb + OFF_A0);
    bf16*  ch_out = (bf16*)(wsb + OFF_A0 + 50331648);
    bf16*  f2pad  = (bf16*)(wsb + OFF_A0);
    bf16*  gpre   = (bf16*)(wsb + OFF_A0 + 51916800);
    bf16*  chqkv  = (bf16*)(wsb + OFF_B0);
    bf16*  hid_s  = (bf16*)(wsb + OFF_B0);
    bf16*  hid_c  = (bf16*)(wsb + OFF_B0 + 12582912);
    bf16*  fpad   = (bf16*)(wsb + OFF_B0);
    bf16*  hidden = (bf16*)(wsb + OFF_B0);
    bf16*  osp    = (bf16*)(wsb + OFF_C0);

    float* stats  = (float*)(sm + SO_STATS);
    float* pgram  = (float*)(sm + SO_PGRAM);
    float* pss    = (float*)(sm + SO_PSS);
    float* attn_b = (float*)(sm + SO_ATTNB);
    float* mean_sp= (float*)(sm + SO_MEANSP);
    float* mean_ch= (float*)(sm + SO_MEANCH);
    float* gate_s = (float*)(sm + SO_GATES);
    float* gate_c = (float*)(sm + SO_GATEC);
    float* bc_sp  = (float*)(sm + SO_BCSP);
    float* Wc_ch  = (float*)(sm + SO_WCCH);
    float* bc_ch  = (float*)(sm + SO_BCCH);
    bf16*  Wfuse  = (bf16*)(sm + SO_WFUSE);
    bf16*  Wc_spB = (bf16*)(sm + SO_WCSPB);
    u16*   wqB    = (u16*)(sm + SO_WQB);
    u16*   ws2c1B = (u16*)(sm + SO_WS2C1B);
    u16*   wc2s1B = (u16*)(sm + SO_WC2S1B);
    u16*   ws2c2B = (u16*)(sm + SO_WS2C2B);
    u16*   wc2s2B = (u16*)(sm + SO_WC2S2B);
    u16*   wf1B   = (u16*)(sm + SO_WF1B);
    u16*   wf2cB  = (u16*)(sm + SO_WF2CB);
    u16*   wsg1cB = (u16*)(sm + SO_WSG1CB);
    u16*   wfc1B  = (u16*)(sm + SO_WFC1B);
    u16*   wfc2B  = (u16*)(sm + SO_WFC2B);

    const dim3 blk(256);

    // ---- weight prep ----
    wprep_lin_k<<<(110592+255)/256, blk, 0, stream>>>(w_qkv,  (bf16*)wqB,    110592);
    wprep_lin_k<<<(9216+255)/256,   blk, 0, stream>>>(w_s2c1, (bf16*)ws2c1B, 9216);
    wprep_lin_k<<<(9216+255)/256,   blk, 0, stream>>>(w_c2s1, (bf16*)wc2s1B, 9216);
    wprep_lin_k<<<(9216+255)/256,   blk, 0, stream>>>(w_s2c2, (bf16*)ws2c2B, 9216);
    wprep_lin_k<<<(9216+255)/256,   blk, 0, stream>>>(w_c2s2, (bf16*)wc2s2B, 9216);
    wprep_lin_k<<<(73728+255)/256,  blk, 0, stream>>>(w_f1,   (bf16*)wf1B,   73728);
    wprep_lin_k<<<(147456+255)/256, blk, 0, stream>>>(w_fc1,  (bf16*)wfc1B,  147456);
    wprep_lin_k<<<(147456+255)/256, blk, 0, stream>>>(w_fc2,  (bf16*)wfc2B,  147456);
    wprep_conv_k<<<(331776+255)/256, blk, 0, stream>>>(w_f2,  (bf16*)wf2cB,  331776);
    wprep_conv_k<<<(165888+255)/256, blk, 0, stream>>>(w_sg1, (bf16*)wsg1cB, 165888);
    combine_sp_k<<<192, 128, 0, stream>>>(w_sp_proj, w_spp, b_spp, Wc_spB, bc_sp);
    combine_ch_k<<<192, 64, 0, stream>>>(w_ch_proj, w_chp, b_chp, Wc_ch, bc_ch);

    // ---- LN1 stats + full-M qkv GEMM (split store) ----
    ln_stats_k<<<MTOK/4, blk, 0, stream>>>(x, stats);
    gemm_k<1,7,1,192,0,0><<<dim3(3, MTOK/GBM), blk, 0, stream>>>(
        x, wqB, b_qkv, spqkv, MTOK, 576, CCH,
        stats, ln1_g, ln1_b, nullptr,
        (const float*)chqkv, nullptr, nullptr, nullptr);

    // ---- spatial attention (full batch) + sp proj (roll store) ----
    sp_attn_k<<<dim3(SPH, NWIN, BATCH), blk, 0, stream>>>(spqkv, rpb, logit_sp, osp);
    gemm_k<0,2,1,192,0,0><<<dim3(1, MTOK/GBM), blk, 0, stream>>>(
        osp, (const u16*)Wc_spB, bc_sp, sp_out, MTOK, CCH, 144,
        nullptr, nullptr, nullptr, nullptr,
        nullptr, nullptr, nullptr, nullptr);

    // ---- channel attention: partial gram -> softmax -> fused W -> GEMM ----
    ch_part_k<<<dim3(16, 2, BATCH), blk, 0, stream>>>(chqkv, pgram, pss);
    ch_soft_k<<<dim3(2, BATCH), blk, 0, stream>>>(pgram, pss, logit_ch, attn_b);
    fuse_chw_k<<<BATCH, 192, 0, stream>>>(Wc_ch, attn_b, Wfuse);
    gemm_k<4,0,1,192,0,1><<<dim3(1, MTOK/GBM), blk, 0, stream>>>(
        chqkv, (const u16*)Wfuse, bc_ch, ch_out, MTOK, CCH, 48,
        nullptr, nullptr, nullptr, nullptr,
        nullptr, nullptr, nullptr, nullptr);

    // ---- CFCA means/gates ----
    mean_k<<<dim3(CCH, BATCH), blk, 0, stream>>>(sp_out, mean_sp);
    mean_k<<<dim3(CCH, BATCH), blk, 0, stream>>>(ch_out, mean_ch);
    gates_k<<<BATCH, 192, 0, stream>>>(mean_sp, w_gs1, w_gs2, b_gs2, gate_s);
    gates_k<<<BATCH, 192, 0, stream>>>(mean_ch, w_gc1, w_gc2, b_gc2, gate_c);

    // ---- CFCA hiddens (chqkv dead now) + gated residual adds ----
    gemm_k<0,1,1,96,0,0><<<dim3(1, MTOK/GBM), blk, 0, stream>>>(
        sp_out, ws2c1B, nullptr, hid_s, MTOK, MIDC, CCH,
        nullptr, nullptr, nullptr, nullptr, nullptr, nullptr, nullptr, nullptr);
    gemm_k<0,1,1,96,0,0><<<dim3(1, MTOK/GBM), blk, 0, stream>>>(
        ch_out, wc2s1B, nullptr, hid_c, MTOK, MIDC, CCH,
        nullptr, nullptr, nullptr, nullptr, nullptr, nullptr, nullptr, nullptr);
    gemm_k<0,4,1,192,0,0><<<dim3(1, MTOK/GBM), blk, 0, stream>>>(
        hid_s, ws2c2B, b_s2c2, ch_out, MTOK, CCH, MIDC,
        nullptr, nullptr, nullptr, nullptr, gate_s, nullptr, nullptr, nullptr);
    gemm_k<0,4,1,192,0,0><<<dim3(1, MTOK/GBM), blk, 0, stream>>>(
        hid_c, wc2s2B, b_c2s2, sp_out, MTOK, CCH, MIDC,
        nullptr, nullptr, nullptr, nullptr, gate_c, nullptr, nullptr, nullptr);

    // ---- f = relu(bn1(concat @ w_f1^T)) -> PADDED fpad ----
    zb_k<<<(8*516*24+255)/256, blk, 0, stream>>>(fpad);
    gemm_k<2,3,1,192,1,0><<<dim3(1, MTOK/GBM), blk, 0, stream>>>(
        sp_out, wf1B, nullptr, fpad, MTOK, CCH, 2*CCH,
        nullptr, nullptr, nullptr, ch_out, bn1_g, bn1_b, bn1_m, bn1_v);

    // ---- f2 = relu(bn2(conv3x3(f))) -> PADDED f2pad ----
    zb_k<<<(8*516*24+255)/256, blk, 0, stream>>>(f2pad);
    gemm_k<3,3,1,192,1,0><<<dim3(1, MTOK/GBM), blk, 0, stream>>>(
        fpad, wf2cB, nullptr, f2pad, MTOK, CCH, 9*CCH,
        nullptr, nullptr, nullptr, nullptr, bn2_g, bn2_b, bn2_m, bn2_v);

    // ---- gpre = conv3x3(f2) (96 ch) ----
    gemm_k<3,0,1,96,0,0><<<dim3(1, MTOK/GBM), blk, 0, stream>>>(
        f2pad, wsg1cB, nullptr, gpre, MTOK, 96, 9*CCH,
        nullptr, nullptr, nullptr, nullptr, nullptr, nullptr, nullptr, nullptr);

    // ---- xnew = x + f2*(1+g) -> d_out ----
    fuse_k<<<MTOK/4, blk, 0, stream>>>(x, f2pad, gpre, w_sg2, b_sg2, out);

    // ---- LN2 + MLP (chunked; hidden over dead fpad region) ----
    ln_stats_k<<<MTOK/4, blk, 0, stream>>>(out, stats);
    const int CHM = MTOK / 4;
    for (int c0 = 0; c0 < MTOK; c0 += CHM) {
        gemm_k<1,5,1,192,0,0><<<dim3(4, CHM/GBM), blk, 0, stream>>>(
            out + (size_t)c0*CCH, wfc1B, b_fc1, hidden, CHM, 4*CCH, CCH,
            stats + (size_t)c0*2, ln2_g, ln2_b, nullptr,
            nullptr, nullptr, nullptr, nullptr);
        gemm_k<0,6,0,192,0,0><<<dim3(1, CHM/GBM), blk, 0, stream>>>(
            hidden, wfc2B, b_fc2, out + (size_t)c0*CCH, CHM, CCH, 4*CCH,
            nullptr, nullptr, nullptr, nullptr, out + (size_t)c0*CCH,
            nullptr, nullptr, nullptr);
    }
}

// Round 7
// 1761.770 us; speedup vs baseline: 4.8485x; 1.1282x over previous
//
#include <hip/hip_runtime.h>
#include <hip/hip_bf16.h>
#include <cstddef>

typedef __hip_bfloat16 bf16;
typedef unsigned short u16;
typedef unsigned int u32;
typedef short s16x8 __attribute__((ext_vector_type(8)));
typedef float f32x4 __attribute__((ext_vector_type(4)));

// ---------------- problem constants ----------------
#define BATCH 8
#define HR 128
#define WR 128
#define CCH 192
#define HW (HR*WR)            // 16384
#define MTOK (BATCH*HW)       // 131072
#define SPH 6
#define SPC 432               // spatial qkv channels (heads 0..5)
#define CHC 144               // channel-head qkv channels (heads 6,7)
#define NWIN 256
#define MIDC 48
#define PH 130                // padded conv H/W
#define PHW (PH*PH)           // 16900
#define LOGMAX 4.6051701859880914f

// ---------------- ws layout (BYTE offsets; peak ~193 MB) ----------------
static const size_t OFF_A0    = 0;
static const size_t OFF_B0    = 113246208;
static const size_t OFF_C0    = 150994944;
static const size_t OFF_SMALL = 188743680;
static const size_t SO_STATS  = 0;          // fp32 2*M
static const size_t SO_PGRAM  = 1048576;    // fp32 [8][2][16][576]
static const size_t SO_PSS    = 1638400;    // fp32 [8][2][16][48]
static const size_t SO_ATTNB  = 1687552;    // fp32 [8][2][24][24]
static const size_t SO_MEANSP = 1724416;
static const size_t SO_MEANCH = 1732608;
static const size_t SO_GATES  = 1740800;
static const size_t SO_GATEC  = 1748992;
static const size_t SO_BCSP   = 1757184;    // fp32 192
static const size_t SO_WCCH   = 1758208;    // fp32 192*48
static const size_t SO_BCCH   = 1795072;    // fp32 192
static const size_t SO_WFUSE  = 1796096;    // bf16 [8][192][48]
static const size_t SO_WCSPB  = 1943552;    // bf16 192*144
static const size_t SO_WQB    = 1998848;    // bf16 576*192
static const size_t SO_WS2C1B = 2220032;    // bf16 48*192
static const size_t SO_WC2S1B = 2238464;
static const size_t SO_WS2C2B = 2256896;    // bf16 192*48
static const size_t SO_WC2S2B = 2275328;
static const size_t SO_WF1B   = 2293760;    // bf16 192*384
static const size_t SO_WF2CB  = 2441216;    // bf16 192*1728
static const size_t SO_WSG1CB = 3104768;    // bf16 96*1728
static const size_t SO_WFC1B  = 3436544;    // bf16 768*192
static const size_t SO_WFC2B  = 3731456;    // bf16 192*768

__device__ __forceinline__ float b2f(bf16 x) { return __bfloat162float(x); }
__device__ __forceinline__ bf16  f2b(float x){ return __float2bfloat16(x); }
__device__ __forceinline__ u16   f2u(float x){
    bf16 h = __float2bfloat16(x);
    union { bf16 b; u16 u; } c; c.b = h; return c.u;
}
__device__ __forceinline__ float s2f(short s){
    union { u16 u; bf16 b; } c; c.u = (u16)s; return b2f(c.b);
}

// =====================================================================
// MFMA bf16 GEMM, register prefetch, bf16 B [N][K].
// block 256 thr = 4 waves (2x2), tile 128 x BNT, BK=32.
// AMODE: 0 plain bf16, 1 LN-fused (A fp32 + stats), 2 concat(A|A2 bf16),
//        3 implicit 3x3 conv over PADDED input, 4 V-extract from chqkv
// EPI: 0 bias, 1 relu, 2 roll-store, 3 BN+relu, 4 gated residual,
//      5 gelu, 6 residual add (fp32 ep0), 7 qkv split store
// =====================================================================
#define GBM 128
#define GBK 32
#define LDA 40   // padded LDS row length in ushorts (80 B)

struct SegRaw { union { uint4 v; struct { float4 lo, hi; } f; } d; };

template<int AMODE, int EPI, int CBF, int BNT, int CPAD, int WPB>
__global__ __launch_bounds__(256)
void gemm_k(const void* __restrict__ A, const u16* __restrict__ W,
            const float* __restrict__ bias, void* __restrict__ Cv,
            int M, int N, int K,
            const float* __restrict__ stats, const float* __restrict__ lng,
            const float* __restrict__ lnb, const void* __restrict__ A2,
            const float* __restrict__ ep0, const float* __restrict__ ep1,
            const float* __restrict__ ep2, const float* __restrict__ ep3)
{
    constexpr int NF = BNT / 32;
    constexpr int NB = (BNT * 4 + 255) / 256;
    __shared__ u16 As[GBM * LDA];
    __shared__ u16 Bs[BNT * LDA];

    const int tid  = threadIdx.x;
    const int lane = tid & 63;
    const int wid  = tid >> 6;
    const int wm   = (wid >> 1) * 64;
    const int wn   = (wid & 1) * (BNT / 2);
    const int m0   = blockIdx.y * GBM;
    const int n0   = blockIdx.x * BNT;
    const int row16 = lane & 15;
    const int koff  = (lane >> 4) * 8;

    const int arow[2] = { tid >> 2, (tid + 256) >> 2 };
    const int akk     = (tid & 3) * 8;

    const u16* Wb = W;
    if constexpr (WPB) Wb = W + (size_t)(m0 >> 14) * 9216;

    float meanA[2], rstdA[2];
    if constexpr (AMODE == 1) {
        #pragma unroll
        for (int it = 0; it < 2; ++it) {
            const int m = m0 + arow[it];
            meanA[it] = stats[2*m]; rstdA[it] = stats[2*m+1];
        }
    }

    f32x4 acc[4][NF];
    #pragma unroll
    for (int mf = 0; mf < 4; ++mf)
        #pragma unroll
        for (int nf = 0; nf < NF; ++nf)
            acc[mf][nf] = (f32x4){0.f, 0.f, 0.f, 0.f};

    const int nsteps = (K + GBK - 1) / GBK;

    auto loadA = [&](int step, SegRaw seg[2]) {
        const int k0 = step * GBK;
        #pragma unroll
        for (int it = 0; it < 2; ++it) {
            const int m = m0 + arow[it];
            const int k = k0 + akk;
            SegRaw& s = seg[it];
            if (k >= K) { s.d.v = (uint4){0u,0u,0u,0u}; continue; }
            if constexpr (AMODE == 0) {
                s.d.v = *(const uint4*)((const u16*)A + (size_t)m * K + k);
            } else if constexpr (AMODE == 1) {
                const float* p = (const float*)A + (size_t)m * K + k;
                s.d.f.lo = *(const float4*)p; s.d.f.hi = *(const float4*)(p+4);
            } else if constexpr (AMODE == 2) {
                const u16* src = (k < CCH) ? (const u16*)A  + (size_t)m * CCH + k
                                           : (const u16*)A2 + (size_t)m * CCH + (k - CCH);
                s.d.v = *(const uint4*)src;
            } else if constexpr (AMODE == 3) {
                const int tap = k / CCH, c = k - tap * CCH;
                const int ky = tap / 3, kx = tap - ky * 3;
                const int b = m >> 14, pix = m & 16383;
                const int h = pix >> 7, w = pix & 127;
                s.d.v = *(const uint4*)((const u16*)A +
                        ((size_t)b * PHW + (size_t)(h + ky) * PH + (w + kx)) * CCH + c);
            } else {
                const int col = (k < 24) ? (48 + k) : (96 + k);
                s.d.v = *(const uint4*)((const u16*)A + (size_t)m * CHC + col);
            }
        }
    };
    auto loadB = [&](int step, SegRaw seg[NB]) {
        const int k0 = step * GBK;
        #pragma unroll
        for (int it = 0; it < NB; ++it) {
            const int s = tid + it * 256;
            const int n = n0 + (s >> 2);
            const int k = k0 + (s & 3) * 8;
            seg[it].d.v = (uint4){0u,0u,0u,0u};
            if (s < BNT*4 && k < K && n < N)
                seg[it].d.v = *(const uint4*)(Wb + (size_t)n * K + k);
        }
    };
    auto writeA = [&](int step, SegRaw seg[2]) {
        const int k0 = step * GBK;
        #pragma unroll
        for (int it = 0; it < 2; ++it) {
            if constexpr (AMODE == 1) {
                const int k = k0 + akk;
                union { u16 u[8]; uint4 v; } pk;
                #pragma unroll
                for (int j = 0; j < 8; ++j) {
                    float xx = (j < 4) ? seg[it].d.f.lo[j] : seg[it].d.f.hi[j-4];
                    xx = (xx - meanA[it]) * rstdA[it] * lng[k+j] + lnb[k+j];
                    pk.u[j] = f2u(xx);
                }
                *(uint4*)&As[arow[it] * LDA + akk] = pk.v;
            } else {
                *(uint4*)&As[arow[it] * LDA + akk] = seg[it].d.v;
            }
        }
    };
    auto writeB = [&](SegRaw seg[NB]) {
        #pragma unroll
        for (int it = 0; it < NB; ++it) {
            const int s = tid + it * 256;
            if (s < BNT*4)
                *(uint4*)&Bs[(s >> 2) * LDA + (s & 3) * 8] = seg[it].d.v;
        }
    };

    SegRaw segA[2], segB[NB];
    loadA(0, segA); loadB(0, segB);

    for (int step = 0; step < nsteps; ++step) {
        writeA(step, segA);
        writeB(segB);
        __syncthreads();
        if (step + 1 < nsteps) { loadA(step+1, segA); loadB(step+1, segB); }
        s16x8 af[4], bfr[NF];
        #pragma unroll
        for (int mf = 0; mf < 4; ++mf)
            af[mf] = *(const s16x8*)&As[(wm + mf*16 + row16) * LDA + koff];
        #pragma unroll
        for (int nf = 0; nf < NF; ++nf)
            bfr[nf] = *(const s16x8*)&Bs[(wn + nf*16 + row16) * LDA + koff];
        #pragma unroll
        for (int mf = 0; mf < 4; ++mf)
            #pragma unroll
            for (int nf = 0; nf < NF; ++nf)
                acc[mf][nf] = __builtin_amdgcn_mfma_f32_16x16x32_bf16(
                    af[mf], bfr[nf], acc[mf][nf], 0, 0, 0);
        __syncthreads();
    }

    #pragma unroll
    for (int mf = 0; mf < 4; ++mf) {
        #pragma unroll
        for (int nf = 0; nf < NF; ++nf) {
            const int n = n0 + wn + nf*16 + row16;
            if (n >= N) continue;
            #pragma unroll
            for (int r = 0; r < 4; ++r) {
                const int m = m0 + wm + mf*16 + (lane >> 4)*4 + r;
                float v = acc[mf][nf][r] + (bias ? bias[n] : 0.f);
                if constexpr (EPI == 7) {
                    if (n < SPC) {
                        ((bf16*)Cv)[(size_t)m * SPC + n] = f2b(v);
                    } else {
                        bf16* chq = (bf16*)ep0;
                        chq[(size_t)m * CHC + (n - SPC)] = f2b(v);
                    }
                    continue;
                }
                size_t outIdx;
                if constexpr (CPAD == 1) {
                    const int b = m >> 14, pix = m & 16383;
                    const int h = pix >> 7, w = pix & 127;
                    outIdx = ((size_t)b * PHW + (size_t)(h+1) * PH + (w+1)) * (size_t)N + n;
                } else if constexpr (EPI == 2) {
                    const int b = m >> 14, pix = m & 16383;
                    const int h2 = ((pix >> 7) + 4) & 127;
                    const int w2 = ((pix & 127) + 4) & 127;
                    outIdx = ((size_t)(b * HW) + h2 * WR + w2) * (size_t)N + n;
                } else {
                    outIdx = (size_t)m * N + n;
                }
                if constexpr (EPI == 1) {
                    v = fmaxf(v, 0.f);
                } else if constexpr (EPI == 3) {
                    v = (v - ep2[n]) * rsqrtf(ep3[n] + 1e-5f) * ep0[n] + ep1[n];
                    v = fmaxf(v, 0.f);
                } else if constexpr (EPI == 4) {
                    const int b = m >> 14;
                    const float cold = CBF ? b2f(((const bf16*)Cv)[outIdx])
                                           : ((const float*)Cv)[outIdx];
                    v = cold + v * ep0[b * N + n];
                } else if constexpr (EPI == 5) {
                    v = 0.5f * v * (1.f + erff(v * 0.70710678118654752f));
                } else if constexpr (EPI == 6) {
                    v = ep0[outIdx] + v;
                }
                if constexpr (CBF) ((bf16*)Cv)[outIdx] = f2b(v);
                else               ((float*)Cv)[outIdx] = v;
            }
        }
    }
}

// =====================================================================
// weight prep
// =====================================================================
__global__ __launch_bounds__(256)
void wprep_lin_k(const float* __restrict__ in, bf16* __restrict__ outb, int n)
{
    const int i = blockIdx.x * 256 + threadIdx.x;
    if (i < n) outb[i] = f2b(in[i]);
}

__global__ __launch_bounds__(256)
void wprep_conv_k(const float* __restrict__ in, bf16* __restrict__ outb, int total)
{
    const int i = blockIdx.x * 256 + threadIdx.x;
    if (i >= total) return;
    const int n = i / 1728, r = i - n * 1728;
    const int tap = r / CCH, c = r - tap * CCH;
    outb[i] = f2b(in[((size_t)n * CCH + c) * 9 + tap]);
}

__global__ __launch_bounds__(256)
void zb_k(bf16* __restrict__ buf)
{
    const int i = blockIdx.x * 256 + threadIdx.x;
    if (i >= 8 * 516 * 24) return;
    const int chunk = i % 24;
    const int p = (i / 24) % 516;
    const int b = i / (24 * 516);
    int h, w;
    if (p < 130)      { h = 0;   w = p; }
    else if (p < 260) { h = 129; w = p - 130; }
    else { const int q = p - 260; h = 1 + (q >> 1); w = (q & 1) ? 129 : 0; }
    *(uint4*)((u16*)buf + ((size_t)b * PHW + (size_t)h * PH + w) * CCH + chunk * 8)
        = (uint4){0u,0u,0u,0u};
}

// =====================================================================
// LN stats
// =====================================================================
__global__ __launch_bounds__(256)
void ln_stats_k(const float* __restrict__ x, float* __restrict__ stats)
{
    const int tok = blockIdx.x * 4 + (threadIdx.x >> 6);
    const int lane = threadIdx.x & 63;
    const float* r = x + (size_t)tok * CCH;
    float s = 0.f, sq = 0.f;
    for (int c = lane; c < CCH; c += 64) { float v = r[c]; s += v; sq += v*v; }
    for (int m = 1; m < 64; m <<= 1) { s += __shfl_xor(s, m); sq += __shfl_xor(sq, m); }
    if (lane == 0) {
        const float mean = s / (float)CCH;
        const float var = sq / (float)CCH - mean * mean;
        stats[(size_t)tok*2]   = mean;
        stats[(size_t)tok*2+1] = rsqrtf(var + 1e-5f);
    }
}

// =====================================================================
// MFMA spatial shifted-window cosine attention.
// Block = 384 thr = 6 waves = 6 heads of one window. Grid = BATCH*NWIN.
// Per wave: S^T = mfma(K,Q) (4x4 tiles, K-dim 24 pad 32); softmax in-reg;
// P redistributed to A-frag layout via 64 shfls; PV = mfma(P, V^T from LDS).
// =====================================================================
__global__ __launch_bounds__(384)
void sp_attn_k(const bf16* __restrict__ spqkv, const float* __restrict__ rpb,
               const float* __restrict__ logit_sp, bf16* __restrict__ osp)
{
    const int b    = blockIdx.x >> 8;
    const int win  = blockIdx.x & 255;
    const int wh = win >> 4, ww = win & 15;
    const int head = threadIdx.x >> 6;
    const int lane = threadIdx.x & 63;
    const int row16 = lane & 15;
    const int hi   = lane >> 4;
    const int koff = hi * 8;

    __shared__ float rpbS[1350];
    __shared__ u16 vT[SPH][32][72];

    for (int i = threadIdx.x; i < 1350; i += 384) rpbS[i] = rpb[i];

    const u16* base = (const u16*)spqkv + (size_t)b * HW * SPC;

    // ---- q (B-op) / k (A-op) fragments straight from global ----
    s16x8 qf[4], kf[4];
    const int wcol = (ww*8 + (row16 & 7) + 4) & 127;
    #pragma unroll
    for (int t = 0; t < 4; ++t) {
        const int pos = t*16 + row16;
        const int h = (wh*8 + (pos >> 3) + 4) & 127;
        const u16* rowp = base + ((size_t)(h * WR + wcol)) * SPC + head * 72;
        if (koff < 24) {
            qf[t] = *(const s16x8*)(rowp + koff);
            kf[t] = *(const s16x8*)(rowp + 24 + koff);
        } else {
            qf[t] = (s16x8){0,0,0,0,0,0,0,0};
            kf[t] = (s16x8){0,0,0,0,0,0,0,0};
        }
    }

    // ---- stage V transposed into per-wave LDS ----
    {
        const int h = (wh*8 + (lane >> 3) + 4) & 127;
        const int w = (ww*8 + (lane & 7) + 4) & 127;
        const u16* vrow = base + ((size_t)(h * WR + w)) * SPC + head * 72 + 48;
        union { uint4 v; u16 u[8]; } seg[3];
        seg[0].v = *(const uint4*)(vrow);
        seg[1].v = *(const uint4*)(vrow + 8);
        seg[2].v = *(const uint4*)(vrow + 16);
        #pragma unroll
        for (int d = 0; d < 24; ++d) vT[head][d][lane] = seg[d>>3].u[d&7];
        #pragma unroll
        for (int d = 24; d < 32; ++d) vT[head][d][lane] = 0;
    }
    __syncthreads();

    // ---- cosine norms (per q-row / k-row) ----
    float rq[4], rk[4];
    #pragma unroll
    for (int t = 0; t < 4; ++t) {
        float sq = 0.f, sk = 0.f;
        #pragma unroll
        for (int e = 0; e < 8; ++e) {
            const float a = s2f(qf[t][e]); sq += a*a;
            const float c = s2f(kf[t][e]); sk += c*c;
        }
        sq += __shfl_xor(sq, 16); sq += __shfl_xor(sq, 32);
        sk += __shfl_xor(sk, 16); sk += __shfl_xor(sk, 32);
        rq[t] = 1.f / fmaxf(sqrtf(sq), 1e-12f);
        rk[t] = 1.f / fmaxf(sqrtf(sk), 1e-12f);
    }
    const float scale_h = __expf(fminf(logit_sp[head], LOGMAX));

    // ---- S^T = mfma(K, Q): acc[mfk][nfq], col=q-row, row=k-idx ----
    f32x4 acc[4][4];
    #pragma unroll
    for (int mfk = 0; mfk < 4; ++mfk)
        #pragma unroll
        for (int nfq = 0; nfq < 4; ++nfq)
            acc[mfk][nfq] = (f32x4){0.f,0.f,0.f,0.f};
    #pragma unroll
    for (int mfk = 0; mfk < 4; ++mfk)
        #pragma unroll
        for (int nfq = 0; nfq < 4; ++nfq)
            acc[mfk][nfq] = __builtin_amdgcn_mfma_f32_16x16x32_bf16(
                kf[mfk], qf[nfq], acc[mfk][nfq], 0, 0, 0);

    // rk for j-rows: rk_j = shfl(rk[mfk], hi*4+r)
    f32x4 rkj[4];
    #pragma unroll
    for (int mfk = 0; mfk < 4; ++mfk)
        #pragma unroll
        for (int r = 0; r < 4; ++r)
            rkj[mfk][r] = __shfl(rk[mfk], hi*4 + r);

    // per-lane i geometry (i = q-pos = row16 + 16*nfq), unrolled coords
    int ip3[4], iw7[4], labi[4];
    #pragma unroll
    for (int t = 0; t < 4; ++t) {
        const int pos = t*16 + row16;
        ip3[t] = pos >> 3; iw7[t] = pos & 7;
        const int hh = wh*8 + ip3[t], w0 = ww*8 + iw7[t];
        const int rh = hh < 120 ? 0 : (hh < 124 ? 1 : 2);
        const int rw = w0 < 120 ? 0 : (w0 < 124 ? 1 : 2);
        labi[t] = rh*3 + rw;
    }

    // ---- scale + rpb + mask ----
    #pragma unroll
    for (int mfk = 0; mfk < 4; ++mfk) {
        #pragma unroll
        for (int r = 0; r < 4; ++r) {
            const int j = hi*4 + r + 16*mfk;
            const int jp3 = j >> 3, jw7 = j & 7;
            const int hh = wh*8 + jp3, w0 = ww*8 + jw7;
            const int rh = hh < 120 ? 0 : (hh < 124 ? 1 : 2);
            const int rw = w0 < 120 ? 0 : (w0 < 124 ? 1 : 2);
            const int labj = rh*3 + rw;
            const float rkv = rkj[mfk][r];
            #pragma unroll
            for (int nfq = 0; nfq < 4; ++nfq) {
                float s = acc[mfk][nfq][r] * rq[nfq] * rkv * scale_h;
                s += rpbS[((ip3[nfq]-jp3+7)*15 + (iw7[nfq]-jw7+7))*SPH + head];
                if (labi[nfq] != labj) s -= 100.f;
                acc[mfk][nfq][r] = s;
            }
        }
    }

    // ---- row softmax (row = q-row; k spread over regs+frags+lane-groups) ----
    float inv[4];
    #pragma unroll
    for (int nfq = 0; nfq < 4; ++nfq) {
        float m = -1e30f;
        #pragma unroll
        for (int mfk = 0; mfk < 4; ++mfk)
            #pragma unroll
            for (int r = 0; r < 4; ++r)
                m = fmaxf(m, acc[mfk][nfq][r]);
        m = fmaxf(m, __shfl_xor(m, 16));
        m = fmaxf(m, __shfl_xor(m, 32));
        float s = 0.f;
        #pragma unroll
        for (int mfk = 0; mfk < 4; ++mfk)
            #pragma unroll
            for (int r = 0; r < 4; ++r) {
                const float p = __expf(acc[mfk][nfq][r] - m);
                acc[mfk][nfq][r] = p;
                s += p;
            }
        s += __shfl_xor(s, 16);
        s += __shfl_xor(s, 32);
        inv[nfq] = 1.f / s;
    }

    // ---- pack P to bf16 pairs ----
    u32 pk01[4][4], pk23[4][4];
    #pragma unroll
    for (int mfk = 0; mfk < 4; ++mfk)
        #pragma unroll
        for (int nfq = 0; nfq < 4; ++nfq) {
            pk01[mfk][nfq] = (u32)f2u(acc[mfk][nfq][0] * inv[nfq])
                           | ((u32)f2u(acc[mfk][nfq][1] * inv[nfq]) << 16);
            pk23[mfk][nfq] = (u32)f2u(acc[mfk][nfq][2] * inv[nfq])
                           | ((u32)f2u(acc[mfk][nfq][3] * inv[nfq]) << 16);
        }

    // ---- PV B-frags from vT ----
    s16x8 vf[2][2];
    #pragma unroll
    for (int nf = 0; nf < 2; ++nf)
        #pragma unroll
        for (int ks = 0; ks < 2; ++ks)
            vf[nf][ks] = *(const s16x8*)&vT[head][row16 + 16*nf][32*ks + koff];

    // ---- P redistribution + PV MFMAs ----
    f32x4 accO[4][2];
    #pragma unroll
    for (int MF = 0; MF < 4; ++MF)
        #pragma unroll
        for (int nf = 0; nf < 2; ++nf)
            accO[MF][nf] = (f32x4){0.f,0.f,0.f,0.f};

    const int g0 = 2*(hi & 1);
    const int src0 = g0*16 + row16, src1 = src0 + 16;
    const bool selhi = (hi >> 1) != 0;
    #pragma unroll
    for (int ks = 0; ks < 2; ++ks) {
        #pragma unroll
        for (int MF = 0; MF < 4; ++MF) {
            const u32 e01a = __shfl(pk01[2*ks][MF],   src0);
            const u32 e01b = __shfl(pk01[2*ks+1][MF], src0);
            const u32 e23a = __shfl(pk23[2*ks][MF],   src0);
            const u32 e23b = __shfl(pk23[2*ks+1][MF], src0);
            const u32 e45a = __shfl(pk01[2*ks][MF],   src1);
            const u32 e45b = __shfl(pk01[2*ks+1][MF], src1);
            const u32 e67a = __shfl(pk23[2*ks][MF],   src1);
            const u32 e67b = __shfl(pk23[2*ks+1][MF], src1);
            union { u32 w[4]; s16x8 v; } af;
            af.w[0] = selhi ? e01b : e01a;
            af.w[1] = selhi ? e23b : e23a;
            af.w[2] = selhi ? e45b : e45a;
            af.w[3] = selhi ? e67b : e67a;
            accO[MF][0] = __builtin_amdgcn_mfma_f32_16x16x32_bf16(
                af.v, vf[0][ks], accO[MF][0], 0, 0, 0);
            accO[MF][1] = __builtin_amdgcn_mfma_f32_16x16x32_bf16(
                af.v, vf[1][ks], accO[MF][1], 0, 0, 0);
        }
    }

    // ---- store O (shifted frame; roll-back happens in sp-proj epilogue) ----
    #pragma unroll
    for (int MF = 0; MF < 4; ++MF) {
        #pragma unroll
        for (int nf = 0; nf < 2; ++nf) {
            const int d = row16 + 16*nf;
            if (d >= 24) continue;
            #pragma unroll
            for (int r = 0; r < 4; ++r) {
                const int qrow = hi*4 + r + 16*MF;
                const int h = wh*8 + (qrow >> 3);
                const int w = ww*8 + (qrow & 7);
                osp[((size_t)b*HW + h*WR + w)*144 + head*24 + d] = f2b(accO[MF][nf][r]);
            }
        }
    }
}

// =====================================================================
// Channel attention stage 1: partial gram + column sum-squares
// =====================================================================
__global__ __launch_bounds__(256)
void ch_part_k(const bf16* __restrict__ chqkv, float* __restrict__ pgram,
               float* __restrict__ pss)
{
    const int ci = blockIdx.x, head = blockIdx.y, b = blockIdx.z;
    const int tid = threadIdx.x;
    __shared__ u16 tile[256][48];
    float g[3] = {0.f, 0.f, 0.f};
    float ss = 0.f;
    const u16* src = (const u16*)chqkv + (size_t)b * HW * CHC + head * 72;
    const int rbase = ci * 1024;

    for (int t0 = 0; t0 < 1024; t0 += 256) {
        __syncthreads();
        for (int idx = tid; idx < 256*6; idx += 256) {
            const int row = idx / 6, seg = idx - (idx/6)*6;
            *(uint4*)&tile[row][seg*8] =
                *(const uint4*)(src + (size_t)(rbase + t0 + row) * CHC + seg*8);
        }
        __syncthreads();
        #pragma unroll
        for (int i = 0; i < 3; ++i) {
            const int e = tid + i*256;
            if (e < 576) {
                const int c = e / 24, d = e - (e/24)*24;
                float s = 0.f;
                for (int r = 0; r < 256; ++r)
                    s += b2f(*(const bf16*)&tile[r][c]) * b2f(*(const bf16*)&tile[r][24+d]);
                g[i] += s;
            }
        }
        if (tid < 48) {
            float s = 0.f;
            for (int r = 0; r < 256; ++r) { const float v = b2f(*(const bf16*)&tile[r][tid]); s += v*v; }
            ss += s;
        }
    }
    float* pg = pgram + ((size_t)(b*2+head)*16 + ci) * 576;
    #pragma unroll
    for (int i = 0; i < 3; ++i) { const int e = tid + i*256; if (e < 576) pg[e] = g[i]; }
    if (tid < 48) pss[((size_t)(b*2+head)*16 + ci) * 48 + tid] = ss;
}

__global__ __launch_bounds__(256)
void ch_soft_k(const float* __restrict__ pgram, const float* __restrict__ pss,
               const float* __restrict__ logit_ch, float* __restrict__ attn)
{
    const int head = blockIdx.x, b = blockIdx.y;
    const int tid = threadIdx.x;
    __shared__ float gs[576], rn[48];
    for (int e = tid; e < 576; e += 256) {
        float s = 0.f;
        const float* pg = pgram + (size_t)(b*2+head)*16*576 + e;
        for (int c = 0; c < 16; ++c) s += pg[c*576];
        gs[e] = s;
    }
    if (tid < 48) {
        float s = 0.f;
        const float* ps = pss + (size_t)(b*2+head)*16*48 + tid;
        for (int c = 0; c < 16; ++c) s += ps[c*48];
        rn[tid] = 1.f / fmaxf(sqrtf(s), 1e-12f);
    }
    __syncthreads();
    if (tid < 24) {
        const float scale = expf(fminf(logit_ch[head], LOGMAX));
        float vals[24], mx = -1e30f;
        #pragma unroll
        for (int d = 0; d < 24; ++d) {
            vals[d] = gs[tid*24+d] * rn[tid] * rn[24+d] * scale;
            mx = fmaxf(mx, vals[d]);
        }
        float sum = 0.f;
        #pragma unroll
        for (int d = 0; d < 24; ++d) { vals[d] = expf(vals[d]-mx); sum += vals[d]; }
        const float inv = 1.f / sum;
        float* o = attn + ((size_t)(b*2+head)*24 + tid)*24;
        #pragma unroll
        for (int d = 0; d < 24; ++d) o[d] = vals[d]*inv;
    }
}

__global__ __launch_bounds__(192)
void fuse_chw_k(const float* __restrict__ Wc, const float* __restrict__ attn,
                bf16* __restrict__ Wf)
{
    const int b = blockIdx.x;
    const int n = threadIdx.x;
    __shared__ float As_[2][24][24];
    for (int e = n; e < 1152; e += 192) {
        const int h = e / 576, r = e - h*576;
        As_[h][r/24][r%24] = attn[(size_t)b*1152 + e];
    }
    __syncthreads();
    const float* wr = Wc + n*48;
    bf16* o = Wf + ((size_t)b*192 + n) * 48;
    for (int h = 0; h < 2; ++h)
        for (int d = 0; d < 24; ++d) {
            float s = 0.f;
            #pragma unroll
            for (int cc = 0; cc < 24; ++cc) s += wr[h*24+cc] * As_[h][cc][d];
            o[h*24+d] = f2b(s);
        }
}

// =====================================================================
// weight combiners
// =====================================================================
__global__ void combine_sp_k(const float* __restrict__ w_sp_proj, const float* __restrict__ w_spp,
                             const float* __restrict__ b_spp, bf16* __restrict__ Wc, float* __restrict__ bc)
{
    const int n = blockIdx.x;
    for (int i = threadIdx.x; i < 144; i += blockDim.x) {
        float s = 0.f;
        for (int j = 0; j < 144; ++j) s += w_sp_proj[n*144 + j] * w_spp[j*144 + i];
        Wc[n*144 + i] = f2b(s);
    }
    if (threadIdx.x == 0) {
        float s = 0.f;
        for (int j = 0; j < 144; ++j) s += w_sp_proj[n*144 + j] * b_spp[j];
        bc[n] = s;
    }
}

__global__ void combine_ch_k(const float* __restrict__ w_ch_proj, const float* __restrict__ w_chp,
                             const float* __restrict__ b_chp, float* __restrict__ Wc, float* __restrict__ bc)
{
    const int n = blockIdx.x;
    for (int c = threadIdx.x; c < 48; c += blockDim.x) {
        float s = 0.f;
        for (int j = 0; j < 48; ++j) s += w_ch_proj[n*48 + j] * w_chp[j*48 + c];
        Wc[n*48 + c] = s;
    }
    if (threadIdx.x == 0) {
        float s = 0.f;
        for (int j = 0; j < 48; ++j) s += w_ch_proj[n*48 + j] * b_chp[j];
        bc[n] = s;
    }
}

// =====================================================================
// per-(b,c) mean over H,W (bf16 src)
// =====================================================================
__global__ __launch_bounds__(256)
void mean_k(const bf16* __restrict__ src, float* __restrict__ dst)
{
    const int c = blockIdx.x, b = blockIdx.y;
    const bf16* base = src + (size_t)b * HW * CCH + c;
    float s = 0.f;
    for (int i = threadIdx.x; i < HW; i += 256) s += b2f(base[(size_t)i * CCH]);
    for (int m = 1; m < 64; m <<= 1) s += __shfl_xor(s, m);
    __shared__ float red[4];
    if ((threadIdx.x & 63) == 0) red[threadIdx.x >> 6] = s;
    __syncthreads();
    if (threadIdx.x == 0) dst[b*CCH + c] = (red[0]+red[1]+red[2]+red[3]) / (float)HW;
}

__global__ __launch_bounds__(192)
void gates_k(const float* __restrict__ meanv, const float* __restrict__ w1,
             const float* __restrict__ w2, const float* __restrict__ b2,
             float* __restrict__ gate)
{
    const int b = blockIdx.x;
    __shared__ float mv[192], hid[48];
    const int t = threadIdx.x;
    mv[t] = meanv[b*CCH + t];
    __syncthreads();
    if (t < 48) {
        float s = 0.f;
        for (int c = 0; c < 192; ++c) s += w1[t*192 + c] * mv[c];
        hid[t] = fmaxf(s, 0.f);
    }
    __syncthreads();
    float s = b2[t];
    for (int j = 0; j < 48; ++j) s += hid[j] * w2[t*48 + j];
    gate[b*CCH + t] = 1.f / (1.f + expf(-s));
}

// =====================================================================
// out = x + f2(padded) * (1 + sigmoid(relu(gpre)@w_sg2 + b))
// =====================================================================
__global__ __launch_bounds__(256)
void fuse_k(const float* __restrict__ x, const bf16* __restrict__ f2pad,
            const bf16* __restrict__ gpre, const float* __restrict__ w_sg2,
            const float* __restrict__ b_sg2, float* __restrict__ out)
{
    const int pix = blockIdx.x * 4 + (threadIdx.x >> 6);
    const int lane = threadIdx.x & 63;
    const bf16* gp = gpre + (size_t)pix * 96;
    float s = fmaxf(b2f(gp[lane]), 0.f) * w_sg2[lane];
    if (lane < 32) s += fmaxf(b2f(gp[lane + 64]), 0.f) * w_sg2[lane + 64];
    for (int m = 1; m < 64; m <<= 1) s += __shfl_xor(s, m);
    const float g1 = 1.f + 1.f / (1.f + expf(-(s + b_sg2[0])));
    const int b = pix >> 14, p = pix & 16383;
    const int h = p >> 7, w = p & 127;
    const bf16* fr = f2pad + ((size_t)b * PHW + (size_t)(h+1) * PH + (w+1)) * CCH;
    const float* xr = x + (size_t)pix * CCH;
    float* orow = out + (size_t)pix * CCH;
    for (int c = lane; c < CCH; c += 64) orow[c] = xr[c] + b2f(fr[c]) * g1;
}

// =====================================================================
// launcher
// =====================================================================
extern "C" void kernel_launch(void* const* d_in, const int* in_sizes, int n_in,
                              void* d_out, int out_size, void* d_ws, size_t ws_size,
                              hipStream_t stream)
{
    const float* x        = (const float*)d_in[0];
    const float* ln1_g    = (const float*)d_in[1];
    const float* ln1_b    = (const float*)d_in[2];
    const float* w_qkv    = (const float*)d_in[3];
    const float* b_qkv    = (const float*)d_in[4];
    const float* logit_sp = (const float*)d_in[5];
    const float* rpb      = (const float*)d_in[6];
    const float* w_spp    = (const float*)d_in[7];
    const float* b_spp    = (const float*)d_in[8];
    const float* logit_ch = (const float*)d_in[9];
    const float* w_chp    = (const float*)d_in[10];
    const float* b_chp    = (const float*)d_in[11];
    const float* w_sp_proj= (const float*)d_in[12];
    const float* w_ch_proj= (const float*)d_in[13];
    const float* w_s2c1   = (const float*)d_in[14];
    const float* w_s2c2   = (const float*)d_in[15];
    const float* b_s2c2   = (const float*)d_in[16];
    const float* w_c2s1   = (const float*)d_in[17];
    const float* w_c2s2   = (const float*)d_in[18];
    const float* b_c2s2   = (const float*)d_in[19];
    const float* w_gs1    = (const float*)d_in[20];
    const float* w_gs2    = (const float*)d_in[21];
    const float* b_gs2    = (const float*)d_in[22];
    const float* w_gc1    = (const float*)d_in[23];
    const float* w_gc2    = (const float*)d_in[24];
    const float* b_gc2    = (const float*)d_in[25];
    const float* w_f1     = (const float*)d_in[26];
    const float* bn1_g    = (const float*)d_in[27];
    const float* bn1_b    = (const float*)d_in[28];
    const float* bn1_m    = (const float*)d_in[29];
    const float* bn1_v    = (const float*)d_in[30];
    const float* w_f2     = (const float*)d_in[31];
    const float* bn2_g    = (const float*)d_in[32];
    const float* bn2_b    = (const float*)d_in[33];
    const float* bn2_m    = (const float*)d_in[34];
    const float* bn2_v    = (const float*)d_in[35];
    const float* w_sg1    = (const float*)d_in[36];
    const float* w_sg2    = (const float*)d_in[37];
    const float* b_sg2    = (const float*)d_in[38];
    const float* ln2_g    = (const float*)d_in[39];
    const float* ln2_b    = (const float*)d_in[40];
    const float* w_fc1    = (const float*)d_in[41];
    const float* b_fc1    = (const float*)d_in[42];
    const float* w_fc2    = (const float*)d_in[43];
    const float* b_fc2    = (const float*)d_in[44];

    char* wsb = (char*)d_ws;
    char* sm  = wsb + OFF_SMALL;
    float* out = (float*)d_out;

    bf16*  spqkv  = (bf16*)(wsb + OFF_A0);
    bf16*  sp_out = (bf16*)(wsb + OFF_A0);
    bf16*  ch_out = (bf16*)(wsb + OFF_A0 + 50331648);
    bf16*  f2pad  = (bf16*)(wsb + OFF_A0);
    bf16*  gpre   = (bf16*)(wsb + OFF_A0 + 51916800);
    bf16*  chqkv  = (bf16*)(wsb + OFF_B0);
    bf16*  hid_s  = (bf16*)(wsb + OFF_B0);
    bf16*  hid_c  = (bf16*)(wsb + OFF_B0 + 12582912);
    bf16*  fpad   = (bf16*)(wsb + OFF_B0);
    bf16*  hidden = (bf16*)(wsb + OFF_B0);
    bf16*  osp    = (bf16*)(wsb + OFF_C0);

    float* stats  = (float*)(sm + SO_STATS);
    float* pgram  = (float*)(sm + SO_PGRAM);
    float* pss    = (float*)(sm + SO_PSS);
    float* attn_b = (float*)(sm + SO_ATTNB);
    float* mean_sp= (float*)(sm + SO_MEANSP);
    float* mean_ch= (float*)(sm + SO_MEANCH);
    float* gate_s = (float*)(sm + SO_GATES);
    float* gate_c = (float*)(sm + SO_GATEC);
    float* bc_sp  = (float*)(sm + SO_BCSP);
    float* Wc_ch  = (float*)(sm + SO_WCCH);
    float* bc_ch  = (float*)(sm + SO_BCCH);
    bf16*  Wfuse  = (bf16*)(sm + SO_WFUSE);
    bf16*  Wc_spB = (bf16*)(sm + SO_WCSPB);
    u16*   wqB    = (u16*)(sm + SO_WQB);
    u16*   ws2c1B = (u16*)(sm + SO_WS2C1B);
    u16*   wc2s1B = (u16*)(sm + SO_WC2S1B);
    u16*   ws2c2B = (u16*)(sm + SO_WS2C2B);
    u16*   wc2s2B = (u16*)(sm + SO_WC2S2B);
    u16*   wf1B   = (u16*)(sm + SO_WF1B);
    u16*   wf2cB  = (u16*)(sm + SO_WF2CB);
    u16*   wsg1cB = (u16*)(sm + SO_WSG1CB);
    u16*   wfc1B  = (u16*)(sm + SO_WFC1B);
    u16*   wfc2B  = (u16*)(sm + SO_WFC2B);

    const dim3 blk(256);

    // ---- weight prep ----
    wprep_lin_k<<<(110592+255)/256, blk, 0, stream>>>(w_qkv,  (bf16*)wqB,    110592);
    wprep_lin_k<<<(9216+255)/256,   blk, 0, stream>>>(w_s2c1, (bf16*)ws2c1B, 9216);
    wprep_lin_k<<<(9216+255)/256,   blk, 0, stream>>>(w_c2s1, (bf16*)wc2s1B, 9216);
    wprep_lin_k<<<(9216+255)/256,   blk, 0, stream>>>(w_s2c2, (bf16*)ws2c2B, 9216);
    wprep_lin_k<<<(9216+255)/256,   blk, 0, stream>>>(w_c2s2, (bf16*)wc2s2B, 9216);
    wprep_lin_k<<<(73728+255)/256,  blk, 0, stream>>>(w_f1,   (bf16*)wf1B,   73728);
    wprep_lin_k<<<(147456+255)/256, blk, 0, stream>>>(w_fc1,  (bf16*)wfc1B,  147456);
    wprep_lin_k<<<(147456+255)/256, blk, 0, stream>>>(w_fc2,  (bf16*)wfc2B,  147456);
    wprep_conv_k<<<(331776+255)/256, blk, 0, stream>>>(w_f2,  (bf16*)wf2cB,  331776);
    wprep_conv_k<<<(165888+255)/256, blk, 0, stream>>>(w_sg1, (bf16*)wsg1cB, 165888);
    combine_sp_k<<<192, 128, 0, stream>>>(w_sp_proj, w_spp, b_spp, Wc_spB, bc_sp);
    combine_ch_k<<<192, 64, 0, stream>>>(w_ch_proj, w_chp, b_chp, Wc_ch, bc_ch);

    // ---- LN1 stats + full-M qkv GEMM (split store) ----
    ln_stats_k<<<MTOK/4, blk, 0, stream>>>(x, stats);
    gemm_k<1,7,1,192,0,0><<<dim3(3, MTOK/GBM), blk, 0, stream>>>(
        x, wqB, b_qkv, spqkv, MTOK, 576, CCH,
        stats, ln1_g, ln1_b, nullptr,
        (const float*)chqkv, nullptr, nullptr, nullptr);

    // ---- MFMA spatial attention (6 heads/block) + sp proj (roll store) ----
    sp_attn_k<<<dim3(BATCH*NWIN), dim3(384), 0, stream>>>(spqkv, rpb, logit_sp, osp);
    gemm_k<0,2,1,192,0,0><<<dim3(1, MTOK/GBM), blk, 0, stream>>>(
        osp, (const u16*)Wc_spB, bc_sp, sp_out, MTOK, CCH, 144,
        nullptr, nullptr, nullptr, nullptr,
        nullptr, nullptr, nullptr, nullptr);

    // ---- channel attention: partial gram -> softmax -> fused W -> GEMM ----
    ch_part_k<<<dim3(16, 2, BATCH), blk, 0, stream>>>(chqkv, pgram, pss);
    ch_soft_k<<<dim3(2, BATCH), blk, 0, stream>>>(pgram, pss, logit_ch, attn_b);
    fuse_chw_k<<<BATCH, 192, 0, stream>>>(Wc_ch, attn_b, Wfuse);
    gemm_k<4,0,1,192,0,1><<<dim3(1, MTOK/GBM), blk, 0, stream>>>(
        chqkv, (const u16*)Wfuse, bc_ch, ch_out, MTOK, CCH, 48,
        nullptr, nullptr, nullptr, nullptr,
        nullptr, nullptr, nullptr, nullptr);

    // ---- CFCA means/gates ----
    mean_k<<<dim3(CCH, BATCH), blk, 0, stream>>>(sp_out, mean_sp);
    mean_k<<<dim3(CCH, BATCH), blk, 0, stream>>>(ch_out, mean_ch);
    gates_k<<<BATCH, 192, 0, stream>>>(mean_sp, w_gs1, w_gs2, b_gs2, gate_s);
    gates_k<<<BATCH, 192, 0, stream>>>(mean_ch, w_gc1, w_gc2, b_gc2, gate_c);

    // ---- CFCA hiddens + gated residual adds ----
    gemm_k<0,1,1,96,0,0><<<dim3(1, MTOK/GBM), blk, 0, stream>>>(
        sp_out, ws2c1B, nullptr, hid_s, MTOK, MIDC, CCH,
        nullptr, nullptr, nullptr, nullptr, nullptr, nullptr, nullptr, nullptr);
    gemm_k<0,1,1,96,0,0><<<dim3(1, MTOK/GBM), blk, 0, stream>>>(
        ch_out, wc2s1B, nullptr, hid_c, MTOK, MIDC, CCH,
        nullptr, nullptr, nullptr, nullptr, nullptr, nullptr, nullptr, nullptr);
    gemm_k<0,4,1,192,0,0><<<dim3(1, MTOK/GBM), blk, 0, stream>>>(
        hid_s, ws2c2B, b_s2c2, ch_out, MTOK, CCH, MIDC,
        nullptr, nullptr, nullptr, nullptr, gate_s, nullptr, nullptr, nullptr);
    gemm_k<0,4,1,192,0,0><<<dim3(1, MTOK/GBM), blk, 0, stream>>>(
        hid_c, wc2s2B, b_c2s2, sp_out, MTOK, CCH, MIDC,
        nullptr, nullptr, nullptr, nullptr, gate_c, nullptr, nullptr, nullptr);

    // ---- f = relu(bn1(concat @ w_f1^T)) -> PADDED fpad ----
    zb_k<<<(8*516*24+255)/256, blk, 0, stream>>>(fpad);
    gemm_k<2,3,1,192,1,0><<<dim3(1, MTOK/GBM), blk, 0, stream>>>(
        sp_out, wf1B, nullptr, fpad, MTOK, CCH, 2*CCH,
        nullptr, nullptr, nullptr, ch_out, bn1_g, bn1_b, bn1_m, bn1_v);

    // ---- f2 = relu(bn2(conv3x3(f))) -> PADDED f2pad ----
    zb_k<<<(8*516*24+255)/256, blk, 0, stream>>>(f2pad);
    gemm_k<3,3,1,192,1,0><<<dim3(1, MTOK/GBM), blk, 0, stream>>>(
        fpad, wf2cB, nullptr, f2pad, MTOK, CCH, 9*CCH,
        nullptr, nullptr, nullptr, nullptr, bn2_g, bn2_b, bn2_m, bn2_v);

    // ---- gpre = conv3x3(f2) (96 ch) ----
    gemm_k<3,0,1,96,0,0><<<dim3(1, MTOK/GBM), blk, 0, stream>>>(
        f2pad, wsg1cB, nullptr, gpre, MTOK, 96, 9*CCH,
        nullptr, nullptr, nullptr, nullptr, nullptr, nullptr, nullptr, nullptr);

    // ---- xnew = x + f2*(1+g) -> d_out ----
    fuse_k<<<MTOK/4, blk, 0, stream>>>(x, f2pad, gpre, w_sg2, b_sg2, out);

    // ---- LN2 + MLP (chunked; hidden over dead fpad region) ----
    ln_stats_k<<<MTOK/4, blk, 0, stream>>>(out, stats);
    const int CHM = MTOK / 4;
    for (int c0 = 0; c0 < MTOK; c0 += CHM) {
        gemm_k<1,5,1,192,0,0><<<dim3(4, CHM/GBM), blk, 0, stream>>>(
            out + (size_t)c0*CCH, wfc1B, b_fc1, hidden, CHM, 4*CCH, CCH,
            stats + (size_t)c0*2, ln2_g, ln2_b, nullptr,
            nullptr, nullptr, nullptr, nullptr);
        gemm_k<0,6,0,192,0,0><<<dim3(1, CHM/GBM), blk, 0, stream>>>(
            hidden, wfc2B, b_fc2, out + (size_t)c0*CCH, CHM, CCH, 4*CCH,
            nullptr, nullptr, nullptr, nullptr, out + (size_t)c0*CCH,
            nullptr, nullptr, nullptr);
    }
}

// Round 8
// 1615.666 us; speedup vs baseline: 5.2870x; 1.0904x over previous
//
#include <hip/hip_runtime.h>
#include <hip/hip_bf16.h>
#include <cstddef>

typedef __hip_bfloat16 bf16;
typedef unsigned short u16;
typedef unsigned int u32;
typedef short s16x8 __attribute__((ext_vector_type(8)));
typedef float f32x4 __attribute__((ext_vector_type(4)));

// ---------------- problem constants ----------------
#define BATCH 8
#define HR 128
#define WR 128
#define CCH 192
#define HW (HR*WR)            // 16384
#define MTOK (BATCH*HW)       // 131072
#define SPH 6
#define SPC 432               // spatial qkv channels (heads 0..5)
#define CHC 144               // channel-head qkv channels (heads 6,7)
#define NWIN 256
#define MIDC 48
#define PH 130                // padded conv H/W
#define PHW (PH*PH)           // 16900
#define LOGMAX 4.6051701859880914f

// ---------------- ws layout (BYTE offsets; peak ~193 MB) ----------------
static const size_t OFF_A0    = 0;
static const size_t OFF_B0    = 113246208;
static const size_t OFF_C0    = 150994944;
static const size_t OFF_SMALL = 188743680;
static const size_t SO_STATS  = 0;          // fp32 2*M
static const size_t SO_PGRAM  = 1048576;    // fp32 [8][2][16][576]
static const size_t SO_PSS    = 1638400;    // fp32 [8][2][16][48]
static const size_t SO_ATTNB  = 1687552;    // fp32 [8][2][24][24]
static const size_t SO_MEANSP = 1724416;
static const size_t SO_MEANCH = 1732608;
static const size_t SO_GATES  = 1740800;
static const size_t SO_GATEC  = 1748992;
static const size_t SO_BCSP   = 1757184;    // fp32 192
static const size_t SO_WCCH   = 1758208;    // fp32 192*48
static const size_t SO_BCCH   = 1795072;    // fp32 192
static const size_t SO_WFUSE  = 1796096;    // bf16 [8][192][48]
static const size_t SO_WCSPB  = 1943552;    // bf16 192*144
static const size_t SO_WQB    = 1998848;    // bf16 576*192
static const size_t SO_WS2C1B = 2220032;    // bf16 48*192
static const size_t SO_WC2S1B = 2238464;
static const size_t SO_WS2C2B = 2256896;    // bf16 192*48
static const size_t SO_WC2S2B = 2275328;
static const size_t SO_WF1B   = 2293760;    // bf16 192*384
static const size_t SO_WF2CB  = 2441216;    // bf16 192*1728
static const size_t SO_WSG1CB = 3104768;    // bf16 96*1728
static const size_t SO_WFC1B  = 3436544;    // bf16 768*192
static const size_t SO_WFC2B  = 3731456;    // bf16 192*768

__device__ __forceinline__ float b2f(bf16 x) { return __bfloat162float(x); }
__device__ __forceinline__ bf16  f2b(float x){ return __float2bfloat16(x); }
__device__ __forceinline__ u16   f2u(float x){
    bf16 h = __float2bfloat16(x);
    union { bf16 b; u16 u; } c; c.b = h; return c.u;
}
__device__ __forceinline__ float s2f(short s){
    union { u16 u; bf16 b; } c; c.u = (u16)s; return b2f(c.b);
}
__device__ __forceinline__ float u2f(u16 u){
    union { u16 u; bf16 b; } c; c.u = u; return b2f(c.b);
}

// =====================================================================
// MFMA bf16 GEMM: double-buffered LDS (1 barrier/K-step), register
// prefetch, LDS-staged vectorized epilogue (bf16 C).
// block 256 thr = 4 waves (2x2), tile 128 x BNT, BK=32.
// AMODE: 0 plain bf16, 1 LN-fused (A fp32 + stats), 2 concat(A|A2 bf16),
//        3 implicit 3x3 conv over PADDED input, 4 V-extract from chqkv
// EPI: 0 bias, 1 relu, 2 roll-store, 3 BN+relu, 4 gated residual,
//      5 gelu, 6 residual add (fp32 ep0, CBF=0 only), 7 qkv split store
// =====================================================================
#define GBM 128
#define GBK 32
#define LDA 40   // padded LDS row length in ushorts (80 B)

struct SegRaw { union { uint4 v; struct { float4 lo, hi; } f; } d; };

template<int AMODE, int EPI, int CBF, int BNT, int CPAD, int WPB>
__global__ __launch_bounds__(256)
void gemm_k(const void* __restrict__ A, const u16* __restrict__ W,
            const float* __restrict__ bias, void* __restrict__ Cv,
            int M, int N, int K,
            const float* __restrict__ stats, const float* __restrict__ lng,
            const float* __restrict__ lnb, const void* __restrict__ A2,
            const float* __restrict__ ep0, const float* __restrict__ ep1,
            const float* __restrict__ ep2, const float* __restrict__ ep3)
{
    constexpr int NF = BNT / 32;
    constexpr int NB = (BNT * 4 + 255) / 256;
    constexpr int ATILE = GBM * LDA;      // u16 units
    constexpr int BTILE = BNT * LDA;
    constexpr int BUFSZ = ATILE + BTILE;
    __shared__ u16 smem[2 * BUFSZ];       // also reused as C staging tile

    const int tid  = threadIdx.x;
    const int lane = tid & 63;
    const int wid  = tid >> 6;
    const int wm   = (wid >> 1) * 64;
    const int wn   = (wid & 1) * (BNT / 2);
    const int m0   = blockIdx.y * GBM;
    const int n0   = blockIdx.x * BNT;
    const int row16 = lane & 15;
    const int hi    = lane >> 4;
    const int koff  = hi * 8;

    const int arow[2] = { tid >> 2, (tid + 256) >> 2 };
    const int akk     = (tid & 3) * 8;

    const u16* Wb = W;
    if constexpr (WPB) Wb = W + (size_t)(m0 >> 14) * 9216;

    float meanA[2], rstdA[2];
    if constexpr (AMODE == 1) {
        #pragma unroll
        for (int it = 0; it < 2; ++it) {
            const int m = m0 + arow[it];
            meanA[it] = stats[2*m]; rstdA[it] = stats[2*m+1];
        }
    }

    f32x4 acc[4][NF];
    #pragma unroll
    for (int mf = 0; mf < 4; ++mf)
        #pragma unroll
        for (int nf = 0; nf < NF; ++nf)
            acc[mf][nf] = (f32x4){0.f, 0.f, 0.f, 0.f};

    const int nsteps = (K + GBK - 1) / GBK;

    auto loadA = [&](int step, SegRaw seg[2]) {
        const int k0 = step * GBK;
        #pragma unroll
        for (int it = 0; it < 2; ++it) {
            const int m = m0 + arow[it];
            const int k = k0 + akk;
            SegRaw& s = seg[it];
            if (k >= K) { s.d.v = (uint4){0u,0u,0u,0u}; continue; }
            if constexpr (AMODE == 0) {
                s.d.v = *(const uint4*)((const u16*)A + (size_t)m * K + k);
            } else if constexpr (AMODE == 1) {
                const float* p = (const float*)A + (size_t)m * K + k;
                s.d.f.lo = *(const float4*)p; s.d.f.hi = *(const float4*)(p+4);
            } else if constexpr (AMODE == 2) {
                const u16* src = (k < CCH) ? (const u16*)A  + (size_t)m * CCH + k
                                           : (const u16*)A2 + (size_t)m * CCH + (k - CCH);
                s.d.v = *(const uint4*)src;
            } else if constexpr (AMODE == 3) {
                const int tap = k / CCH, c = k - tap * CCH;
                const int ky = tap / 3, kx = tap - ky * 3;
                const int b = m >> 14, pix = m & 16383;
                const int h = pix >> 7, w = pix & 127;
                s.d.v = *(const uint4*)((const u16*)A +
                        ((size_t)b * PHW + (size_t)(h + ky) * PH + (w + kx)) * CCH + c);
            } else {
                const int col = (k < 24) ? (48 + k) : (96 + k);
                s.d.v = *(const uint4*)((const u16*)A + (size_t)m * CHC + col);
            }
        }
    };
    auto loadB = [&](int step, SegRaw seg[NB]) {
        const int k0 = step * GBK;
        #pragma unroll
        for (int it = 0; it < NB; ++it) {
            const int s = tid + it * 256;
            const int n = n0 + (s >> 2);
            const int k = k0 + (s & 3) * 8;
            seg[it].d.v = (uint4){0u,0u,0u,0u};
            if (s < BNT*4 && k < K && n < N)
                seg[it].d.v = *(const uint4*)(Wb + (size_t)n * K + k);
        }
    };
    auto writeA = [&](int step, SegRaw seg[2], u16* Ab) {
        const int k0 = step * GBK;
        #pragma unroll
        for (int it = 0; it < 2; ++it) {
            if constexpr (AMODE == 1) {
                const int k = k0 + akk;
                union { u16 u[8]; uint4 v; } pk;
                #pragma unroll
                for (int j = 0; j < 8; ++j) {
                    float xx = (j < 4) ? seg[it].d.f.lo[j] : seg[it].d.f.hi[j-4];
                    xx = (xx - meanA[it]) * rstdA[it] * lng[k+j] + lnb[k+j];
                    pk.u[j] = f2u(xx);
                }
                *(uint4*)&Ab[arow[it] * LDA + akk] = pk.v;
            } else {
                *(uint4*)&Ab[arow[it] * LDA + akk] = seg[it].d.v;
            }
        }
    };
    auto writeB = [&](SegRaw seg[NB], u16* Bb) {
        #pragma unroll
        for (int it = 0; it < NB; ++it) {
            const int s = tid + it * 256;
            if (s < BNT*4)
                *(uint4*)&Bb[(s >> 2) * LDA + (s & 3) * 8] = seg[it].d.v;
        }
    };

    SegRaw segA[2], segB[NB];
    loadA(0, segA); loadB(0, segB);
    writeA(0, segA, smem); writeB(segB, smem + ATILE);
    __syncthreads();

    int cur = 0;
    for (int step = 0; step < nsteps; ++step) {
        const bool more = (step + 1 < nsteps);
        if (more) { loadA(step+1, segA); loadB(step+1, segB); }
        u16* Ab = smem + cur * BUFSZ;
        u16* Bb = Ab + ATILE;
        s16x8 af[4], bfr[NF];
        #pragma unroll
        for (int mf = 0; mf < 4; ++mf)
            af[mf] = *(const s16x8*)&Ab[(wm + mf*16 + row16) * LDA + koff];
        #pragma unroll
        for (int nf = 0; nf < NF; ++nf)
            bfr[nf] = *(const s16x8*)&Bb[(wn + nf*16 + row16) * LDA + koff];
        __builtin_amdgcn_s_setprio(1);
        #pragma unroll
        for (int mf = 0; mf < 4; ++mf)
            #pragma unroll
            for (int nf = 0; nf < NF; ++nf)
                acc[mf][nf] = __builtin_amdgcn_mfma_f32_16x16x32_bf16(
                    af[mf], bfr[nf], acc[mf][nf], 0, 0, 0);
        __builtin_amdgcn_s_setprio(0);
        if (more) {
            u16* An = smem + (cur ^ 1) * BUFSZ;
            writeA(step+1, segA, An); writeB(segB, An + ATILE);
        }
        __syncthreads();
        cur ^= 1;
    }

    // ================= epilogue =================
    if constexpr (CBF == 1) {
        // ---- stage C tile (bf16) into LDS: all math except EPI4 Cold-add ----
        #pragma unroll
        for (int mf = 0; mf < 4; ++mf) {
            #pragma unroll
            for (int nf = 0; nf < NF; ++nf) {
                const int n = n0 + wn + nf*16 + row16;
                #pragma unroll
                for (int r = 0; r < 4; ++r) {
                    const int m_loc = wm + mf*16 + hi*4 + r;
                    float v = acc[mf][nf][r];
                    if (n < N) {
                        v += (bias ? bias[n] : 0.f);
                        if constexpr (EPI == 1) {
                            v = fmaxf(v, 0.f);
                        } else if constexpr (EPI == 3) {
                            v = (v - ep2[n]) * rsqrtf(ep3[n] + 1e-5f) * ep0[n] + ep1[n];
                            v = fmaxf(v, 0.f);
                        } else if constexpr (EPI == 4) {
                            const int b = (m0 + m_loc) >> 14;
                            v = v * ep0[b * N + n];
                        } else if constexpr (EPI == 5) {
                            v = 0.5f * v * (1.f + erff(v * 0.70710678118654752f));
                        }
                    }
                    smem[m_loc * BNT + (wn + nf*16 + row16)] = f2u(v);
                }
            }
        }
        __syncthreads();
        // ---- vectorized store: 8 bf16 (16B) per task ----
        constexpr int CHUNKS = BNT / 8;
        constexpr int TASKS  = GBM * CHUNKS / 256;
        #pragma unroll
        for (int t2 = 0; t2 < TASKS; ++t2) {
            const int task  = tid + t2 * 256;
            const int rloc  = task / CHUNKS;
            const int chunk = task - rloc * CHUNKS;
            const int m  = m0 + rloc;
            const int nn = n0 + chunk * 8;
            if (nn >= N) continue;
            uint4 val = *(const uint4*)&smem[rloc * BNT + chunk * 8];
            if constexpr (EPI == 7) {
                if (nn < SPC) {
                    *(uint4*)((u16*)Cv + (size_t)m * SPC + nn) = val;
                } else {
                    u16* chq = (u16*)ep0;
                    *(uint4*)(chq + (size_t)m * CHC + (nn - SPC)) = val;
                }
                continue;
            }
            size_t outIdx;
            if constexpr (CPAD == 1) {
                const int b = m >> 14, pix = m & 16383;
                const int h = pix >> 7, w = pix & 127;
                outIdx = ((size_t)b * PHW + (size_t)(h+1) * PH + (w+1)) * (size_t)N + nn;
            } else if constexpr (EPI == 2) {
                const int b = m >> 14, pix = m & 16383;
                const int h2 = ((pix >> 7) + 4) & 127;
                const int w2 = ((pix & 127) + 4) & 127;
                outIdx = ((size_t)(b * HW) + h2 * WR + w2) * (size_t)N + nn;
            } else {
                outIdx = (size_t)m * N + nn;
            }
            if constexpr (EPI == 4) {
                union { uint4 v; u16 u[8]; } sv, ov;
                sv.v = val;
                ov.v = *(const uint4*)((const u16*)Cv + outIdx);
                #pragma unroll
                for (int j = 0; j < 8; ++j)
                    sv.u[j] = f2u(u2f(ov.u[j]) + u2f(sv.u[j]));
                *(uint4*)((u16*)Cv + outIdx) = sv.v;
            } else {
                *(uint4*)((u16*)Cv + outIdx) = val;
            }
        }
    } else {
        // ---- legacy per-element fp32 path (fc2: EPI 6) ----
        #pragma unroll
        for (int mf = 0; mf < 4; ++mf) {
            #pragma unroll
            for (int nf = 0; nf < NF; ++nf) {
                const int n = n0 + wn + nf*16 + row16;
                if (n >= N) continue;
                #pragma unroll
                for (int r = 0; r < 4; ++r) {
                    const int m = m0 + wm + mf*16 + hi*4 + r;
                    float v = acc[mf][nf][r] + (bias ? bias[n] : 0.f);
                    const size_t outIdx = (size_t)m * N + n;
                    if constexpr (EPI == 6) v = ep0[outIdx] + v;
                    ((float*)Cv)[outIdx] = v;
                }
            }
        }
    }
}

// =====================================================================
// weight prep
// =====================================================================
__global__ __launch_bounds__(256)
void wprep_lin_k(const float* __restrict__ in, bf16* __restrict__ outb, int n)
{
    const int i = blockIdx.x * 256 + threadIdx.x;
    if (i < n) outb[i] = f2b(in[i]);
}

__global__ __launch_bounds__(256)
void wprep_conv_k(const float* __restrict__ in, bf16* __restrict__ outb, int total)
{
    const int i = blockIdx.x * 256 + threadIdx.x;
    if (i >= total) return;
    const int n = i / 1728, r = i - n * 1728;
    const int tap = r / CCH, c = r - tap * CCH;
    outb[i] = f2b(in[((size_t)n * CCH + c) * 9 + tap]);
}

__global__ __launch_bounds__(256)
void zb_k(bf16* __restrict__ buf)
{
    const int i = blockIdx.x * 256 + threadIdx.x;
    if (i >= 8 * 516 * 24) return;
    const int chunk = i % 24;
    const int p = (i / 24) % 516;
    const int b = i / (24 * 516);
    int h, w;
    if (p < 130)      { h = 0;   w = p; }
    else if (p < 260) { h = 129; w = p - 130; }
    else { const int q = p - 260; h = 1 + (q >> 1); w = (q & 1) ? 129 : 0; }
    *(uint4*)((u16*)buf + ((size_t)b * PHW + (size_t)h * PH + w) * CCH + chunk * 8)
        = (uint4){0u,0u,0u,0u};
}

// =====================================================================
// LN stats
// =====================================================================
__global__ __launch_bounds__(256)
void ln_stats_k(const float* __restrict__ x, float* __restrict__ stats)
{
    const int tok = blockIdx.x * 4 + (threadIdx.x >> 6);
    const int lane = threadIdx.x & 63;
    const float* r = x + (size_t)tok * CCH;
    float s = 0.f, sq = 0.f;
    for (int c = lane; c < CCH; c += 64) { float v = r[c]; s += v; sq += v*v; }
    for (int m = 1; m < 64; m <<= 1) { s += __shfl_xor(s, m); sq += __shfl_xor(sq, m); }
    if (lane == 0) {
        const float mean = s / (float)CCH;
        const float var = sq / (float)CCH - mean * mean;
        stats[(size_t)tok*2]   = mean;
        stats[(size_t)tok*2+1] = rsqrtf(var + 1e-5f);
    }
}

// =====================================================================
// MFMA spatial shifted-window cosine attention (6 waves = 6 heads/window)
// =====================================================================
__global__ __launch_bounds__(384)
void sp_attn_k(const bf16* __restrict__ spqkv, const float* __restrict__ rpb,
               const float* __restrict__ logit_sp, bf16* __restrict__ osp)
{
    const int b    = blockIdx.x >> 8;
    const int win  = blockIdx.x & 255;
    const int wh = win >> 4, ww = win & 15;
    const int head = threadIdx.x >> 6;
    const int lane = threadIdx.x & 63;
    const int row16 = lane & 15;
    const int hi   = lane >> 4;
    const int koff = hi * 8;

    __shared__ float rpbS[1350];
    __shared__ u16 vT[SPH][32][72];

    for (int i = threadIdx.x; i < 1350; i += 384) rpbS[i] = rpb[i];

    const u16* base = (const u16*)spqkv + (size_t)b * HW * SPC;

    s16x8 qf[4], kf[4];
    const int wcol = (ww*8 + (row16 & 7) + 4) & 127;
    #pragma unroll
    for (int t = 0; t < 4; ++t) {
        const int pos = t*16 + row16;
        const int h = (wh*8 + (pos >> 3) + 4) & 127;
        const u16* rowp = base + ((size_t)(h * WR + wcol)) * SPC + head * 72;
        if (koff < 24) {
            qf[t] = *(const s16x8*)(rowp + koff);
            kf[t] = *(const s16x8*)(rowp + 24 + koff);
        } else {
            qf[t] = (s16x8){0,0,0,0,0,0,0,0};
            kf[t] = (s16x8){0,0,0,0,0,0,0,0};
        }
    }

    {
        const int h = (wh*8 + (lane >> 3) + 4) & 127;
        const int w = (ww*8 + (lane & 7) + 4) & 127;
        const u16* vrow = base + ((size_t)(h * WR + w)) * SPC + head * 72 + 48;
        union { uint4 v; u16 u[8]; } seg[3];
        seg[0].v = *(const uint4*)(vrow);
        seg[1].v = *(const uint4*)(vrow + 8);
        seg[2].v = *(const uint4*)(vrow + 16);
        #pragma unroll
        for (int d = 0; d < 24; ++d) vT[head][d][lane] = seg[d>>3].u[d&7];
        #pragma unroll
        for (int d = 24; d < 32; ++d) vT[head][d][lane] = 0;
    }
    __syncthreads();

    float rq[4], rk[4];
    #pragma unroll
    for (int t = 0; t < 4; ++t) {
        float sq = 0.f, sk = 0.f;
        #pragma unroll
        for (int e = 0; e < 8; ++e) {
            const float a = s2f(qf[t][e]); sq += a*a;
            const float c = s2f(kf[t][e]); sk += c*c;
        }
        sq += __shfl_xor(sq, 16); sq += __shfl_xor(sq, 32);
        sk += __shfl_xor(sk, 16); sk += __shfl_xor(sk, 32);
        rq[t] = 1.f / fmaxf(sqrtf(sq), 1e-12f);
        rk[t] = 1.f / fmaxf(sqrtf(sk), 1e-12f);
    }
    const float scale_h = __expf(fminf(logit_sp[head], LOGMAX));

    f32x4 acc[4][4];
    #pragma unroll
    for (int mfk = 0; mfk < 4; ++mfk)
        #pragma unroll
        for (int nfq = 0; nfq < 4; ++nfq)
            acc[mfk][nfq] = (f32x4){0.f,0.f,0.f,0.f};
    #pragma unroll
    for (int mfk = 0; mfk < 4; ++mfk)
        #pragma unroll
        for (int nfq = 0; nfq < 4; ++nfq)
            acc[mfk][nfq] = __builtin_amdgcn_mfma_f32_16x16x32_bf16(
                kf[mfk], qf[nfq], acc[mfk][nfq], 0, 0, 0);

    f32x4 rkj[4];
    #pragma unroll
    for (int mfk = 0; mfk < 4; ++mfk)
        #pragma unroll
        for (int r = 0; r < 4; ++r)
            rkj[mfk][r] = __shfl(rk[mfk], hi*4 + r);

    int ip3[4], iw7[4], labi[4];
    #pragma unroll
    for (int t = 0; t < 4; ++t) {
        const int pos = t*16 + row16;
        ip3[t] = pos >> 3; iw7[t] = pos & 7;
        const int hh = wh*8 + ip3[t], w0 = ww*8 + iw7[t];
        const int rh = hh < 120 ? 0 : (hh < 124 ? 1 : 2);
        const int rw = w0 < 120 ? 0 : (w0 < 124 ? 1 : 2);
        labi[t] = rh*3 + rw;
    }

    #pragma unroll
    for (int mfk = 0; mfk < 4; ++mfk) {
        #pragma unroll
        for (int r = 0; r < 4; ++r) {
            const int j = hi*4 + r + 16*mfk;
            const int jp3 = j >> 3, jw7 = j & 7;
            const int hh = wh*8 + jp3, w0 = ww*8 + jw7;
            const int rh = hh < 120 ? 0 : (hh < 124 ? 1 : 2);
            const int rw = w0 < 120 ? 0 : (w0 < 124 ? 1 : 2);
            const int labj = rh*3 + rw;
            const float rkv = rkj[mfk][r];
            #pragma unroll
            for (int nfq = 0; nfq < 4; ++nfq) {
                float s = acc[mfk][nfq][r] * rq[nfq] * rkv * scale_h;
                s += rpbS[((ip3[nfq]-jp3+7)*15 + (iw7[nfq]-jw7+7))*SPH + head];
                if (labi[nfq] != labj) s -= 100.f;
                acc[mfk][nfq][r] = s;
            }
        }
    }

    float inv[4];
    #pragma unroll
    for (int nfq = 0; nfq < 4; ++nfq) {
        float m = -1e30f;
        #pragma unroll
        for (int mfk = 0; mfk < 4; ++mfk)
            #pragma unroll
            for (int r = 0; r < 4; ++r)
                m = fmaxf(m, acc[mfk][nfq][r]);
        m = fmaxf(m, __shfl_xor(m, 16));
        m = fmaxf(m, __shfl_xor(m, 32));
        float s = 0.f;
        #pragma unroll
        for (int mfk = 0; mfk < 4; ++mfk)
            #pragma unroll
            for (int r = 0; r < 4; ++r) {
                const float p = __expf(acc[mfk][nfq][r] - m);
                acc[mfk][nfq][r] = p;
                s += p;
            }
        s += __shfl_xor(s, 16);
        s += __shfl_xor(s, 32);
        inv[nfq] = 1.f / s;
    }

    u32 pk01[4][4], pk23[4][4];
    #pragma unroll
    for (int mfk = 0; mfk < 4; ++mfk)
        #pragma unroll
        for (int nfq = 0; nfq < 4; ++nfq) {
            pk01[mfk][nfq] = (u32)f2u(acc[mfk][nfq][0] * inv[nfq])
                           | ((u32)f2u(acc[mfk][nfq][1] * inv[nfq]) << 16);
            pk23[mfk][nfq] = (u32)f2u(acc[mfk][nfq][2] * inv[nfq])
                           | ((u32)f2u(acc[mfk][nfq][3] * inv[nfq]) << 16);
        }

    s16x8 vf[2][2];
    #pragma unroll
    for (int nf = 0; nf < 2; ++nf)
        #pragma unroll
        for (int ks = 0; ks < 2; ++ks)
            vf[nf][ks] = *(const s16x8*)&vT[head][row16 + 16*nf][32*ks + koff];

    f32x4 accO[4][2];
    #pragma unroll
    for (int MF = 0; MF < 4; ++MF)
        #pragma unroll
        for (int nf = 0; nf < 2; ++nf)
            accO[MF][nf] = (f32x4){0.f,0.f,0.f,0.f};

    const int g0 = 2*(hi & 1);
    const int src0 = g0*16 + row16, src1 = src0 + 16;
    const bool selhi = (hi >> 1) != 0;
    #pragma unroll
    for (int ks = 0; ks < 2; ++ks) {
        #pragma unroll
        for (int MF = 0; MF < 4; ++MF) {
            const u32 e01a = __shfl(pk01[2*ks][MF],   src0);
            const u32 e01b = __shfl(pk01[2*ks+1][MF], src0);
            const u32 e23a = __shfl(pk23[2*ks][MF],   src0);
            const u32 e23b = __shfl(pk23[2*ks+1][MF], src0);
            const u32 e45a = __shfl(pk01[2*ks][MF],   src1);
            const u32 e45b = __shfl(pk01[2*ks+1][MF], src1);
            const u32 e67a = __shfl(pk23[2*ks][MF],   src1);
            const u32 e67b = __shfl(pk23[2*ks+1][MF], src1);
            union { u32 w[4]; s16x8 v; } af;
            af.w[0] = selhi ? e01b : e01a;
            af.w[1] = selhi ? e23b : e23a;
            af.w[2] = selhi ? e45b : e45a;
            af.w[3] = selhi ? e67b : e67a;
            accO[MF][0] = __builtin_amdgcn_mfma_f32_16x16x32_bf16(
                af.v, vf[0][ks], accO[MF][0], 0, 0, 0);
            accO[MF][1] = __builtin_amdgcn_mfma_f32_16x16x32_bf16(
                af.v, vf[1][ks], accO[MF][1], 0, 0, 0);
        }
    }

    #pragma unroll
    for (int MF = 0; MF < 4; ++MF) {
        #pragma unroll
        for (int nf = 0; nf < 2; ++nf) {
            const int d = row16 + 16*nf;
            if (d >= 24) continue;
            #pragma unroll
            for (int r = 0; r < 4; ++r) {
                const int qrow = hi*4 + r + 16*MF;
                const int h = wh*8 + (qrow >> 3);
                const int w = ww*8 + (qrow & 7);
                osp[((size_t)b*HW + h*WR + w)*144 + head*24 + d] = f2b(accO[MF][nf][r]);
            }
        }
    }
}

// =====================================================================
// Channel attention: partial gram + column sum-squares, softmax, W-fuse
// =====================================================================
__global__ __launch_bounds__(256)
void ch_part_k(const bf16* __restrict__ chqkv, float* __restrict__ pgram,
               float* __restrict__ pss)
{
    const int ci = blockIdx.x, head = blockIdx.y, b = blockIdx.z;
    const int tid = threadIdx.x;
    __shared__ u16 tile[256][48];
    float g[3] = {0.f, 0.f, 0.f};
    float ss = 0.f;
    const u16* src = (const u16*)chqkv + (size_t)b * HW * CHC + head * 72;
    const int rbase = ci * 1024;

    for (int t0 = 0; t0 < 1024; t0 += 256) {
        __syncthreads();
        for (int idx = tid; idx < 256*6; idx += 256) {
            const int row = idx / 6, seg = idx - (idx/6)*6;
            *(uint4*)&tile[row][seg*8] =
                *(const uint4*)(src + (size_t)(rbase + t0 + row) * CHC + seg*8);
        }
        __syncthreads();
        #pragma unroll
        for (int i = 0; i < 3; ++i) {
            const int e = tid + i*256;
            if (e < 576) {
                const int c = e / 24, d = e - (e/24)*24;
                float s = 0.f;
                for (int r = 0; r < 256; ++r)
                    s += b2f(*(const bf16*)&tile[r][c]) * b2f(*(const bf16*)&tile[r][24+d]);
                g[i] += s;
            }
        }
        if (tid < 48) {
            float s = 0.f;
            for (int r = 0; r < 256; ++r) { const float v = b2f(*(const bf16*)&tile[r][tid]); s += v*v; }
            ss += s;
        }
    }
    float* pg = pgram + ((size_t)(b*2+head)*16 + ci) * 576;
    #pragma unroll
    for (int i = 0; i < 3; ++i) { const int e = tid + i*256; if (e < 576) pg[e] = g[i]; }
    if (tid < 48) pss[((size_t)(b*2+head)*16 + ci) * 48 + tid] = ss;
}

__global__ __launch_bounds__(256)
void ch_soft_k(const float* __restrict__ pgram, const float* __restrict__ pss,
               const float* __restrict__ logit_ch, float* __restrict__ attn)
{
    const int head = blockIdx.x, b = blockIdx.y;
    const int tid = threadIdx.x;
    __shared__ float gs[576], rn[48];
    for (int e = tid; e < 576; e += 256) {
        float s = 0.f;
        const float* pg = pgram + (size_t)(b*2+head)*16*576 + e;
        for (int c = 0; c < 16; ++c) s += pg[c*576];
        gs[e] = s;
    }
    if (tid < 48) {
        float s = 0.f;
        const float* ps = pss + (size_t)(b*2+head)*16*48 + tid;
        for (int c = 0; c < 16; ++c) s += ps[c*48];
        rn[tid] = 1.f / fmaxf(sqrtf(s), 1e-12f);
    }
    __syncthreads();
    if (tid < 24) {
        const float scale = expf(fminf(logit_ch[head], LOGMAX));
        float vals[24], mx = -1e30f;
        #pragma unroll
        for (int d = 0; d < 24; ++d) {
            vals[d] = gs[tid*24+d] * rn[tid] * rn[24+d] * scale;
            mx = fmaxf(mx, vals[d]);
        }
        float sum = 0.f;
        #pragma unroll
        for (int d = 0; d < 24; ++d) { vals[d] = expf(vals[d]-mx); sum += vals[d]; }
        const float inv = 1.f / sum;
        float* o = attn + ((size_t)(b*2+head)*24 + tid)*24;
        #pragma unroll
        for (int d = 0; d < 24; ++d) o[d] = vals[d]*inv;
    }
}

__global__ __launch_bounds__(192)
void fuse_chw_k(const float* __restrict__ Wc, const float* __restrict__ attn,
                bf16* __restrict__ Wf)
{
    const int b = blockIdx.x;
    const int n = threadIdx.x;
    __shared__ float As_[2][24][24];
    for (int e = n; e < 1152; e += 192) {
        const int h = e / 576, r = e - h*576;
        As_[h][r/24][r%24] = attn[(size_t)b*1152 + e];
    }
    __syncthreads();
    const float* wr = Wc + n*48;
    bf16* o = Wf + ((size_t)b*192 + n) * 48;
    for (int h = 0; h < 2; ++h)
        for (int d = 0; d < 24; ++d) {
            float s = 0.f;
            #pragma unroll
            for (int cc = 0; cc < 24; ++cc) s += wr[h*24+cc] * As_[h][cc][d];
            o[h*24+d] = f2b(s);
        }
}

// =====================================================================
// weight combiners
// =====================================================================
__global__ void combine_sp_k(const float* __restrict__ w_sp_proj, const float* __restrict__ w_spp,
                             const float* __restrict__ b_spp, bf16* __restrict__ Wc, float* __restrict__ bc)
{
    const int n = blockIdx.x;
    for (int i = threadIdx.x; i < 144; i += blockDim.x) {
        float s = 0.f;
        for (int j = 0; j < 144; ++j) s += w_sp_proj[n*144 + j] * w_spp[j*144 + i];
        Wc[n*144 + i] = f2b(s);
    }
    if (threadIdx.x == 0) {
        float s = 0.f;
        for (int j = 0; j < 144; ++j) s += w_sp_proj[n*144 + j] * b_spp[j];
        bc[n] = s;
    }
}

__global__ void combine_ch_k(const float* __restrict__ w_ch_proj, const float* __restrict__ w_chp,
                             const float* __restrict__ b_chp, float* __restrict__ Wc, float* __restrict__ bc)
{
    const int n = blockIdx.x;
    for (int c = threadIdx.x; c < 48; c += blockDim.x) {
        float s = 0.f;
        for (int j = 0; j < 48; ++j) s += w_ch_proj[n*48 + j] * w_chp[j*48 + c];
        Wc[n*48 + c] = s;
    }
    if (threadIdx.x == 0) {
        float s = 0.f;
        for (int j = 0; j < 48; ++j) s += w_ch_proj[n*48 + j] * b_chp[j];
        bc[n] = s;
    }
}

// =====================================================================
// per-(b,c) mean over H,W (bf16 src)
// =====================================================================
__global__ __launch_bounds__(256)
void mean_k(const bf16* __restrict__ src, float* __restrict__ dst)
{
    const int c = blockIdx.x, b = blockIdx.y;
    const bf16* base = src + (size_t)b * HW * CCH + c;
    float s = 0.f;
    for (int i = threadIdx.x; i < HW; i += 256) s += b2f(base[(size_t)i * CCH]);
    for (int m = 1; m < 64; m <<= 1) s += __shfl_xor(s, m);
    __shared__ float red[4];
    if ((threadIdx.x & 63) == 0) red[threadIdx.x >> 6] = s;
    __syncthreads();
    if (threadIdx.x == 0) dst[b*CCH + c] = (red[0]+red[1]+red[2]+red[3]) / (float)HW;
}

__global__ __launch_bounds__(192)
void gates_k(const float* __restrict__ meanv, const float* __restrict__ w1,
             const float* __restrict__ w2, const float* __restrict__ b2,
             float* __restrict__ gate)
{
    const int b = blockIdx.x;
    __shared__ float mv[192], hid[48];
    const int t = threadIdx.x;
    mv[t] = meanv[b*CCH + t];
    __syncthreads();
    if (t < 48) {
        float s = 0.f;
        for (int c = 0; c < 192; ++c) s += w1[t*192 + c] * mv[c];
        hid[t] = fmaxf(s, 0.f);
    }
    __syncthreads();
    float s = b2[t];
    for (int j = 0; j < 48; ++j) s += hid[j] * w2[t*48 + j];
    gate[b*CCH + t] = 1.f / (1.f + expf(-s));
}

// =====================================================================
// out = x + f2(padded) * (1 + sigmoid(relu(gpre)@w_sg2 + b))
// =====================================================================
__global__ __launch_bounds__(256)
void fuse_k(const float* __restrict__ x, const bf16* __restrict__ f2pad,
            const bf16* __restrict__ gpre, const float* __restrict__ w_sg2,
            const float* __restrict__ b_sg2, float* __restrict__ out)
{
    const int pix = blockIdx.x * 4 + (threadIdx.x >> 6);
    const int lane = threadIdx.x & 63;
    const bf16* gp = gpre + (size_t)pix * 96;
    float s = fmaxf(b2f(gp[lane]), 0.f) * w_sg2[lane];
    if (lane < 32) s += fmaxf(b2f(gp[lane + 64]), 0.f) * w_sg2[lane + 64];
    for (int m = 1; m < 64; m <<= 1) s += __shfl_xor(s, m);
    const float g1 = 1.f + 1.f / (1.f + expf(-(s + b_sg2[0])));
    const int b = pix >> 14, p = pix & 16383;
    const int h = p >> 7, w = p & 127;
    const bf16* fr = f2pad + ((size_t)b * PHW + (size_t)(h+1) * PH + (w+1)) * CCH;
    const float* xr = x + (size_t)pix * CCH;
    float* orow = out + (size_t)pix * CCH;
    for (int c = lane; c < CCH; c += 64) orow[c] = xr[c] + b2f(fr[c]) * g1;
}

// =====================================================================
// launcher
// =====================================================================
extern "C" void kernel_launch(void* const* d_in, const int* in_sizes, int n_in,
                              void* d_out, int out_size, void* d_ws, size_t ws_size,
                              hipStream_t stream)
{
    const float* x        = (const float*)d_in[0];
    const float* ln1_g    = (const float*)d_in[1];
    const float* ln1_b    = (const float*)d_in[2];
    const float* w_qkv    = (const float*)d_in[3];
    const float* b_qkv    = (const float*)d_in[4];
    const float* logit_sp = (const float*)d_in[5];
    const float* rpb      = (const float*)d_in[6];
    const float* w_spp    = (const float*)d_in[7];
    const float* b_spp    = (const float*)d_in[8];
    const float* logit_ch = (const float*)d_in[9];
    const float* w_chp    = (const float*)d_in[10];
    const float* b_chp    = (const float*)d_in[11];
    const float* w_sp_proj= (const float*)d_in[12];
    const float* w_ch_proj= (const float*)d_in[13];
    const float* w_s2c1   = (const float*)d_in[14];
    const float* w_s2c2   = (const float*)d_in[15];
    const float* b_s2c2   = (const float*)d_in[16];
    const float* w_c2s1   = (const float*)d_in[17];
    const float* w_c2s2   = (const float*)d_in[18];
    const float* b_c2s2   = (const float*)d_in[19];
    const float* w_gs1    = (const float*)d_in[20];
    const float* w_gs2    = (const float*)d_in[21];
    const float* b_gs2    = (const float*)d_in[22];
    const float* w_gc1    = (const float*)d_in[23];
    const float* w_gc2    = (const float*)d_in[24];
    const float* b_gc2    = (const float*)d_in[25];
    const float* w_f1     = (const float*)d_in[26];
    const float* bn1_g    = (const float*)d_in[27];
    const float* bn1_b    = (const float*)d_in[28];
    const float* bn1_m    = (const float*)d_in[29];
    const float* bn1_v    = (const float*)d_in[30];
    const float* w_f2     = (const float*)d_in[31];
    const float* bn2_g    = (const float*)d_in[32];
    const float* bn2_b    = (const float*)d_in[33];
    const float* bn2_m    = (const float*)d_in[34];
    const float* bn2_v    = (const float*)d_in[35];
    const float* w_sg1    = (const float*)d_in[36];
    const float* w_sg2    = (const float*)d_in[37];
    const float* b_sg2    = (const float*)d_in[38];
    const float* ln2_g    = (const float*)d_in[39];
    const float* ln2_b    = (const float*)d_in[40];
    const float* w_fc1    = (const float*)d_in[41];
    const float* b_fc1    = (const float*)d_in[42];
    const float* w_fc2    = (const float*)d_in[43];
    const float* b_fc2    = (const float*)d_in[44];

    char* wsb = (char*)d_ws;
    char* sm  = wsb + OFF_SMALL;
    float* out = (float*)d_out;

    bf16*  spqkv  = (bf16*)(wsb + OFF_A0);
    bf16*  sp_out = (bf16*)(wsb + OFF_A0);
    bf16*  ch_out = (bf16*)(wsb + OFF_A0 + 50331648);
    bf16*  f2pad  = (bf16*)(wsb + OFF_A0);
    bf16*  gpre   = (bf16*)(wsb + OFF_A0 + 51916800);
    bf16*  chqkv  = (bf16*)(wsb + OFF_B0);
    bf16*  hid_s  = (bf16*)(wsb + OFF_B0);
    bf16*  hid_c  = (bf16*)(wsb + OFF_B0 + 12582912);
    bf16*  fpad   = (bf16*)(wsb + OFF_B0);
    bf16*  hidden = (bf16*)(wsb + OFF_B0);
    bf16*  osp    = (bf16*)(wsb + OFF_C0);

    float* stats  = (float*)(sm + SO_STATS);
    float* pgram  = (float*)(sm + SO_PGRAM);
    float* pss    = (float*)(sm + SO_PSS);
    float* attn_b = (float*)(sm + SO_ATTNB);
    float* mean_sp= (float*)(sm + SO_MEANSP);
    float* mean_ch= (float*)(sm + SO_MEANCH);
    float* gate_s = (float*)(sm + SO_GATES);
    float* gate_c = (float*)(sm + SO_GATEC);
    float* bc_sp  = (float*)(sm + SO_BCSP);
    float* Wc_ch  = (float*)(sm + SO_WCCH);
    float* bc_ch  = (float*)(sm + SO_BCCH);
    bf16*  Wfuse  = (bf16*)(sm + SO_WFUSE);
    bf16*  Wc_spB = (bf16*)(sm + SO_WCSPB);
    u16*   wqB    = (u16*)(sm + SO_WQB);
    u16*   ws2c1B = (u16*)(sm + SO_WS2C1B);
    u16*   wc2s1B = (u16*)(sm + SO_WC2S1B);
    u16*   ws2c2B = (u16*)(sm + SO_WS2C2B);
    u16*   wc2s2B = (u16*)(sm + SO_WC2S2B);
    u16*   wf1B   = (u16*)(sm + SO_WF1B);
    u16*   wf2cB  = (u16*)(sm + SO_WF2CB);
    u16*   wsg1cB = (u16*)(sm + SO_WSG1CB);
    u16*   wfc1B  = (u16*)(sm + SO_WFC1B);
    u16*   wfc2B  = (u16*)(sm + SO_WFC2B);

    const dim3 blk(256);

    // ---- weight prep ----
    wprep_lin_k<<<(110592+255)/256, blk, 0, stream>>>(w_qkv,  (bf16*)wqB,    110592);
    wprep_lin_k<<<(9216+255)/256,   blk, 0, stream>>>(w_s2c1, (bf16*)ws2c1B, 9216);
    wprep_lin_k<<<(9216+255)/256,   blk, 0, stream>>>(w_c2s1, (bf16*)wc2s1B, 9216);
    wprep_lin_k<<<(9216+255)/256,   blk, 0, stream>>>(w_s2c2, (bf16*)ws2c2B, 9216);
    wprep_lin_k<<<(9216+255)/256,   blk, 0, stream>>>(w_c2s2, (bf16*)wc2s2B, 9216);
    wprep_lin_k<<<(73728+255)/256,  blk, 0, stream>>>(w_f1,   (bf16*)wf1B,   73728);
    wprep_lin_k<<<(147456+255)/256, blk, 0, stream>>>(w_fc1,  (bf16*)wfc1B,  147456);
    wprep_lin_k<<<(147456+255)/256, blk, 0, stream>>>(w_fc2,  (bf16*)wfc2B,  147456);
    wprep_conv_k<<<(331776+255)/256, blk, 0, stream>>>(w_f2,  (bf16*)wf2cB,  331776);
    wprep_conv_k<<<(165888+255)/256, blk, 0, stream>>>(w_sg1, (bf16*)wsg1cB, 165888);
    combine_sp_k<<<192, 128, 0, stream>>>(w_sp_proj, w_spp, b_spp, Wc_spB, bc_sp);
    combine_ch_k<<<192, 64, 0, stream>>>(w_ch_proj, w_chp, b_chp, Wc_ch, bc_ch);

    // ---- LN1 stats + full-M qkv GEMM (split store) ----
    ln_stats_k<<<MTOK/4, blk, 0, stream>>>(x, stats);
    gemm_k<1,7,1,192,0,0><<<dim3(3, MTOK/GBM), blk, 0, stream>>>(
        x, wqB, b_qkv, spqkv, MTOK, 576, CCH,
        stats, ln1_g, ln1_b, nullptr,
        (const float*)chqkv, nullptr, nullptr, nullptr);

    // ---- MFMA spatial attention + sp proj (roll store) ----
    sp_attn_k<<<dim3(BATCH*NWIN), dim3(384), 0, stream>>>(spqkv, rpb, logit_sp, osp);
    gemm_k<0,2,1,192,0,0><<<dim3(1, MTOK/GBM), blk, 0, stream>>>(
        osp, (const u16*)Wc_spB, bc_sp, sp_out, MTOK, CCH, 144,
        nullptr, nullptr, nullptr, nullptr,
        nullptr, nullptr, nullptr, nullptr);

    // ---- channel attention: partial gram -> softmax -> fused W -> GEMM ----
    ch_part_k<<<dim3(16, 2, BATCH), blk, 0, stream>>>(chqkv, pgram, pss);
    ch_soft_k<<<dim3(2, BATCH), blk, 0, stream>>>(pgram, pss, logit_ch, attn_b);
    fuse_chw_k<<<BATCH, 192, 0, stream>>>(Wc_ch, attn_b, Wfuse);
    gemm_k<4,0,1,192,0,1><<<dim3(1, MTOK/GBM), blk, 0, stream>>>(
        chqkv, (const u16*)Wfuse, bc_ch, ch_out, MTOK, CCH, 48,
        nullptr, nullptr, nullptr, nullptr,
        nullptr, nullptr, nullptr, nullptr);

    // ---- CFCA means/gates ----
    mean_k<<<dim3(CCH, BATCH), blk, 0, stream>>>(sp_out, mean_sp);
    mean_k<<<dim3(CCH, BATCH), blk, 0, stream>>>(ch_out, mean_ch);
    gates_k<<<BATCH, 192, 0, stream>>>(mean_sp, w_gs1, w_gs2, b_gs2, gate_s);
    gates_k<<<BATCH, 192, 0, stream>>>(mean_ch, w_gc1, w_gc2, b_gc2, gate_c);

    // ---- CFCA hiddens + gated residual adds ----
    gemm_k<0,1,1,96,0,0><<<dim3(1, MTOK/GBM), blk, 0, stream>>>(
        sp_out, ws2c1B, nullptr, hid_s, MTOK, MIDC, CCH,
        nullptr, nullptr, nullptr, nullptr, nullptr, nullptr, nullptr, nullptr);
    gemm_k<0,1,1,96,0,0><<<dim3(1, MTOK/GBM), blk, 0, stream>>>(
        ch_out, wc2s1B, nullptr, hid_c, MTOK, MIDC, CCH,
        nullptr, nullptr, nullptr, nullptr, nullptr, nullptr, nullptr, nullptr);
    gemm_k<0,4,1,192,0,0><<<dim3(1, MTOK/GBM), blk, 0, stream>>>(
        hid_s, ws2c2B, b_s2c2, ch_out, MTOK, CCH, MIDC,
        nullptr, nullptr, nullptr, nullptr, gate_s, nullptr, nullptr, nullptr);
    gemm_k<0,4,1,192,0,0><<<dim3(1, MTOK/GBM), blk, 0, stream>>>(
        hid_c, wc2s2B, b_c2s2, sp_out, MTOK, CCH, MIDC,
        nullptr, nullptr, nullptr, nullptr, gate_c, nullptr, nullptr, nullptr);

    // ---- f = relu(bn1(concat @ w_f1^T)) -> PADDED fpad ----
    zb_k<<<(8*516*24+255)/256, blk, 0, stream>>>(fpad);
    gemm_k<2,3,1,192,1,0><<<dim3(1, MTOK/GBM), blk, 0, stream>>>(
        sp_out, wf1B, nullptr, fpad, MTOK, CCH, 2*CCH,
        nullptr, nullptr, nullptr, ch_out, bn1_g, bn1_b, bn1_m, bn1_v);

    // ---- f2 = relu(bn2(conv3x3(f))) -> PADDED f2pad ----
    zb_k<<<(8*516*24+255)/256, blk, 0, stream>>>(f2pad);
    gemm_k<3,3,1,192,1,0><<<dim3(1, MTOK/GBM), blk, 0, stream>>>(
        fpad, wf2cB, nullptr, f2pad, MTOK, CCH, 9*CCH,
        nullptr, nullptr, nullptr, nullptr, bn2_g, bn2_b, bn2_m, bn2_v);

    // ---- gpre = conv3x3(f2) (96 ch) ----
    gemm_k<3,0,1,96,0,0><<<dim3(1, MTOK/GBM), blk, 0, stream>>>(
        f2pad, wsg1cB, nullptr, gpre, MTOK, 96, 9*CCH,
        nullptr, nullptr, nullptr, nullptr, nullptr, nullptr, nullptr, nullptr);

    // ---- xnew = x + f2*(1+g) -> d_out ----
    fuse_k<<<MTOK/4, blk, 0, stream>>>(x, f2pad, gpre, w_sg2, b_sg2, out);

    // ---- LN2 + MLP (chunked; hidden over dead fpad region) ----
    ln_stats_k<<<MTOK/4, blk, 0, stream>>>(out, stats);
    const int CHM = MTOK / 4;
    for (int c0 = 0; c0 < MTOK; c0 += CHM) {
        gemm_k<1,5,1,192,0,0><<<dim3(4, CHM/GBM), blk, 0, stream>>>(
            out + (size_t)c0*CCH, wfc1B, b_fc1, hidden, CHM, 4*CCH, CCH,
            stats + (size_t)c0*2, ln2_g, ln2_b, nullptr,
            nullptr, nullptr, nullptr, nullptr);
        gemm_k<0,6,0,192,0,0><<<dim3(1, CHM/GBM), blk, 0, stream>>>(
            hidden, wfc2B, b_fc2, out + (size_t)c0*CCH, CHM, CCH, 4*CCH,
            nullptr, nullptr, nullptr, nullptr, out + (size_t)c0*CCH,
            nullptr, nullptr, nullptr);
    }
}

// Round 9
// 1341.346 us; speedup vs baseline: 6.3682x; 1.2045x over previous
//
#include <hip/hip_runtime.h>
#include <hip/hip_bf16.h>
#include <cstddef>

typedef __hip_bfloat16 bf16;
typedef unsigned short u16;
typedef unsigned int u32;
typedef short s16x8 __attribute__((ext_vector_type(8)));
typedef float f32x4 __attribute__((ext_vector_type(4)));

// ---------------- problem constants ----------------
#define BATCH 8
#define HR 128
#define WR 128
#define CCH 192
#define HW (HR*WR)            // 16384
#define MTOK (BATCH*HW)       // 131072
#define SPH 6
#define SPC 432               // spatial qkv channels (heads 0..5)
#define CHC 144               // channel-head qkv channels (heads 6,7)
#define NWIN 256
#define MIDC 48
#define PH 130                // padded conv H/W
#define PHW (PH*PH)           // 16900
#define LOGMAX 4.6051701859880914f

// ---------------- ws layout (BYTE offsets; peak ~193 MB) ----------------
static const size_t OFF_A0    = 0;
static const size_t OFF_B0    = 113246208;
static const size_t OFF_C0    = 150994944;
static const size_t OFF_SMALL = 188743680;
static const size_t SO_STATS  = 0;          // fp32 2*M
static const size_t SO_PGRAM  = 1048576;    // fp32 [8][2][16][576]
static const size_t SO_PSS    = 1638400;    // fp32 [8][2][16][48]
static const size_t SO_ATTNB  = 1687552;    // fp32 [8][2][24][24]
static const size_t SO_MEANSP = 1724416;
static const size_t SO_MEANCH = 1732608;
static const size_t SO_GATES  = 1740800;
static const size_t SO_GATEC  = 1748992;
static const size_t SO_BCSP   = 1757184;    // fp32 192
static const size_t SO_WCCH   = 1758208;    // fp32 192*48
static const size_t SO_BCCH   = 1795072;    // fp32 192
static const size_t SO_WFUSE  = 1796096;    // bf16 [8][192][48]
static const size_t SO_WCSPB  = 1943552;    // bf16 192*144
static const size_t SO_WQB    = 1998848;    // bf16 576*192
static const size_t SO_WS2C1B = 2220032;    // bf16 48*192
static const size_t SO_WC2S1B = 2238464;
static const size_t SO_WS2C2B = 2256896;    // bf16 192*48
static const size_t SO_WC2S2B = 2275328;
static const size_t SO_WF1B   = 2293760;    // bf16 192*384
static const size_t SO_WF2CB  = 2441216;    // bf16 192*1728
static const size_t SO_WSG1CB = 3104768;    // bf16 96*1728
static const size_t SO_WFC1B  = 3436544;    // bf16 768*192
static const size_t SO_WFC2B  = 3731456;    // bf16 192*768

__device__ __forceinline__ float b2f(bf16 x) { return __bfloat162float(x); }
__device__ __forceinline__ bf16  f2b(float x){ return __float2bfloat16(x); }
__device__ __forceinline__ u16   f2u(float x){
    bf16 h = __float2bfloat16(x);
    union { bf16 b; u16 u; } c; c.b = h; return c.u;
}
__device__ __forceinline__ float s2f(short s){
    union { u16 u; bf16 b; } c; c.u = (u16)s; return b2f(c.b);
}
__device__ __forceinline__ float u2f(u16 u){
    union { u16 u; bf16 b; } c; c.u = u; return b2f(c.b);
}
// bijective XCD-aware remap (m204 variant)
__device__ __forceinline__ int xcdswz(int b, int n){
    const int q = n >> 3, r = n & 7, x = b & 7, o = b >> 3;
    return (x < r) ? (x * (q + 1) + o) : (r * (q + 1) + (x - r) * q + o);
}

// =====================================================================
// MFMA bf16 GEMM: double-buffered LDS (1 barrier/K-step), register
// prefetch, LDS-staged vectorized epilogue (bf16 C), XCD-swizzled M-blocks.
// block 256 thr = 4 waves (2x2), tile 128 x BNT, BK=32.
// AMODE: 0 plain bf16, 1 LN-fused (A fp32 + stats), 2 concat(A|A2 bf16),
//        3 implicit 3x3 conv over PADDED input, 4 V-extract from chqkv
// EPI: 0 bias, 1 relu, 2 roll-store, 3 BN+relu, 4 gated residual,
//      5 gelu, 6 residual add (fp32 ep0, CBF=0 only), 7 qkv split store
// =====================================================================
#define GBM 128
#define GBK 32
#define LDA 40   // padded LDS row length in ushorts (80 B)

struct SegRaw { union { uint4 v; struct { float4 lo, hi; } f; } d; };

template<int AMODE, int EPI, int CBF, int BNT, int CPAD, int WPB>
__global__ __launch_bounds__(256)
void gemm_k(const void* __restrict__ A, const u16* __restrict__ W,
            const float* __restrict__ bias, void* __restrict__ Cv,
            int M, int N, int K,
            const float* __restrict__ stats, const float* __restrict__ lng,
            const float* __restrict__ lnb, const void* __restrict__ A2,
            const float* __restrict__ ep0, const float* __restrict__ ep1,
            const float* __restrict__ ep2, const float* __restrict__ ep3)
{
    constexpr int NF = BNT / 32;
    constexpr int NB = (BNT * 4 + 255) / 256;
    constexpr int ATILE = GBM * LDA;      // u16 units
    constexpr int BTILE = BNT * LDA;
    constexpr int BUFSZ = ATILE + BTILE;
    constexpr int CST   = BNT + 8;        // padded C-staging stride (u16)
    __shared__ u16 smem[2 * BUFSZ];       // also reused as C staging tile

    const int tid  = threadIdx.x;
    const int lane = tid & 63;
    const int wid  = tid >> 6;
    const int wm   = (wid >> 1) * 64;
    const int wn   = (wid & 1) * (BNT / 2);
    const int m0   = xcdswz(blockIdx.y, gridDim.y) * GBM;
    const int n0   = blockIdx.x * BNT;
    const int row16 = lane & 15;
    const int hi    = lane >> 4;
    const int koff  = hi * 8;

    const int arow[2] = { tid >> 2, (tid + 256) >> 2 };
    const int akk     = (tid & 3) * 8;

    const u16* Wb = W;
    if constexpr (WPB) Wb = W + (size_t)(m0 >> 14) * 9216;

    float meanA[2], rstdA[2];
    if constexpr (AMODE == 1) {
        #pragma unroll
        for (int it = 0; it < 2; ++it) {
            const int m = m0 + arow[it];
            meanA[it] = stats[2*m]; rstdA[it] = stats[2*m+1];
        }
    }

    f32x4 acc[4][NF];
    #pragma unroll
    for (int mf = 0; mf < 4; ++mf)
        #pragma unroll
        for (int nf = 0; nf < NF; ++nf)
            acc[mf][nf] = (f32x4){0.f, 0.f, 0.f, 0.f};

    const int nsteps = (K + GBK - 1) / GBK;

    auto loadA = [&](int step, SegRaw seg[2]) {
        const int k0 = step * GBK;
        #pragma unroll
        for (int it = 0; it < 2; ++it) {
            const int m = m0 + arow[it];
            const int k = k0 + akk;
            SegRaw& s = seg[it];
            if (k >= K) { s.d.v = (uint4){0u,0u,0u,0u}; continue; }
            if constexpr (AMODE == 0) {
                s.d.v = *(const uint4*)((const u16*)A + (size_t)m * K + k);
            } else if constexpr (AMODE == 1) {
                const float* p = (const float*)A + (size_t)m * K + k;
                s.d.f.lo = *(const float4*)p; s.d.f.hi = *(const float4*)(p+4);
            } else if constexpr (AMODE == 2) {
                const u16* src = (k < CCH) ? (const u16*)A  + (size_t)m * CCH + k
                                           : (const u16*)A2 + (size_t)m * CCH + (k - CCH);
                s.d.v = *(const uint4*)src;
            } else if constexpr (AMODE == 3) {
                const int tap = k / CCH, c = k - tap * CCH;
                const int ky = tap / 3, kx = tap - ky * 3;
                const int b = m >> 14, pix = m & 16383;
                const int h = pix >> 7, w = pix & 127;
                s.d.v = *(const uint4*)((const u16*)A +
                        ((size_t)b * PHW + (size_t)(h + ky) * PH + (w + kx)) * CCH + c);
            } else {
                const int col = (k < 24) ? (48 + k) : (96 + k);
                s.d.v = *(const uint4*)((const u16*)A + (size_t)m * CHC + col);
            }
        }
    };
    auto loadB = [&](int step, SegRaw seg[NB]) {
        const int k0 = step * GBK;
        #pragma unroll
        for (int it = 0; it < NB; ++it) {
            const int s = tid + it * 256;
            const int n = n0 + (s >> 2);
            const int k = k0 + (s & 3) * 8;
            seg[it].d.v = (uint4){0u,0u,0u,0u};
            if (s < BNT*4 && k < K && n < N)
                seg[it].d.v = *(const uint4*)(Wb + (size_t)n * K + k);
        }
    };
    auto writeA = [&](int step, SegRaw seg[2], u16* Ab) {
        const int k0 = step * GBK;
        #pragma unroll
        for (int it = 0; it < 2; ++it) {
            if constexpr (AMODE == 1) {
                const int k = k0 + akk;
                union { u16 u[8]; uint4 v; } pk;
                #pragma unroll
                for (int j = 0; j < 8; ++j) {
                    float xx = (j < 4) ? seg[it].d.f.lo[j] : seg[it].d.f.hi[j-4];
                    xx = (xx - meanA[it]) * rstdA[it] * lng[k+j] + lnb[k+j];
                    pk.u[j] = f2u(xx);
                }
                *(uint4*)&Ab[arow[it] * LDA + akk] = pk.v;
            } else {
                *(uint4*)&Ab[arow[it] * LDA + akk] = seg[it].d.v;
            }
        }
    };
    auto writeB = [&](SegRaw seg[NB], u16* Bb) {
        #pragma unroll
        for (int it = 0; it < NB; ++it) {
            const int s = tid + it * 256;
            if (s < BNT*4)
                *(uint4*)&Bb[(s >> 2) * LDA + (s & 3) * 8] = seg[it].d.v;
        }
    };

    SegRaw segA[2], segB[NB];
    loadA(0, segA); loadB(0, segB);
    writeA(0, segA, smem); writeB(segB, smem + ATILE);
    __syncthreads();

    int cur = 0;
    for (int step = 0; step < nsteps; ++step) {
        const bool more = (step + 1 < nsteps);
        if (more) { loadA(step+1, segA); loadB(step+1, segB); }
        u16* Ab = smem + cur * BUFSZ;
        u16* Bb = Ab + ATILE;
        s16x8 af[4], bfr[NF];
        #pragma unroll
        for (int mf = 0; mf < 4; ++mf)
            af[mf] = *(const s16x8*)&Ab[(wm + mf*16 + row16) * LDA + koff];
        #pragma unroll
        for (int nf = 0; nf < NF; ++nf)
            bfr[nf] = *(const s16x8*)&Bb[(wn + nf*16 + row16) * LDA + koff];
        __builtin_amdgcn_s_setprio(1);
        #pragma unroll
        for (int mf = 0; mf < 4; ++mf)
            #pragma unroll
            for (int nf = 0; nf < NF; ++nf)
                acc[mf][nf] = __builtin_amdgcn_mfma_f32_16x16x32_bf16(
                    af[mf], bfr[nf], acc[mf][nf], 0, 0, 0);
        __builtin_amdgcn_s_setprio(0);
        if (more) {
            u16* An = smem + (cur ^ 1) * BUFSZ;
            writeA(step+1, segA, An); writeB(segB, An + ATILE);
        }
        __syncthreads();
        cur ^= 1;
    }

    // ================= epilogue =================
    if constexpr (CBF == 1) {
        // ---- stage C tile (bf16) into LDS (padded stride CST) ----
        #pragma unroll
        for (int mf = 0; mf < 4; ++mf) {
            #pragma unroll
            for (int nf = 0; nf < NF; ++nf) {
                const int n = n0 + wn + nf*16 + row16;
                #pragma unroll
                for (int r = 0; r < 4; ++r) {
                    const int m_loc = wm + mf*16 + hi*4 + r;
                    float v = acc[mf][nf][r];
                    if (n < N) {
                        v += (bias ? bias[n] : 0.f);
                        if constexpr (EPI == 1) {
                            v = fmaxf(v, 0.f);
                        } else if constexpr (EPI == 3) {
                            v = (v - ep2[n]) * rsqrtf(ep3[n] + 1e-5f) * ep0[n] + ep1[n];
                            v = fmaxf(v, 0.f);
                        } else if constexpr (EPI == 4) {
                            const int b = (m0 + m_loc) >> 14;
                            v = v * ep0[b * N + n];
                        } else if constexpr (EPI == 5) {
                            v = 0.5f * v * (1.f + erff(v * 0.70710678118654752f));
                        }
                    }
                    smem[m_loc * CST + (wn + nf*16 + row16)] = f2u(v);
                }
            }
        }
        __syncthreads();
        // ---- vectorized store: 8 bf16 (16B) per task ----
        constexpr int CHUNKS = BNT / 8;
        constexpr int TASKS  = GBM * CHUNKS / 256;
        #pragma unroll
        for (int t2 = 0; t2 < TASKS; ++t2) {
            const int task  = tid + t2 * 256;
            const int rloc  = task / CHUNKS;
            const int chunk = task - rloc * CHUNKS;
            const int m  = m0 + rloc;
            const int nn = n0 + chunk * 8;
            if (nn >= N) continue;
            uint4 val = *(const uint4*)&smem[rloc * CST + chunk * 8];
            if constexpr (EPI == 7) {
                if (nn < SPC) {
                    *(uint4*)((u16*)Cv + (size_t)m * SPC + nn) = val;
                } else {
                    u16* chq = (u16*)ep0;
                    *(uint4*)(chq + (size_t)m * CHC + (nn - SPC)) = val;
                }
                continue;
            }
            size_t outIdx;
            if constexpr (CPAD == 1) {
                const int b = m >> 14, pix = m & 16383;
                const int h = pix >> 7, w = pix & 127;
                outIdx = ((size_t)b * PHW + (size_t)(h+1) * PH + (w+1)) * (size_t)N + nn;
            } else if constexpr (EPI == 2) {
                const int b = m >> 14, pix = m & 16383;
                const int h2 = ((pix >> 7) + 4) & 127;
                const int w2 = ((pix & 127) + 4) & 127;
                outIdx = ((size_t)(b * HW) + h2 * WR + w2) * (size_t)N + nn;
            } else {
                outIdx = (size_t)m * N + nn;
            }
            if constexpr (EPI == 4) {
                union { uint4 v; u16 u[8]; } sv, ov;
                sv.v = val;
                ov.v = *(const uint4*)((const u16*)Cv + outIdx);
                #pragma unroll
                for (int j = 0; j < 8; ++j)
                    sv.u[j] = f2u(u2f(ov.u[j]) + u2f(sv.u[j]));
                *(uint4*)((u16*)Cv + outIdx) = sv.v;
            } else {
                *(uint4*)((u16*)Cv + outIdx) = val;
            }
        }
    } else {
        // ---- legacy per-element fp32 path (fc2: EPI 6) ----
        #pragma unroll
        for (int mf = 0; mf < 4; ++mf) {
            #pragma unroll
            for (int nf = 0; nf < NF; ++nf) {
                const int n = n0 + wn + nf*16 + row16;
                if (n >= N) continue;
                #pragma unroll
                for (int r = 0; r < 4; ++r) {
                    const int m = m0 + wm + mf*16 + hi*4 + r;
                    float v = acc[mf][nf][r] + (bias ? bias[n] : 0.f);
                    const size_t outIdx = (size_t)m * N + n;
                    if constexpr (EPI == 6) v = ep0[outIdx] + v;
                    ((float*)Cv)[outIdx] = v;
                }
            }
        }
    }
}

// =====================================================================
// weight prep
// =====================================================================
__global__ __launch_bounds__(256)
void wprep_lin_k(const float* __restrict__ in, bf16* __restrict__ outb, int n)
{
    const int i = blockIdx.x * 256 + threadIdx.x;
    if (i < n) outb[i] = f2b(in[i]);
}

__global__ __launch_bounds__(256)
void wprep_conv_k(const float* __restrict__ in, bf16* __restrict__ outb, int total)
{
    const int i = blockIdx.x * 256 + threadIdx.x;
    if (i >= total) return;
    const int n = i / 1728, r = i - n * 1728;
    const int tap = r / CCH, c = r - tap * CCH;
    outb[i] = f2b(in[((size_t)n * CCH + c) * 9 + tap]);
}

__global__ __launch_bounds__(256)
void zb_k(bf16* __restrict__ buf)
{
    const int i = blockIdx.x * 256 + threadIdx.x;
    if (i >= 8 * 516 * 24) return;
    const int chunk = i % 24;
    const int p = (i / 24) % 516;
    const int b = i / (24 * 516);
    int h, w;
    if (p < 130)      { h = 0;   w = p; }
    else if (p < 260) { h = 129; w = p - 130; }
    else { const int q = p - 260; h = 1 + (q >> 1); w = (q & 1) ? 129 : 0; }
    *(uint4*)((u16*)buf + ((size_t)b * PHW + (size_t)h * PH + w) * CCH + chunk * 8)
        = (uint4){0u,0u,0u,0u};
}

__global__ __launch_bounds__(256)
void zerof_k(float* __restrict__ p, int n)
{
    const int i = blockIdx.x * 256 + threadIdx.x;
    if (i < n) p[i] = 0.f;
}

// =====================================================================
// LN stats
// =====================================================================
__global__ __launch_bounds__(256)
void ln_stats_k(const float* __restrict__ x, float* __restrict__ stats)
{
    const int tok = blockIdx.x * 4 + (threadIdx.x >> 6);
    const int lane = threadIdx.x & 63;
    const float* r = x + (size_t)tok * CCH;
    float s = 0.f, sq = 0.f;
    for (int c = lane; c < CCH; c += 64) { float v = r[c]; s += v; sq += v*v; }
    for (int m = 1; m < 64; m <<= 1) { s += __shfl_xor(s, m); sq += __shfl_xor(sq, m); }
    if (lane == 0) {
        const float mean = s / (float)CCH;
        const float var = sq / (float)CCH - mean * mean;
        stats[(size_t)tok*2]   = mean;
        stats[(size_t)tok*2+1] = rsqrtf(var + 1e-5f);
    }
}

// =====================================================================
// MFMA spatial shifted-window cosine attention (6 waves = 6 heads/window)
// =====================================================================
__global__ __launch_bounds__(384)
void sp_attn_k(const bf16* __restrict__ spqkv, const float* __restrict__ rpb,
               const float* __restrict__ logit_sp, bf16* __restrict__ osp)
{
    const int b    = blockIdx.x >> 8;
    const int win  = blockIdx.x & 255;
    const int wh = win >> 4, ww = win & 15;
    const int head = threadIdx.x >> 6;
    const int lane = threadIdx.x & 63;
    const int row16 = lane & 15;
    const int hi   = lane >> 4;
    const int koff = hi * 8;

    __shared__ float rpbS[1350];
    __shared__ u16 vT[SPH][32][72];

    for (int i = threadIdx.x; i < 1350; i += 384) rpbS[i] = rpb[i];

    const u16* base = (const u16*)spqkv + (size_t)b * HW * SPC;

    s16x8 qf[4], kf[4];
    const int wcol = (ww*8 + (row16 & 7) + 4) & 127;
    #pragma unroll
    for (int t = 0; t < 4; ++t) {
        const int pos = t*16 + row16;
        const int h = (wh*8 + (pos >> 3) + 4) & 127;
        const u16* rowp = base + ((size_t)(h * WR + wcol)) * SPC + head * 72;
        if (koff < 24) {
            qf[t] = *(const s16x8*)(rowp + koff);
            kf[t] = *(const s16x8*)(rowp + 24 + koff);
        } else {
            qf[t] = (s16x8){0,0,0,0,0,0,0,0};
            kf[t] = (s16x8){0,0,0,0,0,0,0,0};
        }
    }

    {
        const int h = (wh*8 + (lane >> 3) + 4) & 127;
        const int w = (ww*8 + (lane & 7) + 4) & 127;
        const u16* vrow = base + ((size_t)(h * WR + w)) * SPC + head * 72 + 48;
        union { uint4 v; u16 u[8]; } seg[3];
        seg[0].v = *(const uint4*)(vrow);
        seg[1].v = *(const uint4*)(vrow + 8);
        seg[2].v = *(const uint4*)(vrow + 16);
        #pragma unroll
        for (int d = 0; d < 24; ++d) vT[head][d][lane] = seg[d>>3].u[d&7];
        #pragma unroll
        for (int d = 24; d < 32; ++d) vT[head][d][lane] = 0;
    }
    __syncthreads();

    float rq[4], rk[4];
    #pragma unroll
    for (int t = 0; t < 4; ++t) {
        float sq = 0.f, sk = 0.f;
        #pragma unroll
        for (int e = 0; e < 8; ++e) {
            const float a = s2f(qf[t][e]); sq += a*a;
            const float c = s2f(kf[t][e]); sk += c*c;
        }
        sq += __shfl_xor(sq, 16); sq += __shfl_xor(sq, 32);
        sk += __shfl_xor(sk, 16); sk += __shfl_xor(sk, 32);
        rq[t] = 1.f / fmaxf(sqrtf(sq), 1e-12f);
        rk[t] = 1.f / fmaxf(sqrtf(sk), 1e-12f);
    }
    const float scale_h = __expf(fminf(logit_sp[head], LOGMAX));

    f32x4 acc[4][4];
    #pragma unroll
    for (int mfk = 0; mfk < 4; ++mfk)
        #pragma unroll
        for (int nfq = 0; nfq < 4; ++nfq)
            acc[mfk][nfq] = (f32x4){0.f,0.f,0.f,0.f};
    #pragma unroll
    for (int mfk = 0; mfk < 4; ++mfk)
        #pragma unroll
        for (int nfq = 0; nfq < 4; ++nfq)
            acc[mfk][nfq] = __builtin_amdgcn_mfma_f32_16x16x32_bf16(
                kf[mfk], qf[nfq], acc[mfk][nfq], 0, 0, 0);

    f32x4 rkj[4];
    #pragma unroll
    for (int mfk = 0; mfk < 4; ++mfk)
        #pragma unroll
        for (int r = 0; r < 4; ++r)
            rkj[mfk][r] = __shfl(rk[mfk], hi*4 + r);

    int ip3[4], iw7[4], labi[4];
    #pragma unroll
    for (int t = 0; t < 4; ++t) {
        const int pos = t*16 + row16;
        ip3[t] = pos >> 3; iw7[t] = pos & 7;
        const int hh = wh*8 + ip3[t], w0 = ww*8 + iw7[t];
        const int rh = hh < 120 ? 0 : (hh < 124 ? 1 : 2);
        const int rw = w0 < 120 ? 0 : (w0 < 124 ? 1 : 2);
        labi[t] = rh*3 + rw;
    }

    #pragma unroll
    for (int mfk = 0; mfk < 4; ++mfk) {
        #pragma unroll
        for (int r = 0; r < 4; ++r) {
            const int j = hi*4 + r + 16*mfk;
            const int jp3 = j >> 3, jw7 = j & 7;
            const int hh = wh*8 + jp3, w0 = ww*8 + jw7;
            const int rh = hh < 120 ? 0 : (hh < 124 ? 1 : 2);
            const int rw = w0 < 120 ? 0 : (w0 < 124 ? 1 : 2);
            const int labj = rh*3 + rw;
            const float rkv = rkj[mfk][r];
            #pragma unroll
            for (int nfq = 0; nfq < 4; ++nfq) {
                float s = acc[mfk][nfq][r] * rq[nfq] * rkv * scale_h;
                s += rpbS[((ip3[nfq]-jp3+7)*15 + (iw7[nfq]-jw7+7))*SPH + head];
                if (labi[nfq] != labj) s -= 100.f;
                acc[mfk][nfq][r] = s;
            }
        }
    }

    float inv[4];
    #pragma unroll
    for (int nfq = 0; nfq < 4; ++nfq) {
        float m = -1e30f;
        #pragma unroll
        for (int mfk = 0; mfk < 4; ++mfk)
            #pragma unroll
            for (int r = 0; r < 4; ++r)
                m = fmaxf(m, acc[mfk][nfq][r]);
        m = fmaxf(m, __shfl_xor(m, 16));
        m = fmaxf(m, __shfl_xor(m, 32));
        float s = 0.f;
        #pragma unroll
        for (int mfk = 0; mfk < 4; ++mfk)
            #pragma unroll
            for (int r = 0; r < 4; ++r) {
                const float p = __expf(acc[mfk][nfq][r] - m);
                acc[mfk][nfq][r] = p;
                s += p;
            }
        s += __shfl_xor(s, 16);
        s += __shfl_xor(s, 32);
        inv[nfq] = 1.f / s;
    }

    u32 pk01[4][4], pk23[4][4];
    #pragma unroll
    for (int mfk = 0; mfk < 4; ++mfk)
        #pragma unroll
        for (int nfq = 0; nfq < 4; ++nfq) {
            pk01[mfk][nfq] = (u32)f2u(acc[mfk][nfq][0] * inv[nfq])
                           | ((u32)f2u(acc[mfk][nfq][1] * inv[nfq]) << 16);
            pk23[mfk][nfq] = (u32)f2u(acc[mfk][nfq][2] * inv[nfq])
                           | ((u32)f2u(acc[mfk][nfq][3] * inv[nfq]) << 16);
        }

    s16x8 vf[2][2];
    #pragma unroll
    for (int nf = 0; nf < 2; ++nf)
        #pragma unroll
        for (int ks = 0; ks < 2; ++ks)
            vf[nf][ks] = *(const s16x8*)&vT[head][row16 + 16*nf][32*ks + koff];

    f32x4 accO[4][2];
    #pragma unroll
    for (int MF = 0; MF < 4; ++MF)
        #pragma unroll
        for (int nf = 0; nf < 2; ++nf)
            accO[MF][nf] = (f32x4){0.f,0.f,0.f,0.f};

    const int g0 = 2*(hi & 1);
    const int src0 = g0*16 + row16, src1 = src0 + 16;
    const bool selhi = (hi >> 1) != 0;
    #pragma unroll
    for (int ks = 0; ks < 2; ++ks) {
        #pragma unroll
        for (int MF = 0; MF < 4; ++MF) {
            const u32 e01a = __shfl(pk01[2*ks][MF],   src0);
            const u32 e01b = __shfl(pk01[2*ks+1][MF], src0);
            const u32 e23a = __shfl(pk23[2*ks][MF],   src0);
            const u32 e23b = __shfl(pk23[2*ks+1][MF], src0);
            const u32 e45a = __shfl(pk01[2*ks][MF],   src1);
            const u32 e45b = __shfl(pk01[2*ks+1][MF], src1);
            const u32 e67a = __shfl(pk23[2*ks][MF],   src1);
            const u32 e67b = __shfl(pk23[2*ks+1][MF], src1);
            union { u32 w[4]; s16x8 v; } af;
            af.w[0] = selhi ? e01b : e01a;
            af.w[1] = selhi ? e23b : e23a;
            af.w[2] = selhi ? e45b : e45a;
            af.w[3] = selhi ? e67b : e67a;
            accO[MF][0] = __builtin_amdgcn_mfma_f32_16x16x32_bf16(
                af.v, vf[0][ks], accO[MF][0], 0, 0, 0);
            accO[MF][1] = __builtin_amdgcn_mfma_f32_16x16x32_bf16(
                af.v, vf[1][ks], accO[MF][1], 0, 0, 0);
        }
    }

    #pragma unroll
    for (int MF = 0; MF < 4; ++MF) {
        #pragma unroll
        for (int nf = 0; nf < 2; ++nf) {
            const int d = row16 + 16*nf;
            if (d >= 24) continue;
            #pragma unroll
            for (int r = 0; r < 4; ++r) {
                const int qrow = hi*4 + r + 16*MF;
                const int h = wh*8 + (qrow >> 3);
                const int w = ww*8 + (qrow & 7);
                osp[((size_t)b*HW + h*WR + w)*144 + head*24 + d] = f2b(accO[MF][nf][r]);
            }
        }
    }
}

// =====================================================================
// Channel attention: partial gram + column sum-squares, softmax, W-fuse
// =====================================================================
__global__ __launch_bounds__(256)
void ch_part_k(const bf16* __restrict__ chqkv, float* __restrict__ pgram,
               float* __restrict__ pss)
{
    const int ci = blockIdx.x, head = blockIdx.y, b = blockIdx.z;
    const int tid = threadIdx.x;
    __shared__ u16 tile[256][48];
    float g[3] = {0.f, 0.f, 0.f};
    float ss = 0.f;
    const u16* src = (const u16*)chqkv + (size_t)b * HW * CHC + head * 72;
    const int rbase = ci * 1024;

    for (int t0 = 0; t0 < 1024; t0 += 256) {
        __syncthreads();
        for (int idx = tid; idx < 256*6; idx += 256) {
            const int row = idx / 6, seg = idx - (idx/6)*6;
            *(uint4*)&tile[row][seg*8] =
                *(const uint4*)(src + (size_t)(rbase + t0 + row) * CHC + seg*8);
        }
        __syncthreads();
        #pragma unroll
        for (int i = 0; i < 3; ++i) {
            const int e = tid + i*256;
            if (e < 576) {
                const int c = e / 24, d = e - (e/24)*24;
                float s = 0.f;
                for (int r = 0; r < 256; ++r)
                    s += b2f(*(const bf16*)&tile[r][c]) * b2f(*(const bf16*)&tile[r][24+d]);
                g[i] += s;
            }
        }
        if (tid < 48) {
            float s = 0.f;
            for (int r = 0; r < 256; ++r) { const float v = b2f(*(const bf16*)&tile[r][tid]); s += v*v; }
            ss += s;
        }
    }
    float* pg = pgram + ((size_t)(b*2+head)*16 + ci) * 576;
    #pragma unroll
    for (int i = 0; i < 3; ++i) { const int e = tid + i*256; if (e < 576) pg[e] = g[i]; }
    if (tid < 48) pss[((size_t)(b*2+head)*16 + ci) * 48 + tid] = ss;
}

__global__ __launch_bounds__(256)
void ch_soft_k(const float* __restrict__ pgram, const float* __restrict__ pss,
               const float* __restrict__ logit_ch, float* __restrict__ attn)
{
    const int head = blockIdx.x, b = blockIdx.y;
    const int tid = threadIdx.x;
    __shared__ float gs[576], rn[48];
    for (int e = tid; e < 576; e += 256) {
        float s = 0.f;
        const float* pg = pgram + (size_t)(b*2+head)*16*576 + e;
        for (int c = 0; c < 16; ++c) s += pg[c*576];
        gs[e] = s;
    }
    if (tid < 48) {
        float s = 0.f;
        const float* ps = pss + (size_t)(b*2+head)*16*48 + tid;
        for (int c = 0; c < 16; ++c) s += ps[c*48];
        rn[tid] = 1.f / fmaxf(sqrtf(s), 1e-12f);
    }
    __syncthreads();
    if (tid < 24) {
        const float scale = expf(fminf(logit_ch[head], LOGMAX));
        float vals[24], mx = -1e30f;
        #pragma unroll
        for (int d = 0; d < 24; ++d) {
            vals[d] = gs[tid*24+d] * rn[tid] * rn[24+d] * scale;
            mx = fmaxf(mx, vals[d]);
        }
        float sum = 0.f;
        #pragma unroll
        for (int d = 0; d < 24; ++d) { vals[d] = expf(vals[d]-mx); sum += vals[d]; }
        const float inv = 1.f / sum;
        float* o = attn + ((size_t)(b*2+head)*24 + tid)*24;
        #pragma unroll
        for (int d = 0; d < 24; ++d) o[d] = vals[d]*inv;
    }
}

__global__ __launch_bounds__(192)
void fuse_chw_k(const float* __restrict__ Wc, const float* __restrict__ attn,
                bf16* __restrict__ Wf)
{
    const int b = blockIdx.x;
    const int n = threadIdx.x;
    __shared__ float As_[2][24][24];
    for (int e = n; e < 1152; e += 192) {
        const int h = e / 576, r = e - h*576;
        As_[h][r/24][r%24] = attn[(size_t)b*1152 + e];
    }
    __syncthreads();
    const float* wr = Wc + n*48;
    bf16* o = Wf + ((size_t)b*192 + n) * 48;
    for (int h = 0; h < 2; ++h)
        for (int d = 0; d < 24; ++d) {
            float s = 0.f;
            #pragma unroll
            for (int cc = 0; cc < 24; ++cc) s += wr[h*24+cc] * As_[h][cc][d];
            o[h*24+d] = f2b(s);
        }
}

// =====================================================================
// weight combiners
// =====================================================================
__global__ void combine_sp_k(const float* __restrict__ w_sp_proj, const float* __restrict__ w_spp,
                             const float* __restrict__ b_spp, bf16* __restrict__ Wc, float* __restrict__ bc)
{
    const int n = blockIdx.x;
    for (int i = threadIdx.x; i < 144; i += blockDim.x) {
        float s = 0.f;
        for (int j = 0; j < 144; ++j) s += w_sp_proj[n*144 + j] * w_spp[j*144 + i];
        Wc[n*144 + i] = f2b(s);
    }
    if (threadIdx.x == 0) {
        float s = 0.f;
        for (int j = 0; j < 144; ++j) s += w_sp_proj[n*144 + j] * b_spp[j];
        bc[n] = s;
    }
}

__global__ void combine_ch_k(const float* __restrict__ w_ch_proj, const float* __restrict__ w_chp,
                             const float* __restrict__ b_chp, float* __restrict__ Wc, float* __restrict__ bc)
{
    const int n = blockIdx.x;
    for (int c = threadIdx.x; c < 48; c += blockDim.x) {
        float s = 0.f;
        for (int j = 0; j < 48; ++j) s += w_ch_proj[n*48 + j] * w_chp[j*48 + c];
        Wc[n*48 + c] = s;
    }
    if (threadIdx.x == 0) {
        float s = 0.f;
        for (int j = 0; j < 48; ++j) s += w_ch_proj[n*48 + j] * b_chp[j];
        bc[n] = s;
    }
}

// =====================================================================
// coalesced per-(b,c) SUM over H,W (bf16 src), atomic accumulate.
// grid (HW/256, BATCH), 256 thr. dst must be pre-zeroed; gates_k divides.
// =====================================================================
__global__ __launch_bounds__(256)
void mean2_k(const bf16* __restrict__ src, float* __restrict__ dst)
{
    const int b = blockIdx.y;
    const int r0 = blockIdx.x * 256;
    const int t = threadIdx.x;
    const int chunk = t & 31;          // 0..31, valid < 24
    const int rg = t >> 5;             // 0..7
    float acc[8] = {0.f,0.f,0.f,0.f,0.f,0.f,0.f,0.f};
    if (chunk < 24) {
        for (int r = rg; r < 256; r += 8) {
            const u16* p = (const u16*)src + ((size_t)(b*HW) + r0 + r) * CCH + chunk*8;
            union { uint4 v; u16 u[8]; } s; s.v = *(const uint4*)p;
            #pragma unroll
            for (int j = 0; j < 8; ++j) acc[j] += u2f(s.u[j]);
        }
    }
    __shared__ float red[8][24][8];
    if (chunk < 24) {
        #pragma unroll
        for (int j = 0; j < 8; ++j) red[rg][chunk][j] = acc[j];
    }
    __syncthreads();
    if (t < 192) {
        const int ch = t >> 3, j = t & 7;
        float s = 0.f;
        #pragma unroll
        for (int g = 0; g < 8; ++g) s += red[g][ch][j];
        atomicAdd(&dst[b*CCH + ch*8 + j], s);
    }
}

// gate = sigmoid(relu((sum/HW) @ w1^T) @ w2^T + b2)
__global__ __launch_bounds__(192)
void gates_k(const float* __restrict__ sumv, const float* __restrict__ w1,
             const float* __restrict__ w2, const float* __restrict__ b2,
             float* __restrict__ gate)
{
    const int b = blockIdx.x;
    __shared__ float mv[192], hid[48];
    const int t = threadIdx.x;
    mv[t] = sumv[b*CCH + t] * (1.f / (float)HW);
    __syncthreads();
    if (t < 48) {
        float s = 0.f;
        for (int c = 0; c < 192; ++c) s += w1[t*192 + c] * mv[c];
        hid[t] = fmaxf(s, 0.f);
    }
    __syncthreads();
    float s = b2[t];
    for (int j = 0; j < 48; ++j) s += hid[j] * w2[t*48 + j];
    gate[b*CCH + t] = 1.f / (1.f + expf(-s));
}

// =====================================================================
// out = x + f2(padded) * (1 + sigmoid(relu(gpre)@w_sg2 + b))
// =====================================================================
__global__ __launch_bounds__(256)
void fuse_k(const float* __restrict__ x, const bf16* __restrict__ f2pad,
            const bf16* __restrict__ gpre, const float* __restrict__ w_sg2,
            const float* __restrict__ b_sg2, float* __restrict__ out)
{
    const int pix = blockIdx.x * 4 + (threadIdx.x >> 6);
    const int lane = threadIdx.x & 63;
    const bf16* gp = gpre + (size_t)pix * 96;
    float s = fmaxf(b2f(gp[lane]), 0.f) * w_sg2[lane];
    if (lane < 32) s += fmaxf(b2f(gp[lane + 64]), 0.f) * w_sg2[lane + 64];
    for (int m = 1; m < 64; m <<= 1) s += __shfl_xor(s, m);
    const float g1 = 1.f + 1.f / (1.f + expf(-(s + b_sg2[0])));
    const int b = pix >> 14, p = pix & 16383;
    const int h = p >> 7, w = p & 127;
    const bf16* fr = f2pad + ((size_t)b * PHW + (size_t)(h+1) * PH + (w+1)) * CCH;
    const float* xr = x + (size_t)pix * CCH;
    float* orow = out + (size_t)pix * CCH;
    for (int c = lane; c < CCH; c += 64) orow[c] = xr[c] + b2f(fr[c]) * g1;
}

// =====================================================================
// launcher
// =====================================================================
extern "C" void kernel_launch(void* const* d_in, const int* in_sizes, int n_in,
                              void* d_out, int out_size, void* d_ws, size_t ws_size,
                              hipStream_t stream)
{
    const float* x        = (const float*)d_in[0];
    const float* ln1_g    = (const float*)d_in[1];
    const float* ln1_b    = (const float*)d_in[2];
    const float* w_qkv    = (const float*)d_in[3];
    const float* b_qkv    = (const float*)d_in[4];
    const float* logit_sp = (const float*)d_in[5];
    const float* rpb      = (const float*)d_in[6];
    const float* w_spp    = (const float*)d_in[7];
    const float* b_spp    = (const float*)d_in[8];
    const float* logit_ch = (const float*)d_in[9];
    const float* w_chp    = (const float*)d_in[10];
    const float* b_chp    = (const float*)d_in[11];
    const float* w_sp_proj= (const float*)d_in[12];
    const float* w_ch_proj= (const float*)d_in[13];
    const float* w_s2c1   = (const float*)d_in[14];
    const float* w_s2c2   = (const float*)d_in[15];
    const float* b_s2c2   = (const float*)d_in[16];
    const float* w_c2s1   = (const float*)d_in[17];
    const float* w_c2s2   = (const float*)d_in[18];
    const float* b_c2s2   = (const float*)d_in[19];
    const float* w_gs1    = (const float*)d_in[20];
    const float* w_gs2    = (const float*)d_in[21];
    const float* b_gs2    = (const float*)d_in[22];
    const float* w_gc1    = (const float*)d_in[23];
    const float* w_gc2    = (const float*)d_in[24];
    const float* b_gc2    = (const float*)d_in[25];
    const float* w_f1     = (const float*)d_in[26];
    const float* bn1_g    = (const float*)d_in[27];
    const float* bn1_b    = (const float*)d_in[28];
    const float* bn1_m    = (const float*)d_in[29];
    const float* bn1_v    = (const float*)d_in[30];
    const float* w_f2     = (const float*)d_in[31];
    const float* bn2_g    = (const float*)d_in[32];
    const float* bn2_b    = (const float*)d_in[33];
    const float* bn2_m    = (const float*)d_in[34];
    const float* bn2_v    = (const float*)d_in[35];
    const float* w_sg1    = (const float*)d_in[36];
    const float* w_sg2    = (const float*)d_in[37];
    const float* b_sg2    = (const float*)d_in[38];
    const float* ln2_g    = (const float*)d_in[39];
    const float* ln2_b    = (const float*)d_in[40];
    const float* w_fc1    = (const float*)d_in[41];
    const float* b_fc1    = (const float*)d_in[42];
    const float* w_fc2    = (const float*)d_in[43];
    const float* b_fc2    = (const float*)d_in[44];

    char* wsb = (char*)d_ws;
    char* sm  = wsb + OFF_SMALL;
    float* out = (float*)d_out;

    bf16*  spqkv  = (bf16*)(wsb + OFF_A0);
    bf16*  sp_out = (bf16*)(wsb + OFF_A0);
    bf16*  ch_out = (bf16*)(wsb + OFF_A0 + 50331648);
    bf16*  f2pad  = (bf16*)(wsb + OFF_A0);
    bf16*  gpre   = (bf16*)(wsb + OFF_A0 + 51916800);
    bf16*  chqkv  = (bf16*)(wsb + OFF_B0);
    bf16*  hid_s  = (bf16*)(wsb + OFF_B0);
    bf16*  hid_c  = (bf16*)(wsb + OFF_B0 + 12582912);
    bf16*  fpad   = (bf16*)(wsb + OFF_B0);
    bf16*  hidden = (bf16*)(wsb + OFF_A0);   // fc1 out: A0 fully dead after fuse_k
    bf16*  osp    = (bf16*)(wsb + OFF_C0);

    float* stats  = (float*)(sm + SO_STATS);
    float* pgram  = (float*)(sm + SO_PGRAM);
    float* pss    = (float*)(sm + SO_PSS);
    float* attn_b = (float*)(sm + SO_ATTNB);
    float* mean_sp= (float*)(sm + SO_MEANSP);
    float* mean_ch= (float*)(sm + SO_MEANCH);
    float* gate_s = (float*)(sm + SO_GATES);
    float* gate_c = (float*)(sm + SO_GATEC);
    float* bc_sp  = (float*)(sm + SO_BCSP);
    float* Wc_ch  = (float*)(sm + SO_WCCH);
    float* bc_ch  = (float*)(sm + SO_BCCH);
    bf16*  Wfuse  = (bf16*)(sm + SO_WFUSE);
    bf16*  Wc_spB = (bf16*)(sm + SO_WCSPB);
    u16*   wqB    = (u16*)(sm + SO_WQB);
    u16*   ws2c1B = (u16*)(sm + SO_WS2C1B);
    u16*   wc2s1B = (u16*)(sm + SO_WC2S1B);
    u16*   ws2c2B = (u16*)(sm + SO_WS2C2B);
    u16*   wc2s2B = (u16*)(sm + SO_WC2S2B);
    u16*   wf1B   = (u16*)(sm + SO_WF1B);
    u16*   wf2cB  = (u16*)(sm + SO_WF2CB);
    u16*   wsg1cB = (u16*)(sm + SO_WSG1CB);
    u16*   wfc1B  = (u16*)(sm + SO_WFC1B);
    u16*   wfc2B  = (u16*)(sm + SO_WFC2B);

    const dim3 blk(256);

    // ---- weight prep ----
    wprep_lin_k<<<(110592+255)/256, blk, 0, stream>>>(w_qkv,  (bf16*)wqB,    110592);
    wprep_lin_k<<<(9216+255)/256,   blk, 0, stream>>>(w_s2c1, (bf16*)ws2c1B, 9216);
    wprep_lin_k<<<(9216+255)/256,   blk, 0, stream>>>(w_c2s1, (bf16*)wc2s1B, 9216);
    wprep_lin_k<<<(9216+255)/256,   blk, 0, stream>>>(w_s2c2, (bf16*)ws2c2B, 9216);
    wprep_lin_k<<<(9216+255)/256,   blk, 0, stream>>>(w_c2s2, (bf16*)wc2s2B, 9216);
    wprep_lin_k<<<(73728+255)/256,  blk, 0, stream>>>(w_f1,   (bf16*)wf1B,   73728);
    wprep_lin_k<<<(147456+255)/256, blk, 0, stream>>>(w_fc1,  (bf16*)wfc1B,  147456);
    wprep_lin_k<<<(147456+255)/256, blk, 0, stream>>>(w_fc2,  (bf16*)wfc2B,  147456);
    wprep_conv_k<<<(331776+255)/256, blk, 0, stream>>>(w_f2,  (bf16*)wf2cB,  331776);
    wprep_conv_k<<<(165888+255)/256, blk, 0, stream>>>(w_sg1, (bf16*)wsg1cB, 165888);
    combine_sp_k<<<192, 128, 0, stream>>>(w_sp_proj, w_spp, b_spp, Wc_spB, bc_sp);
    combine_ch_k<<<192, 64, 0, stream>>>(w_ch_proj, w_chp, b_chp, Wc_ch, bc_ch);
    zerof_k<<<6, blk, 0, stream>>>(mean_sp, 1536);
    zerof_k<<<6, blk, 0, stream>>>(mean_ch, 1536);

    // ---- LN1 stats + full-M qkv GEMM (split store) ----
    ln_stats_k<<<MTOK/4, blk, 0, stream>>>(x, stats);
    gemm_k<1,7,1,192,0,0><<<dim3(3, MTOK/GBM), blk, 0, stream>>>(
        x, wqB, b_qkv, spqkv, MTOK, 576, CCH,
        stats, ln1_g, ln1_b, nullptr,
        (const float*)chqkv, nullptr, nullptr, nullptr);

    // ---- MFMA spatial attention + sp proj (roll store) ----
    sp_attn_k<<<dim3(BATCH*NWIN), dim3(384), 0, stream>>>(spqkv, rpb, logit_sp, osp);
    gemm_k<0,2,1,192,0,0><<<dim3(1, MTOK/GBM), blk, 0, stream>>>(
        osp, (const u16*)Wc_spB, bc_sp, sp_out, MTOK, CCH, 144,
        nullptr, nullptr, nullptr, nullptr,
        nullptr, nullptr, nullptr, nullptr);

    // ---- channel attention: partial gram -> softmax -> fused W -> GEMM ----
    ch_part_k<<<dim3(16, 2, BATCH), blk, 0, stream>>>(chqkv, pgram, pss);
    ch_soft_k<<<dim3(2, BATCH), blk, 0, stream>>>(pgram, pss, logit_ch, attn_b);
    fuse_chw_k<<<BATCH, 192, 0, stream>>>(Wc_ch, attn_b, Wfuse);
    gemm_k<4,0,1,192,0,1><<<dim3(1, MTOK/GBM), blk, 0, stream>>>(
        chqkv, (const u16*)Wfuse, bc_ch, ch_out, MTOK, CCH, 48,
        nullptr, nullptr, nullptr, nullptr,
        nullptr, nullptr, nullptr, nullptr);

    // ---- CFCA means/gates (coalesced sum + atomic) ----
    mean2_k<<<dim3(HW/256, BATCH), blk, 0, stream>>>(sp_out, mean_sp);
    mean2_k<<<dim3(HW/256, BATCH), blk, 0, stream>>>(ch_out, mean_ch);
    gates_k<<<BATCH, 192, 0, stream>>>(mean_sp, w_gs1, w_gs2, b_gs2, gate_s);
    gates_k<<<BATCH, 192, 0, stream>>>(mean_ch, w_gc1, w_gc2, b_gc2, gate_c);

    // ---- CFCA hiddens + gated residual adds ----
    gemm_k<0,1,1,96,0,0><<<dim3(1, MTOK/GBM), blk, 0, stream>>>(
        sp_out, ws2c1B, nullptr, hid_s, MTOK, MIDC, CCH,
        nullptr, nullptr, nullptr, nullptr, nullptr, nullptr, nullptr, nullptr);
    gemm_k<0,1,1,96,0,0><<<dim3(1, MTOK/GBM), blk, 0, stream>>>(
        ch_out, wc2s1B, nullptr, hid_c, MTOK, MIDC, CCH,
        nullptr, nullptr, nullptr, nullptr, nullptr, nullptr, nullptr, nullptr);
    gemm_k<0,4,1,192,0,0><<<dim3(1, MTOK/GBM), blk, 0, stream>>>(
        hid_s, ws2c2B, b_s2c2, ch_out, MTOK, CCH, MIDC,
        nullptr, nullptr, nullptr, nullptr, gate_s, nullptr, nullptr, nullptr);
    gemm_k<0,4,1,192,0,0><<<dim3(1, MTOK/GBM), blk, 0, stream>>>(
        hid_c, wc2s2B, b_c2s2, sp_out, MTOK, CCH, MIDC,
        nullptr, nullptr, nullptr, nullptr, gate_c, nullptr, nullptr, nullptr);

    // ---- f = relu(bn1(concat @ w_f1^T)) -> PADDED fpad ----
    zb_k<<<(8*516*24+255)/256, blk, 0, stream>>>(fpad);
    gemm_k<2,3,1,192,1,0><<<dim3(1, MTOK/GBM), blk, 0, stream>>>(
        sp_out, wf1B, nullptr, fpad, MTOK, CCH, 2*CCH,
        nullptr, nullptr, nullptr, ch_out, bn1_g, bn1_b, bn1_m, bn1_v);

    // ---- f2 = relu(bn2(conv3x3(f))) -> PADDED f2pad ----
    zb_k<<<(8*516*24+255)/256, blk, 0, stream>>>(f2pad);
    gemm_k<3,3,1,192,1,0><<<dim3(1, MTOK/GBM), blk, 0, stream>>>(
        fpad, wf2cB, nullptr, f2pad, MTOK, CCH, 9*CCH,
        nullptr, nullptr, nullptr, nullptr, bn2_g, bn2_b, bn2_m, bn2_v);

    // ---- gpre = conv3x3(f2) (96 ch) ----
    gemm_k<3,0,1,96,0,0><<<dim3(1, MTOK/GBM), blk, 0, stream>>>(
        f2pad, wsg1cB, nullptr, gpre, MTOK, 96, 9*CCH,
        nullptr, nullptr, nullptr, nullptr, nullptr, nullptr, nullptr, nullptr);

    // ---- xnew = x + f2*(1+g) -> d_out ----
    fuse_k<<<MTOK/4, blk, 0, stream>>>(x, f2pad, gpre, w_sg2, b_sg2, out);

    // ---- LN2 + MLP (2 chunks; hidden over dead A0 region) ----
    ln_stats_k<<<MTOK/4, blk, 0, stream>>>(out, stats);
    const int CHM = MTOK / 2;  // 65536 tokens per chunk; hidden chunk = 100 MB
    for (int c0 = 0; c0 < MTOK; c0 += CHM) {
        gemm_k<1,5,1,192,0,0><<<dim3(4, CHM/GBM), blk, 0, stream>>>(
            out + (size_t)c0*CCH, wfc1B, b_fc1, hidden, CHM, 4*CCH, CCH,
            stats + (size_t)c0*2, ln2_g, ln2_b, nullptr,
            nullptr, nullptr, nullptr, nullptr);
        gemm_k<0,6,0,192,0,0><<<dim3(1, CHM/GBM), blk, 0, stream>>>(
            hidden, wfc2B, b_fc2, out + (size_t)c0*CCH, CHM, CCH, 4*CCH,
            nullptr, nullptr, nullptr, nullptr, out + (size_t)c0*CCH,
            nullptr, nullptr, nullptr);
    }
}